// Round 9
// baseline (719.512 us; speedup 1.0000x reference)
//
#include <hip/hip_runtime.h>
#include <hip/hip_bf16.h>
#include <math.h>

// Problem constants
#define BB 32
#define LL 300
#define TT 12
#define HH 256
#define EE 128
#define VV 50000
#define OOV 30
#define NPR 6
#define UNK 1
#define H2 512   // 2H
#define H3 768   // 3H
#define H4 1024  // 4H
#define BT (BB*TT)       // 384
#define NVB 391          // ceil(50000/128)
#define KSTEPS 24        // 768/32

// ---------------- ws layout (float offsets) ----------------
#define OFF_X        0                          // BT*EE
#define OFF_HID      (OFF_X + BT*EE)            // BT*HH
#define OFF_ENCP     (OFF_HID + BT*HH)          // BB*LL*H2
#define OFF_DECP     (OFF_ENCP + BB*LL*H2)      // BT*H2
#define OFF_ATTN     (OFF_DECP + BT*H2)         // BT*LL
#define OFF_S        (OFF_ATTN + BT*LL)         // BT*H3
#define OFF_PSW      (OFF_S + BT*H3)            // BT*3
#define OFF_COPY     (OFF_PSW + BT*3)           // BT
#define OFF_TLOGIT   (OFF_COPY + BT)            // BT
#define OFF_PMAX     (OFF_TLOGIT + BT)          // BT*NVB (unused)
#define OFF_PSUM     (OFF_PMAX + BT*NVB)        // BT*NVB
#define OFF_NLL      (OFF_PSUM + BT*NVB)        // BT
#define OFF_APACK    (OFF_NLL + BT)             // BT*H3 shorts = BT*H3/2 floats
#define OFF_XW       (OFF_APACK + BT*H3/2)      // BT*H4 floats (x@W_ih + b)
#define OFF_WHH      (OFF_XW + BT*H4)           // HH*H4 shorts = HH*H4/2 floats

typedef __attribute__((ext_vector_type(8))) short short8;
typedef __attribute__((ext_vector_type(16))) float floatx16;

__device__ __forceinline__ short f2bf(float f) {
    __hip_bfloat16 h = __float2bfloat16(f);
    return *reinterpret_cast<short*>(&h);
}
__device__ __forceinline__ float bf2f(short s) {
    unsigned int u = ((unsigned int)(unsigned short)s) << 16;
    return __uint_as_float(u);
}
__device__ __forceinline__ float sigm(float x) { return 1.f/(1.f + expf(-x)); }

// ---------------- K0: embedding lookup ----------------
__global__ __launch_bounds__(256) void k_embed(
    const float* __restrict__ embed, const int* __restrict__ dec_input,
    float* __restrict__ x_out)
{
    int i = blockIdx.x*256 + threadIdx.x;      // one float4 per thread, BT*EE/4
    int bt = i >> 5;                           // EE/4 = 32 float4 per row
    int e4 = i & 31;
    int tok = dec_input[bt];
    reinterpret_cast<float4*>(x_out)[(size_t)bt*32 + e4] =
        reinterpret_cast<const float4*>(embed)[(size_t)tok*32 + e4];
}

// ---------------- K0b: W_hh [256][1024] fp32 -> bf16 B-frag order ----------------
// slot s = ((ct*16 + kstep)*2 + half)*32 + col ; 8 shorts each:
//   value j = W_hh[kstep*16 + half*8 + j][ct*32 + col]
__global__ __launch_bounds__(256) void k_whh_pack(
    const float* __restrict__ Whh, short* __restrict__ wp)
{
    int s = blockIdx.x*256 + threadIdx.x;      // 0..32767
    int col = s & 31;
    int half = (s >> 5) & 1;
    int kstep = (s >> 6) & 15;
    int ct = s >> 10;
    int kb = kstep*16 + half*8;
    int c = ct*32 + col;
    short8 v;
    #pragma unroll
    for (int j = 0; j < 8; ++j) v[j] = f2bf(Whh[(size_t)(kb + j)*H4 + c]);
    *reinterpret_cast<short8*>(wp + (size_t)s*8) = v;
}

// ---------------- generic fp32 GEMM + bias ----------------
__global__ __launch_bounds__(256) void k_gemm_bias(
    const float* __restrict__ A, const float* __restrict__ Wm,
    const float* __restrict__ bias, float* __restrict__ C, int N_, int K_)
{
    __shared__ float As[64][17];
    __shared__ __align__(16) float Bs[16][128];
    int bm = blockIdx.x*64, bn = blockIdx.y*128;
    int tid = threadIdx.x, tr = tid >> 4, tc = tid & 15;
    float acc[4][8] = {};
    for (int k0 = 0; k0 < K_; k0 += 16) {
        for (int i = tid; i < 64*16; i += 256) { int r = i >> 4, c = i & 15; As[r][c] = A[(size_t)(bm+r)*K_ + k0 + c]; }
        for (int i = tid; i < 16*128; i += 256) { int r = i >> 7, c = i & 127; Bs[r][c] = Wm[(size_t)(k0+r)*N_ + bn + c]; }
        __syncthreads();
        #pragma unroll
        for (int kk = 0; kk < 16; ++kk) {
            float a0 = As[tr*4+0][kk], a1 = As[tr*4+1][kk], a2 = As[tr*4+2][kk], a3 = As[tr*4+3][kk];
            const float4* bp = reinterpret_cast<const float4*>(&Bs[kk][tc*8]);
            float4 q0 = bp[0], q1 = bp[1];
            float bb[8] = {q0.x,q0.y,q0.z,q0.w,q1.x,q1.y,q1.z,q1.w};
            #pragma unroll
            for (int j = 0; j < 8; ++j) {
                acc[0][j] += a0*bb[j]; acc[1][j] += a1*bb[j];
                acc[2][j] += a2*bb[j]; acc[3][j] += a3*bb[j];
            }
        }
        __syncthreads();
    }
    for (int i = 0; i < 4; ++i) {
        int r = bm + tr*4 + i;
        for (int j = 0; j < 8; ++j) {
            int c = bn + tc*8 + j;
            C[(size_t)r*N_ + c] = acc[i][j] + bias[c];
        }
    }
}

// ---------------- K1: batched-MFMA LSTM, ONE block (all 32 batch rows) ----------------
// Per step: [32,256]@[256,1024] via 16 waves x 2 col-tiles x 16 K-steps of
// mfma_f32_32x32x16_bf16. h lives in LDS in A-frag bf16 layout; gates -> LDS
// bf16; c fp32 in LDS. xw = x@W_ih+b precomputed (read in epilogue, L2-hot).
__global__ __launch_bounds__(1024) void k_lstm2(
    const float* __restrict__ xw, const short* __restrict__ whhp,
    const float* __restrict__ h0, const float* __restrict__ c0,
    float* __restrict__ hid_out)
{
    __shared__ short hfrag[32*32*8];   // slot ((kstep*2+half)*32 + row)*8 + j : 16 KB
    __shared__ float c_lds[32][HH];    // 32 KB
    __shared__ short g_lds[32][H4];    // 64 KB
    int tid = threadIdx.x;
    int wid = tid >> 6, lane = tid & 63;
    int cin = lane & 31, half = lane >> 5;

    // init h0 -> hfrag (bf16, A-frag layout), c0 -> c_lds
    for (int i = tid; i < 32*HH; i += 1024) {
        int b = i >> 8, k = i & 255;
        hfrag[((k>>4)*2 + ((k>>3)&1))*256 + b*8 + (k&7)] = f2bf(h0[b*HH + k]);
        c_lds[b][k] = c0[b*HH + k];
    }
    __syncthreads();

    const short8* wp = reinterpret_cast<const short8*>(whhp);
    int ct0 = wid*2, ct1 = wid*2 + 1;

    for (int t = 0; t < TT; ++t) {
        floatx16 a0, a1;
        #pragma unroll
        for (int r = 0; r < 16; ++r) { a0[r] = 0.f; a1[r] = 0.f; }
        #pragma unroll
        for (int kstep = 0; kstep < 16; ++kstep) {
            short8 af = *reinterpret_cast<const short8*>(
                &hfrag[((kstep*2 + half)*32 + cin)*8]);
            short8 b0 = wp[(size_t)(((ct0*16 + kstep)*2 + half)*32 + cin)];
            short8 b1 = wp[(size_t)(((ct1*16 + kstep)*2 + half)*32 + cin)];
            a0 = __builtin_amdgcn_mfma_f32_32x32x16_bf16(af, b0, a0, 0, 0, 0);
            a1 = __builtin_amdgcn_mfma_f32_32x32x16_bf16(af, b1, a1, 0, 0, 0);
        }
        // epilogue: g = acc + xw  -> g_lds (bf16). acc: col=cin, row=(r&3)+8*(r>>2)+4*half
        #pragma unroll
        for (int r = 0; r < 16; ++r) {
            int row = (r & 3) + 8*(r >> 2) + 4*half;   // batch index
            int cA = ct0*32 + cin;
            int cB = ct1*32 + cin;
            g_lds[row][cA] = f2bf(a0[r] + xw[(size_t)(row*TT + t)*H4 + cA]);
            g_lds[row][cB] = f2bf(a1[r] + xw[(size_t)(row*TT + t)*H4 + cB]);
        }
        __syncthreads();
        // update: thread -> (j = tid&255, 8 batch rows)
        int j = tid & 255;
        int bbase = (tid >> 8) * 8;
        #pragma unroll
        for (int bb = 0; bb < 8; ++bb) {
            int b = bbase + bb;
            float gi = bf2f(g_lds[b][j]);
            float gf = bf2f(g_lds[b][HH + j]);
            float gg = bf2f(g_lds[b][2*HH + j]);
            float go = bf2f(g_lds[b][3*HH + j]);
            float c = sigm(gf)*c_lds[b][j] + sigm(gi)*tanhf(gg);
            float h = sigm(go)*tanhf(c);
            c_lds[b][j] = c;
            hfrag[((j>>4)*2 + ((j>>3)&1))*256 + b*8 + (j&7)] = f2bf(h);
            hid_out[(size_t)(b*TT + t)*HH + j] = h;
        }
        __syncthreads();
    }
}

// ---------------- K4: e[b,t,l] = v·tanh(enc_proj[b,l]+dec_proj[b,t]) + v_b ----------------
__global__ __launch_bounds__(256) void k_e(
    const float* __restrict__ enc_proj, const float* __restrict__ dec_proj,
    const float* __restrict__ v_w, const float* __restrict__ v_b,
    const unsigned char* __restrict__ enc_mask, float* __restrict__ e_out)
{
    int b = blockIdx.x, lbase = blockIdx.y*4;
    __shared__ float decp[TT*H2];
    int tid = threadIdx.x;
    for (int i = tid; i < TT*H2; i += 256) decp[i] = dec_proj[(size_t)b*TT*H2 + i];
    __syncthreads();
    int wave = tid >> 6, lane = tid & 63;
    int l = lbase + wave;
    const float* er = &enc_proj[(size_t)(b*LL + l)*H2];
    float ep[8], vw[8];
    #pragma unroll
    for (int k = 0; k < 8; ++k) { int e = lane + 64*k; ep[k] = er[e]; vw[k] = v_w[e]; }
    float vb = v_b[0];
    bool masked = enc_mask[b*LL + l] != 0;
    for (int t = 0; t < TT; ++t) {
        float acc = 0.f;
        #pragma unroll
        for (int k = 0; k < 8; ++k) {
            int e = lane + 64*k;
            acc += vw[k] * tanhf(ep[k] + decp[t*H2 + e]);
        }
        #pragma unroll
        for (int off = 32; off; off >>= 1) acc += __shfl_xor(acc, off);
        if (lane == 0)
            e_out[(size_t)(b*TT + t)*LL + l] = masked ? -INFINITY : (acc + vb);
    }
}

// ---------------- K5: softmax over L + context + build s=[hidden,context] ----------------
__global__ __launch_bounds__(256) void k_softmax_ctx(
    float* __restrict__ attn, const float* __restrict__ enc_states,
    const float* __restrict__ hidden, float* __restrict__ s_out)
{
    int bt = blockIdx.x, b = bt / TT, tid = threadIdx.x;
    __shared__ float a[LL];
    __shared__ float red[256];
    float m = -INFINITY;
    for (int l = tid; l < LL; l += 256) m = fmaxf(m, attn[(size_t)bt*LL + l]);
    red[tid] = m; __syncthreads();
    for (int s = 128; s; s >>= 1) { if (tid < s) red[tid] = fmaxf(red[tid], red[tid+s]); __syncthreads(); }
    m = red[0]; __syncthreads();
    float sum = 0.f;
    for (int l = tid; l < LL; l += 256) { float w = expf(attn[(size_t)bt*LL + l] - m); a[l] = w; sum += w; }
    red[tid] = sum; __syncthreads();
    for (int s = 128; s; s >>= 1) { if (tid < s) red[tid] += red[tid+s]; __syncthreads(); }
    float inv = 1.0f / red[0];
    __syncthreads();
    for (int l = tid; l < LL; l += 256) { float w = a[l]*inv; a[l] = w; attn[(size_t)bt*LL + l] = w; }
    __syncthreads();
    for (int c = tid; c < H2; c += 256) {
        float acc = 0.f;
        const float* es = &enc_states[(size_t)b*LL*H2 + c];
        for (int l = 0; l < LL; ++l) acc += a[l] * es[(size_t)l*H2];
        s_out[(size_t)bt*H3 + HH + c] = acc;
    }
    for (int c = tid; c < HH; c += 256) s_out[(size_t)bt*H3 + c] = hidden[(size_t)bt*HH + c];
}

// ---------------- K6: switch softmax + copy score ----------------
__global__ __launch_bounds__(64) void k_switch_copy(
    const float* __restrict__ s, const float* __restrict__ x,
    const float* __restrict__ enc_h0,
    const float* __restrict__ wh_w, const float* __restrict__ wh_b,
    const float* __restrict__ ws_w, const float* __restrict__ ws_b,
    const float* __restrict__ wx_w, const float* __restrict__ wx_b,
    const float* __restrict__ wc_w, const float* __restrict__ wc_b,
    const int* __restrict__ article_inds, const int* __restrict__ targets,
    const float* __restrict__ attn, float* __restrict__ psw, float* __restrict__ copysc)
{
    int bt = blockIdx.x, b = bt / TT, lane = threadIdx.x;
    float s0 = 0.f, s1 = 0.f, s2 = 0.f;
    const float* ctx = &s[(size_t)bt*H3 + HH];
    const float* hid = &s[(size_t)bt*H3];
    for (int k = lane; k < H2; k += 64) { float v = ctx[k]; s0 += v*wh_w[k*3]; s1 += v*wh_w[k*3+1]; s2 += v*wh_w[k*3+2]; }
    for (int k = lane; k < HH; k += 64) { float v = hid[k]; s0 += v*ws_w[k*3]; s1 += v*ws_w[k*3+1]; s2 += v*ws_w[k*3+2]; }
    for (int k = lane; k < EE; k += 64) { float v = x[(size_t)bt*EE + k]; s0 += v*wx_w[k*3]; s1 += v*wx_w[k*3+1]; s2 += v*wx_w[k*3+2]; }
    for (int k = lane; k < HH; k += 64) { float v = enc_h0[b*HH + k]; s0 += v*wc_w[k*3]; s1 += v*wc_w[k*3+1]; s2 += v*wc_w[k*3+2]; }
    #pragma unroll
    for (int off = 32; off; off >>= 1) {
        s0 += __shfl_xor(s0, off); s1 += __shfl_xor(s1, off); s2 += __shfl_xor(s2, off);
    }
    if (lane == 0) {
        s0 += wh_b[0] + ws_b[0] + wx_b[0] + wc_b[0];
        s1 += wh_b[1] + ws_b[1] + wx_b[1] + wc_b[1];
        s2 += wh_b[2] + ws_b[2] + wx_b[2] + wc_b[2];
        float mm = fmaxf(s0, fmaxf(s1, s2));
        float e0 = expf(s0-mm), e1 = expf(s1-mm), e2 = expf(s2-mm);
        float inv = 1.f/(e0+e1+e2);
        psw[bt*3+0] = e0*inv; psw[bt*3+1] = e1*inv; psw[bt*3+2] = e2*inv;
    }
    int tgt = targets[bt];
    float cs = 0.f;
    for (int l = lane; l < LL; l += 64)
        if (article_inds[b*LL + l] == tgt) cs += attn[(size_t)bt*LL + l];
    #pragma unroll
    for (int off = 32; off; off >>= 1) cs += __shfl_xor(cs, off);
    if (lane == 0) copysc[bt] = cs;
}

// ---------------- K_pack: s_buf [384][768] fp32 -> fragment-ordered bf16 ----------------
__global__ __launch_bounds__(256) void k_pack(
    const float* __restrict__ A, short* __restrict__ Apack)
{
    int s = blockIdx.x*256 + threadIdx.x;          // 0 .. 36863
    int l = s & 63;
    int ks = (s >> 6) & 1;
    int rest = s >> 7;
    int mt = rest % 12;
    int kstep = rest / 12;
    int row = mt*32 + (l & 31);
    int kb = kstep*32 + ks*16 + ((l >> 5) << 3);
    const float4* src = reinterpret_cast<const float4*>(&A[(size_t)row*H3 + kb]);
    float4 a = src[0], b = src[1];
    short8 v;
    v[0]=f2bf(a.x); v[1]=f2bf(a.y); v[2]=f2bf(a.z); v[3]=f2bf(a.w);
    v[4]=f2bf(b.x); v[5]=f2bf(b.y); v[6]=f2bf(b.z); v[7]=f2bf(b.w);
    *reinterpret_cast<short8*>(Apack + (size_t)s*8) = v;
}

// ---------------- K7: MFMA bf16 GEMM, A+B prefetched in consume order ----------------
__global__ __launch_bounds__(512) void k_big(
    const short* __restrict__ Apack, const float* __restrict__ Wm,
    const float* __restrict__ bias, const int* __restrict__ targets,
    float* __restrict__ psum, float* __restrict__ tlogit)
{
    __shared__ float pv_l[192][4];

    int bm = blockIdx.x;            // 0..1  (192-row chunk)
    int nvb = blockIdx.y;           // 0..390
    int bn = nvb * 128;
    int t = threadIdx.x;
    int wid = t >> 6, lane = t & 63;
    int wave_m = wid >> 2;          // 0..1
    int wave_n = wid & 3;           // 0..3

    int colB = bn + wave_n*32 + (lane & 31);
    int kOff = (lane >> 5) << 3;    // 0 or 8
    bool colOK = colB < VV;
    int mt0 = bm*6 + wave_m*3;

    const short8* ap = reinterpret_cast<const short8*>(Apack);

    floatx16 acc[3];
    #pragma unroll
    for (int mi = 0; mi < 3; ++mi)
        #pragma unroll
        for (int r = 0; r < 16; ++r) acc[mi][r] = 0.f;

    float Bq0a[8], Bq1a[8], Bq0b[8], Bq1b[8];
    short8 Fa[6], Fb[6];

#define LOADB(Q0, Q1, kst) do { \
    int kb_ = (kst)*32 + kOff; \
    _Pragma("unroll") \
    for (int j = 0; j < 8; ++j) Q0[j] = colOK ? Wm[(size_t)(kb_ + j)*VV + colB] : 0.f; \
    _Pragma("unroll") \
    for (int j = 0; j < 8; ++j) Q1[j] = colOK ? Wm[(size_t)(kb_ + 16 + j)*VV + colB] : 0.f; \
} while (0)

#define LOADA(F, kst) do { \
    _Pragma("unroll") \
    for (int mi = 0; mi < 3; ++mi) { \
        F[mi]   = ap[(size_t)(((kst)*12 + (mt0 + mi))*2 + 0)*64 + lane]; \
        F[3+mi] = ap[(size_t)(((kst)*12 + (mt0 + mi))*2 + 1)*64 + lane]; \
    } \
} while (0)

#define STEP(Q0, Q1, F) do { \
    short8 b0_, b1_; \
    _Pragma("unroll") \
    for (int j = 0; j < 8; ++j) { b0_[j] = f2bf(Q0[j]); b1_[j] = f2bf(Q1[j]); } \
    _Pragma("unroll") \
    for (int mi = 0; mi < 3; ++mi) \
        acc[mi] = __builtin_amdgcn_mfma_f32_32x32x16_bf16(F[mi], b0_, acc[mi], 0, 0, 0); \
    _Pragma("unroll") \
    for (int mi = 0; mi < 3; ++mi) \
        acc[mi] = __builtin_amdgcn_mfma_f32_32x32x16_bf16(F[3+mi], b1_, acc[mi], 0, 0, 0); \
} while (0)

    LOADB(Bq0a, Bq1a, 0); LOADA(Fa, 0);
    LOADB(Bq0b, Bq1b, 1); LOADA(Fb, 1);

    for (int k = 0; k < KSTEPS; k += 2) {
        STEP(Bq0a, Bq1a, Fa);
        if (k + 2 < KSTEPS) { LOADB(Bq0a, Bq1a, k+2); LOADA(Fa, k+2); }
        STEP(Bq0b, Bq1b, Fb);
        if (k + 3 < KSTEPS) { LOADB(Bq0b, Bq1b, k+3); LOADA(Fb, k+3); }
    }
#undef LOADB
#undef LOADA
#undef STEP

    float bias_v = colOK ? bias[colB] : 0.f;
    int rsub = 4*(lane >> 5);
    #pragma unroll
    for (int mi = 0; mi < 3; ++mi) {
        #pragma unroll
        for (int r = 0; r < 16; ++r) {
            int row_l = wave_m*96 + mi*32 + rsub + (r & 3) + 8*(r >> 2);
            int rowg = bm*192 + row_l;
            float logit = acc[mi][r] + bias_v;
            if (colOK && colB == targets[rowg]) tlogit[rowg] = logit;
            float e = colOK ? expf(logit) : 0.f;
            #pragma unroll
            for (int msk = 16; msk; msk >>= 1) e += __shfl_xor(e, msk);
            if ((lane & 31) == 0) pv_l[row_l][wave_n] = e;
        }
    }
    __syncthreads();
    if (t < 192) {
        float ss = pv_l[t][0] + pv_l[t][1] + pv_l[t][2] + pv_l[t][3];
        int rowg = bm*192 + t;
        psum[(size_t)rowg*NVB + nvb] = ss;
    }
}

// ---------------- K8: sum partials + per-token nll ----------------
__global__ __launch_bounds__(64) void k_lsum(
    const float* __restrict__ psum,
    const float* __restrict__ tlogit, const int* __restrict__ targets,
    const float* __restrict__ psw, const float* __restrict__ copysc,
    const float* __restrict__ dec_mask, float* __restrict__ nll)
{
    int pair = blockIdx.x, lane = threadIdx.x;
    float s = 0.f;
    for (int j = lane; j < NVB; j += 64) s += psum[(size_t)pair*NVB + j];
    #pragma unroll
    for (int off = 32; off; off >>= 1) s += __shfl_xor(s, off);
    if (lane == 0) {
        int tgt = targets[pair];
        float outv;
        if (tgt == UNK) outv = 1.0f;
        else {
            float base = 0.f;
            if (tgt < VV) {
                float pvv = expf(tlogit[pair]) / s;
                float pg = (tgt < VV - NPR) ? psw[pair*3] : psw[pair*3+1];
                base = pg * pvv;
            }
            outv = base + psw[pair*3+2] * copysc[pair];
        }
        outv = fmaxf(outv, 1e-38f);
        nll[pair] = -logf(outv) * dec_mask[pair];
    }
}

// ---------------- K9: final per-batch loss ----------------
__global__ __launch_bounds__(64) void k_final(
    const float* __restrict__ nll, const float* __restrict__ dec_lens, float* __restrict__ out)
{
    int b = threadIdx.x;
    if (b < BB) {
        float a = 0.f;
        for (int t = 0; t < TT; ++t) a += nll[b*TT + t];
        out[b] = a / dec_lens[b];
    }
}

extern "C" void kernel_launch(void* const* d_in, const int* in_sizes, int n_in,
                              void* d_out, int out_size, void* d_ws, size_t ws_size,
                              hipStream_t stream)
{
    const float* enc_states = (const float*)d_in[0];
    const float* enc_h0     = (const float*)d_in[1];
    const float* enc_c0     = (const float*)d_in[2];
    const unsigned char* enc_mask = (const unsigned char*)d_in[3];
    const int* article_inds = (const int*)d_in[4];
    const int* dec_input    = (const int*)d_in[5];
    const int* targets      = (const int*)d_in[6];
    const float* dec_lens   = (const float*)d_in[7];
    const float* dec_mask   = (const float*)d_in[8];
    const float* embed      = (const float*)d_in[9];
    const float* W_ih       = (const float*)d_in[10];
    const float* W_hh       = (const float*)d_in[11];
    const float* b_lstm     = (const float*)d_in[12];
    const float* Wh_w = (const float*)d_in[13]; const float* Wh_b = (const float*)d_in[14];
    const float* Ws_w = (const float*)d_in[15]; const float* Ws_b = (const float*)d_in[16];
    const float* v_w  = (const float*)d_in[17]; const float* v_b  = (const float*)d_in[18];
    const float* wh_w = (const float*)d_in[19]; const float* wh_b = (const float*)d_in[20];
    const float* ws_w = (const float*)d_in[21]; const float* ws_b = (const float*)d_in[22];
    const float* wx_w = (const float*)d_in[23]; const float* wx_b = (const float*)d_in[24];
    const float* wc_w = (const float*)d_in[25]; const float* wc_b = (const float*)d_in[26];
    const float* Vout_w = (const float*)d_in[27]; const float* Vout_b = (const float*)d_in[28];

    float* ws = (float*)d_ws;
    float* x_buf   = ws + OFF_X;
    float* hid     = ws + OFF_HID;
    float* encp    = ws + OFF_ENCP;
    float* decp    = ws + OFF_DECP;
    float* attn    = ws + OFF_ATTN;
    float* s_buf   = ws + OFF_S;
    float* psw     = ws + OFF_PSW;
    float* copysc  = ws + OFF_COPY;
    float* tlogit  = ws + OFF_TLOGIT;
    float* psum    = ws + OFF_PSUM;
    float* nll     = ws + OFF_NLL;
    short* apack   = (short*)(ws + OFF_APACK);
    float* xw      = ws + OFF_XW;
    short* whhp    = (short*)(ws + OFF_WHH);
    float* out     = (float*)d_out;

    // 1a. embedding lookup (x_buf also feeds k_switch_copy)
    k_embed<<<dim3(BT*EE/4/256), dim3(256), 0, stream>>>(embed, dec_input, x_buf);
    // 1b. xw = x @ W_ih + b_lstm   [384,1024]
    k_gemm_bias<<<dim3(BT/64, H4/128), dim3(256), 0, stream>>>(x_buf, W_ih, b_lstm, xw, H4, EE);
    // 1c. pack W_hh -> bf16 B-frag order
    k_whh_pack<<<dim3(HH*H4/8/256), dim3(256), 0, stream>>>(W_hh, whhp);
    // 1d. batched MFMA LSTM (one block)
    k_lstm2<<<dim3(1), dim3(1024), 0, stream>>>(xw, whhp, enc_h0, enc_c0, hid);
    // 2. enc_proj = enc_states @ Wh_w + Wh_b   [9600,512]
    k_gemm_bias<<<dim3(BB*LL/64, H2/128), dim3(256), 0, stream>>>(enc_states, Wh_w, Wh_b, encp, H2, H2);
    // 3. dec_proj = hidden @ Ws_w + Ws_b       [384,512]
    k_gemm_bias<<<dim3(BT/64, H2/128), dim3(256), 0, stream>>>(hid, Ws_w, Ws_b, decp, H2, HH);
    // 4. e scores
    k_e<<<dim3(BB, LL/4), dim3(256), 0, stream>>>(encp, decp, v_w, v_b, enc_mask, attn);
    // 5. softmax + context + s
    k_softmax_ctx<<<dim3(BT), dim3(256), 0, stream>>>(attn, enc_states, hid, s_buf);
    // 6. switch + copy score
    k_switch_copy<<<dim3(BT), dim3(64), 0, stream>>>(s_buf, x_buf, enc_h0,
        wh_w, wh_b, ws_w, ws_b, wx_w, wx_b, wc_w, wc_b,
        article_inds, targets, attn, psw, copysc);
    // 6.5 pack A into fragment-ordered bf16
    k_pack<<<dim3(BT*H3/(8*256)), dim3(256), 0, stream>>>(s_buf, apack);
    // 7. big MFMA GEMM + exp partials
    k_big<<<dim3(2, NVB), dim3(512), 0, stream>>>(apack, Vout_w, Vout_b, targets, psum, tlogit);
    // 8. merge + nll
    k_lsum<<<dim3(BT), dim3(64), 0, stream>>>(psum, tlogit, targets, psw, copysc, dec_mask, nll);
    // 9. final loss
    k_final<<<dim3(1), dim3(64), 0, stream>>>(nll, dec_lens, out);
}

// Round 10
// 640.427 us; speedup vs baseline: 1.1235x; 1.1235x over previous
//
#include <hip/hip_runtime.h>
#include <hip/hip_bf16.h>
#include <math.h>

// Problem constants
#define BB 32
#define LL 300
#define TT 12
#define HH 256
#define EE 128
#define VV 50000
#define OOV 30
#define NPR 6
#define UNK 1
#define H2 512   // 2H
#define H3 768   // 3H
#define H4 1024  // 4H
#define BT (BB*TT)       // 384
#define NVB 391          // ceil(50000/128)
#define KSTEPS 24        // 768/32

// ---------------- ws layout (float offsets) ----------------
#define OFF_X        0                          // BT*EE
#define OFF_HID      (OFF_X + BT*EE)            // BT*HH
#define OFF_ENCP     (OFF_HID + BT*HH)          // BB*LL*H2
#define OFF_DECP     (OFF_ENCP + BB*LL*H2)      // BT*H2
#define OFF_ATTN     (OFF_DECP + BT*H2)         // BT*LL
#define OFF_S        (OFF_ATTN + BT*LL)         // BT*H3
#define OFF_PSW      (OFF_S + BT*H3)            // BT*3
#define OFF_COPY     (OFF_PSW + BT*3)           // BT
#define OFF_TLOGIT   (OFF_COPY + BT)            // BT
#define OFF_PMAX     (OFF_TLOGIT + BT)          // BT*NVB (unused)
#define OFF_PSUM     (OFF_PMAX + BT*NVB)        // BT*NVB
#define OFF_NLL      (OFF_PSUM + BT*NVB)        // BT
#define OFF_APACK    (OFF_NLL + BT)             // BT*H3 shorts = BT*H3/2 floats
#define OFF_XW       (OFF_APACK + BT*H3/2)      // BT*H4 floats (x@W_ih + b)
#define OFF_WHH      (OFF_XW + BT*H4)           // HH*H4 shorts = HH*H4/2 floats

typedef __attribute__((ext_vector_type(8))) short short8;
typedef __attribute__((ext_vector_type(4))) float floatx4;
typedef __attribute__((ext_vector_type(16))) float floatx16;

__device__ __forceinline__ short f2bf(float f) {
    __hip_bfloat16 h = __float2bfloat16(f);
    return *reinterpret_cast<short*>(&h);
}
__device__ __forceinline__ float sigm(float x) { return 1.f/(1.f + expf(-x)); }

// ---------------- K0: embedding lookup ----------------
__global__ __launch_bounds__(256) void k_embed(
    const float* __restrict__ embed, const int* __restrict__ dec_input,
    float* __restrict__ x_out)
{
    int i = blockIdx.x*256 + threadIdx.x;      // one float4 per thread, BT*EE/4
    int bt = i >> 5;                           // EE/4 = 32 float4 per row
    int e4 = i & 31;
    int tok = dec_input[bt];
    reinterpret_cast<float4*>(x_out)[(size_t)bt*32 + e4] =
        reinterpret_cast<const float4*>(embed)[(size_t)tok*32 + e4];
}

// ---------------- K0b: W_hh [256][1024] fp32 -> bf16 16x16x32 B-frag order ----
// slot s = (ct*8 + kstep)*64 + l ; 8 shorts each:
//   value j = W_hh[kstep*32 + (l>>4)*8 + j][ct*16 + (l&15)]
__global__ __launch_bounds__(256) void k_whh_pack(
    const float* __restrict__ Whh, short* __restrict__ wp)
{
    int s = blockIdx.x*256 + threadIdx.x;      // 0..32767
    int l = s & 63;
    int kstep = (s >> 6) & 7;
    int ct = s >> 9;                           // 0..63
    int kb = kstep*32 + ((l >> 4) << 3);
    int c = ct*16 + (l & 15);
    short8 v;
    #pragma unroll
    for (int j = 0; j < 8; ++j) v[j] = f2bf(Whh[(size_t)(kb + j)*H4 + c]);
    *reinterpret_cast<short8*>(wp + (size_t)s*8) = v;
}

// ---------------- generic fp32 GEMM + bias ----------------
__global__ __launch_bounds__(256) void k_gemm_bias(
    const float* __restrict__ A, const float* __restrict__ Wm,
    const float* __restrict__ bias, float* __restrict__ C, int N_, int K_)
{
    __shared__ float As[64][17];
    __shared__ __align__(16) float Bs[16][128];
    int bm = blockIdx.x*64, bn = blockIdx.y*128;
    int tid = threadIdx.x, tr = tid >> 4, tc = tid & 15;
    float acc[4][8] = {};
    for (int k0 = 0; k0 < K_; k0 += 16) {
        for (int i = tid; i < 64*16; i += 256) { int r = i >> 4, c = i & 15; As[r][c] = A[(size_t)(bm+r)*K_ + k0 + c]; }
        for (int i = tid; i < 16*128; i += 256) { int r = i >> 7, c = i & 127; Bs[r][c] = Wm[(size_t)(k0+r)*N_ + bn + c]; }
        __syncthreads();
        #pragma unroll
        for (int kk = 0; kk < 16; ++kk) {
            float a0 = As[tr*4+0][kk], a1 = As[tr*4+1][kk], a2 = As[tr*4+2][kk], a3 = As[tr*4+3][kk];
            const float4* bp = reinterpret_cast<const float4*>(&Bs[kk][tc*8]);
            float4 q0 = bp[0], q1 = bp[1];
            float bb[8] = {q0.x,q0.y,q0.z,q0.w,q1.x,q1.y,q1.z,q1.w};
            #pragma unroll
            for (int j = 0; j < 8; ++j) {
                acc[0][j] += a0*bb[j]; acc[1][j] += a1*bb[j];
                acc[2][j] += a2*bb[j]; acc[3][j] += a3*bb[j];
            }
        }
        __syncthreads();
    }
    for (int i = 0; i < 4; ++i) {
        int r = bm + tr*4 + i;
        for (int j = 0; j < 8; ++j) {
            int c = bn + tc*8 + j;
            C[(size_t)r*N_ + c] = acc[i][j] + bias[c];
        }
    }
}

// ---------------- K1: batch-split MFMA LSTM: 4 blocks x 8 batch rows ----------------
// Per step per block: [8(pad16) x 256] @ [256 x 1024] via 8 waves x 8 col-tiles
// x 8 K-steps of mfma_f32_16x16x32_bf16. h in LDS in A-frag bf16 layout
// (rows 8..15 zero), gates in fp32 LDS, c fp32 LDS. Blocks are independent
// (batch rows don't interact) -> no cross-block sync.
__global__ __launch_bounds__(512) void k_lstm3(
    const float* __restrict__ xw, const short* __restrict__ whhp,
    const float* __restrict__ h0, const float* __restrict__ c0,
    float* __restrict__ hid_out)
{
    __shared__ short hfrag[8*64*8];    // slot (kstep*64 + l)*8 + j : 8 KB
    __shared__ float c_lds[8][HH];     // 8 KB
    __shared__ float g_lds[8][H4];     // 32 KB
    int tid = threadIdx.x, wid = tid >> 6, lane = tid & 63;
    int bgrp = blockIdx.x;             // 0..3 -> batch rows bgrp*8 .. +7

    // init: h0 -> hfrag rows 0..7 (A-frag layout: l = ((j&31)>>3)*16 + row,
    // kstep = j>>5, elem = j&7), zeros rows 8..15; c0 -> c_lds
    for (int i = tid; i < 8*HH; i += 512) {
        int r = i >> 8, j = i & 255;
        int b = bgrp*8 + r;
        hfrag[((j >> 5)*64 + ((j & 31) >> 3)*16 + r)*8 + (j & 7)] = f2bf(h0[b*HH + j]);
        hfrag[((j >> 5)*64 + ((j & 31) >> 3)*16 + (r + 8))*8 + (j & 7)] = 0;
        c_lds[r][j] = c0[b*HH + j];
    }
    __syncthreads();

    const short8* wp = reinterpret_cast<const short8*>(whhp);
    int colbase = lane & 15;
    int rowq = lane >> 4;              // 0..3

    for (int t = 0; t < TT; ++t) {
        floatx4 acc[8];
        #pragma unroll
        for (int c8 = 0; c8 < 8; ++c8)
            #pragma unroll
            for (int r = 0; r < 4; ++r) acc[c8][r] = 0.f;

        #pragma unroll
        for (int kstep = 0; kstep < 8; ++kstep) {
            short8 af = *reinterpret_cast<const short8*>(&hfrag[(kstep*64 + lane)*8]);
            #pragma unroll
            for (int c8 = 0; c8 < 8; ++c8) {
                int ct = wid*8 + c8;
                short8 bf = wp[(size_t)(ct*8 + kstep)*64 + lane];
                acc[c8] = __builtin_amdgcn_mfma_f32_16x16x32_bf16(af, bf, acc[c8], 0, 0, 0);
            }
        }
        // epilogue: g = acc + xw -> g_lds fp32. C/D: col=lane&15, row=rowq*4+reg
        #pragma unroll
        for (int c8 = 0; c8 < 8; ++c8) {
            int col = (wid*8 + c8)*16 + colbase;
            #pragma unroll
            for (int reg = 0; reg < 4; ++reg) {
                int row = rowq*4 + reg;
                if (row < 8) {
                    int b = bgrp*8 + row;
                    g_lds[row][col] = acc[c8][reg] + xw[(size_t)(b*TT + t)*H4 + col];
                }
            }
        }
        __syncthreads();
        // update: thread -> col j, 4 rows
        int j = tid & 255, rq = tid >> 8;   // rq 0/1
        #pragma unroll
        for (int rr = 0; rr < 4; ++rr) {
            int r = rq*4 + rr;
            float gi = g_lds[r][j];
            float gf = g_lds[r][HH + j];
            float gg = g_lds[r][2*HH + j];
            float go = g_lds[r][3*HH + j];
            float c = sigm(gf)*c_lds[r][j] + sigm(gi)*tanhf(gg);
            float h = sigm(go)*tanhf(c);
            c_lds[r][j] = c;
            hfrag[((j >> 5)*64 + ((j & 31) >> 3)*16 + r)*8 + (j & 7)] = f2bf(h);
            hid_out[(size_t)((bgrp*8 + r)*TT + t)*HH + j] = h;
        }
        __syncthreads();
    }
}

// ---------------- K4: e[b,t,l] = v·tanh(enc_proj[b,l]+dec_proj[b,t]) + v_b ----------------
__global__ __launch_bounds__(256) void k_e(
    const float* __restrict__ enc_proj, const float* __restrict__ dec_proj,
    const float* __restrict__ v_w, const float* __restrict__ v_b,
    const unsigned char* __restrict__ enc_mask, float* __restrict__ e_out)
{
    int b = blockIdx.x, lbase = blockIdx.y*4;
    __shared__ float decp[TT*H2];
    int tid = threadIdx.x;
    for (int i = tid; i < TT*H2; i += 256) decp[i] = dec_proj[(size_t)b*TT*H2 + i];
    __syncthreads();
    int wave = tid >> 6, lane = tid & 63;
    int l = lbase + wave;
    const float* er = &enc_proj[(size_t)(b*LL + l)*H2];
    float ep[8], vw[8];
    #pragma unroll
    for (int k = 0; k < 8; ++k) { int e = lane + 64*k; ep[k] = er[e]; vw[k] = v_w[e]; }
    float vb = v_b[0];
    bool masked = enc_mask[b*LL + l] != 0;
    for (int t = 0; t < TT; ++t) {
        float acc = 0.f;
        #pragma unroll
        for (int k = 0; k < 8; ++k) {
            int e = lane + 64*k;
            acc += vw[k] * tanhf(ep[k] + decp[t*H2 + e]);
        }
        #pragma unroll
        for (int off = 32; off; off >>= 1) acc += __shfl_xor(acc, off);
        if (lane == 0)
            e_out[(size_t)(b*TT + t)*LL + l] = masked ? -INFINITY : (acc + vb);
    }
}

// ---------------- K5: softmax over L + context + build s=[hidden,context] ----------------
__global__ __launch_bounds__(256) void k_softmax_ctx(
    float* __restrict__ attn, const float* __restrict__ enc_states,
    const float* __restrict__ hidden, float* __restrict__ s_out)
{
    int bt = blockIdx.x, b = bt / TT, tid = threadIdx.x;
    __shared__ float a[LL];
    __shared__ float red[256];
    float m = -INFINITY;
    for (int l = tid; l < LL; l += 256) m = fmaxf(m, attn[(size_t)bt*LL + l]);
    red[tid] = m; __syncthreads();
    for (int s = 128; s; s >>= 1) { if (tid < s) red[tid] = fmaxf(red[tid], red[tid+s]); __syncthreads(); }
    m = red[0]; __syncthreads();
    float sum = 0.f;
    for (int l = tid; l < LL; l += 256) { float w = expf(attn[(size_t)bt*LL + l] - m); a[l] = w; sum += w; }
    red[tid] = sum; __syncthreads();
    for (int s = 128; s; s >>= 1) { if (tid < s) red[tid] += red[tid+s]; __syncthreads(); }
    float inv = 1.0f / red[0];
    __syncthreads();
    for (int l = tid; l < LL; l += 256) { float w = a[l]*inv; a[l] = w; attn[(size_t)bt*LL + l] = w; }
    __syncthreads();
    for (int c = tid; c < H2; c += 256) {
        float acc = 0.f;
        const float* es = &enc_states[(size_t)b*LL*H2 + c];
        for (int l = 0; l < LL; ++l) acc += a[l] * es[(size_t)l*H2];
        s_out[(size_t)bt*H3 + HH + c] = acc;
    }
    for (int c = tid; c < HH; c += 256) s_out[(size_t)bt*H3 + c] = hidden[(size_t)bt*HH + c];
}

// ---------------- K6: switch softmax + copy score ----------------
__global__ __launch_bounds__(64) void k_switch_copy(
    const float* __restrict__ s, const float* __restrict__ x,
    const float* __restrict__ enc_h0,
    const float* __restrict__ wh_w, const float* __restrict__ wh_b,
    const float* __restrict__ ws_w, const float* __restrict__ ws_b,
    const float* __restrict__ wx_w, const float* __restrict__ wx_b,
    const float* __restrict__ wc_w, const float* __restrict__ wc_b,
    const int* __restrict__ article_inds, const int* __restrict__ targets,
    const float* __restrict__ attn, float* __restrict__ psw, float* __restrict__ copysc)
{
    int bt = blockIdx.x, b = bt / TT, lane = threadIdx.x;
    float s0 = 0.f, s1 = 0.f, s2 = 0.f;
    const float* ctx = &s[(size_t)bt*H3 + HH];
    const float* hid = &s[(size_t)bt*H3];
    for (int k = lane; k < H2; k += 64) { float v = ctx[k]; s0 += v*wh_w[k*3]; s1 += v*wh_w[k*3+1]; s2 += v*wh_w[k*3+2]; }
    for (int k = lane; k < HH; k += 64) { float v = hid[k]; s0 += v*ws_w[k*3]; s1 += v*ws_w[k*3+1]; s2 += v*ws_w[k*3+2]; }
    for (int k = lane; k < EE; k += 64) { float v = x[(size_t)bt*EE + k]; s0 += v*wx_w[k*3]; s1 += v*wx_w[k*3+1]; s2 += v*wx_w[k*3+2]; }
    for (int k = lane; k < HH; k += 64) { float v = enc_h0[b*HH + k]; s0 += v*wc_w[k*3]; s1 += v*wc_w[k*3+1]; s2 += v*wc_w[k*3+2]; }
    #pragma unroll
    for (int off = 32; off; off >>= 1) {
        s0 += __shfl_xor(s0, off); s1 += __shfl_xor(s1, off); s2 += __shfl_xor(s2, off);
    }
    if (lane == 0) {
        s0 += wh_b[0] + ws_b[0] + wx_b[0] + wc_b[0];
        s1 += wh_b[1] + ws_b[1] + wx_b[1] + wc_b[1];
        s2 += wh_b[2] + ws_b[2] + wx_b[2] + wc_b[2];
        float mm = fmaxf(s0, fmaxf(s1, s2));
        float e0 = expf(s0-mm), e1 = expf(s1-mm), e2 = expf(s2-mm);
        float inv = 1.f/(e0+e1+e2);
        psw[bt*3+0] = e0*inv; psw[bt*3+1] = e1*inv; psw[bt*3+2] = e2*inv;
    }
    int tgt = targets[bt];
    float cs = 0.f;
    for (int l = lane; l < LL; l += 64)
        if (article_inds[b*LL + l] == tgt) cs += attn[(size_t)bt*LL + l];
    #pragma unroll
    for (int off = 32; off; off >>= 1) cs += __shfl_xor(cs, off);
    if (lane == 0) copysc[bt] = cs;
}

// ---------------- K_pack: s_buf [384][768] fp32 -> fragment-ordered bf16 ----------------
__global__ __launch_bounds__(256) void k_pack(
    const float* __restrict__ A, short* __restrict__ Apack)
{
    int s = blockIdx.x*256 + threadIdx.x;          // 0 .. 36863
    int l = s & 63;
    int ks = (s >> 6) & 1;
    int rest = s >> 7;
    int mt = rest % 12;
    int kstep = rest / 12;
    int row = mt*32 + (l & 31);
    int kb = kstep*32 + ks*16 + ((l >> 5) << 3);
    const float4* src = reinterpret_cast<const float4*>(&A[(size_t)row*H3 + kb]);
    float4 a = src[0], b = src[1];
    short8 v;
    v[0]=f2bf(a.x); v[1]=f2bf(a.y); v[2]=f2bf(a.z); v[3]=f2bf(a.w);
    v[4]=f2bf(b.x); v[5]=f2bf(b.y); v[6]=f2bf(b.z); v[7]=f2bf(b.w);
    *reinterpret_cast<short8*>(Apack + (size_t)s*8) = v;
}

// ---------------- K7: MFMA bf16 GEMM, A+B prefetched in consume order ----------------
__global__ __launch_bounds__(512) void k_big(
    const short* __restrict__ Apack, const float* __restrict__ Wm,
    const float* __restrict__ bias, const int* __restrict__ targets,
    float* __restrict__ psum, float* __restrict__ tlogit)
{
    __shared__ float pv_l[192][4];

    int bm = blockIdx.x;            // 0..1  (192-row chunk)
    int nvb = blockIdx.y;           // 0..390
    int bn = nvb * 128;
    int t = threadIdx.x;
    int wid = t >> 6, lane = t & 63;
    int wave_m = wid >> 2;          // 0..1
    int wave_n = wid & 3;           // 0..3

    int colB = bn + wave_n*32 + (lane & 31);
    int kOff = (lane >> 5) << 3;    // 0 or 8
    bool colOK = colB < VV;
    int mt0 = bm*6 + wave_m*3;

    const short8* ap = reinterpret_cast<const short8*>(Apack);

    floatx16 acc[3];
    #pragma unroll
    for (int mi = 0; mi < 3; ++mi)
        #pragma unroll
        for (int r = 0; r < 16; ++r) acc[mi][r] = 0.f;

    float Bq0a[8], Bq1a[8], Bq0b[8], Bq1b[8];
    short8 Fa[6], Fb[6];

#define LOADB(Q0, Q1, kst) do { \
    int kb_ = (kst)*32 + kOff; \
    _Pragma("unroll") \
    for (int j = 0; j < 8; ++j) Q0[j] = colOK ? Wm[(size_t)(kb_ + j)*VV + colB] : 0.f; \
    _Pragma("unroll") \
    for (int j = 0; j < 8; ++j) Q1[j] = colOK ? Wm[(size_t)(kb_ + 16 + j)*VV + colB] : 0.f; \
} while (0)

#define LOADA(F, kst) do { \
    _Pragma("unroll") \
    for (int mi = 0; mi < 3; ++mi) { \
        F[mi]   = ap[(size_t)(((kst)*12 + (mt0 + mi))*2 + 0)*64 + lane]; \
        F[3+mi] = ap[(size_t)(((kst)*12 + (mt0 + mi))*2 + 1)*64 + lane]; \
    } \
} while (0)

#define STEP(Q0, Q1, F) do { \
    short8 b0_, b1_; \
    _Pragma("unroll") \
    for (int j = 0; j < 8; ++j) { b0_[j] = f2bf(Q0[j]); b1_[j] = f2bf(Q1[j]); } \
    _Pragma("unroll") \
    for (int mi = 0; mi < 3; ++mi) \
        acc[mi] = __builtin_amdgcn_mfma_f32_32x32x16_bf16(F[mi], b0_, acc[mi], 0, 0, 0); \
    _Pragma("unroll") \
    for (int mi = 0; mi < 3; ++mi) \
        acc[mi] = __builtin_amdgcn_mfma_f32_32x32x16_bf16(F[3+mi], b1_, acc[mi], 0, 0, 0); \
} while (0)

    LOADB(Bq0a, Bq1a, 0); LOADA(Fa, 0);
    LOADB(Bq0b, Bq1b, 1); LOADA(Fb, 1);

    for (int k = 0; k < KSTEPS; k += 2) {
        STEP(Bq0a, Bq1a, Fa);
        if (k + 2 < KSTEPS) { LOADB(Bq0a, Bq1a, k+2); LOADA(Fa, k+2); }
        STEP(Bq0b, Bq1b, Fb);
        if (k + 3 < KSTEPS) { LOADB(Bq0b, Bq1b, k+3); LOADA(Fb, k+3); }
    }
#undef LOADB
#undef LOADA
#undef STEP

    float bias_v = colOK ? bias[colB] : 0.f;
    int rsub = 4*(lane >> 5);
    #pragma unroll
    for (int mi = 0; mi < 3; ++mi) {
        #pragma unroll
        for (int r = 0; r < 16; ++r) {
            int row_l = wave_m*96 + mi*32 + rsub + (r & 3) + 8*(r >> 2);
            int rowg = bm*192 + row_l;
            float logit = acc[mi][r] + bias_v;
            if (colOK && colB == targets[rowg]) tlogit[rowg] = logit;
            float e = colOK ? expf(logit) : 0.f;
            #pragma unroll
            for (int msk = 16; msk; msk >>= 1) e += __shfl_xor(e, msk);
            if ((lane & 31) == 0) pv_l[row_l][wave_n] = e;
        }
    }
    __syncthreads();
    if (t < 192) {
        float ss = pv_l[t][0] + pv_l[t][1] + pv_l[t][2] + pv_l[t][3];
        int rowg = bm*192 + t;
        psum[(size_t)rowg*NVB + nvb] = ss;
    }
}

// ---------------- K8: sum partials + per-token nll ----------------
__global__ __launch_bounds__(64) void k_lsum(
    const float* __restrict__ psum,
    const float* __restrict__ tlogit, const int* __restrict__ targets,
    const float* __restrict__ psw, const float* __restrict__ copysc,
    const float* __restrict__ dec_mask, float* __restrict__ nll)
{
    int pair = blockIdx.x, lane = threadIdx.x;
    float s = 0.f;
    for (int j = lane; j < NVB; j += 64) s += psum[(size_t)pair*NVB + j];
    #pragma unroll
    for (int off = 32; off; off >>= 1) s += __shfl_xor(s, off);
    if (lane == 0) {
        int tgt = targets[pair];
        float outv;
        if (tgt == UNK) outv = 1.0f;
        else {
            float base = 0.f;
            if (tgt < VV) {
                float pvv = expf(tlogit[pair]) / s;
                float pg = (tgt < VV - NPR) ? psw[pair*3] : psw[pair*3+1];
                base = pg * pvv;
            }
            outv = base + psw[pair*3+2] * copysc[pair];
        }
        outv = fmaxf(outv, 1e-38f);
        nll[pair] = -logf(outv) * dec_mask[pair];
    }
}

// ---------------- K9: final per-batch loss ----------------
__global__ __launch_bounds__(64) void k_final(
    const float* __restrict__ nll, const float* __restrict__ dec_lens, float* __restrict__ out)
{
    int b = threadIdx.x;
    if (b < BB) {
        float a = 0.f;
        for (int t = 0; t < TT; ++t) a += nll[b*TT + t];
        out[b] = a / dec_lens[b];
    }
}

extern "C" void kernel_launch(void* const* d_in, const int* in_sizes, int n_in,
                              void* d_out, int out_size, void* d_ws, size_t ws_size,
                              hipStream_t stream)
{
    const float* enc_states = (const float*)d_in[0];
    const float* enc_h0     = (const float*)d_in[1];
    const float* enc_c0     = (const float*)d_in[2];
    const unsigned char* enc_mask = (const unsigned char*)d_in[3];
    const int* article_inds = (const int*)d_in[4];
    const int* dec_input    = (const int*)d_in[5];
    const int* targets      = (const int*)d_in[6];
    const float* dec_lens   = (const float*)d_in[7];
    const float* dec_mask   = (const float*)d_in[8];
    const float* embed      = (const float*)d_in[9];
    const float* W_ih       = (const float*)d_in[10];
    const float* W_hh       = (const float*)d_in[11];
    const float* b_lstm     = (const float*)d_in[12];
    const float* Wh_w = (const float*)d_in[13]; const float* Wh_b = (const float*)d_in[14];
    const float* Ws_w = (const float*)d_in[15]; const float* Ws_b = (const float*)d_in[16];
    const float* v_w  = (const float*)d_in[17]; const float* v_b  = (const float*)d_in[18];
    const float* wh_w = (const float*)d_in[19]; const float* wh_b = (const float*)d_in[20];
    const float* ws_w = (const float*)d_in[21]; const float* ws_b = (const float*)d_in[22];
    const float* wx_w = (const float*)d_in[23]; const float* wx_b = (const float*)d_in[24];
    const float* wc_w = (const float*)d_in[25]; const float* wc_b = (const float*)d_in[26];
    const float* Vout_w = (const float*)d_in[27]; const float* Vout_b = (const float*)d_in[28];

    float* ws = (float*)d_ws;
    float* x_buf   = ws + OFF_X;
    float* hid     = ws + OFF_HID;
    float* encp    = ws + OFF_ENCP;
    float* decp    = ws + OFF_DECP;
    float* attn    = ws + OFF_ATTN;
    float* s_buf   = ws + OFF_S;
    float* psw     = ws + OFF_PSW;
    float* copysc  = ws + OFF_COPY;
    float* tlogit  = ws + OFF_TLOGIT;
    float* psum    = ws + OFF_PSUM;
    float* nll     = ws + OFF_NLL;
    short* apack   = (short*)(ws + OFF_APACK);
    float* xw      = ws + OFF_XW;
    short* whhp    = (short*)(ws + OFF_WHH);
    float* out     = (float*)d_out;

    // 1a. embedding lookup (x_buf also feeds k_switch_copy)
    k_embed<<<dim3(BT*EE/4/256), dim3(256), 0, stream>>>(embed, dec_input, x_buf);
    // 1b. xw = x @ W_ih + b_lstm   [384,1024]
    k_gemm_bias<<<dim3(BT/64, H4/128), dim3(256), 0, stream>>>(x_buf, W_ih, b_lstm, xw, H4, EE);
    // 1c. pack W_hh -> bf16 16x16x32 B-frag order
    k_whh_pack<<<dim3(HH*H4/8/256), dim3(256), 0, stream>>>(W_hh, whhp);
    // 1d. batch-split MFMA LSTM (4 independent blocks x 8 rows)
    k_lstm3<<<dim3(4), dim3(512), 0, stream>>>(xw, whhp, enc_h0, enc_c0, hid);
    // 2. enc_proj = enc_states @ Wh_w + Wh_b   [9600,512]
    k_gemm_bias<<<dim3(BB*LL/64, H2/128), dim3(256), 0, stream>>>(enc_states, Wh_w, Wh_b, encp, H2, H2);
    // 3. dec_proj = hidden @ Ws_w + Ws_b       [384,512]
    k_gemm_bias<<<dim3(BT/64, H2/128), dim3(256), 0, stream>>>(hid, Ws_w, Ws_b, decp, H2, HH);
    // 4. e scores
    k_e<<<dim3(BB, LL/4), dim3(256), 0, stream>>>(encp, decp, v_w, v_b, enc_mask, attn);
    // 5. softmax + context + s
    k_softmax_ctx<<<dim3(BT), dim3(256), 0, stream>>>(attn, enc_states, hid, s_buf);
    // 6. switch + copy score
    k_switch_copy<<<dim3(BT), dim3(64), 0, stream>>>(s_buf, x_buf, enc_h0,
        wh_w, wh_b, ws_w, ws_b, wx_w, wx_b, wc_w, wc_b,
        article_inds, targets, attn, psw, copysc);
    // 6.5 pack A into fragment-ordered bf16
    k_pack<<<dim3(BT*H3/(8*256)), dim3(256), 0, stream>>>(s_buf, apack);
    // 7. big MFMA GEMM + exp partials
    k_big<<<dim3(2, NVB), dim3(512), 0, stream>>>(apack, Vout_w, Vout_b, targets, psum, tlogit);
    // 8. merge + nll
    k_lsum<<<dim3(BT), dim3(64), 0, stream>>>(psum, tlogit, targets, psw, copysc, dec_mask, nll);
    // 9. final loss
    k_final<<<dim3(1), dim3(64), 0, stream>>>(nll, dec_lens, out);
}

// Round 11
// 544.515 us; speedup vs baseline: 1.3214x; 1.1761x over previous
//
#include <hip/hip_runtime.h>
#include <hip/hip_bf16.h>
#include <math.h>

// Problem constants
#define BB 32
#define LL 300
#define TT 12
#define HH 256
#define EE 128
#define VV 50000
#define OOV 30
#define NPR 6
#define UNK 1
#define H2 512   // 2H
#define H3 768   // 3H
#define H4 1024  // 4H
#define BT (BB*TT)       // 384
#define NVB 391          // ceil(50000/128)
#define KSTEPS 24        // 768/32
#define NT32P (196*8)    // padded 32-col tile count for Bpack (1568)

// ---------------- ws layout (float offsets) ----------------
#define OFF_X        0                          // BT*EE
#define OFF_HID      (OFF_X + BT*EE)            // BT*HH
#define OFF_ENCP     (OFF_HID + BT*HH)          // BB*LL*H2
#define OFF_DECP     (OFF_ENCP + BB*LL*H2)      // BT*H2
#define OFF_ATTN     (OFF_DECP + BT*H2)         // BT*LL
#define OFF_S        (OFF_ATTN + BT*LL)         // BT*H3
#define OFF_PSW      (OFF_S + BT*H3)            // BT*3
#define OFF_COPY     (OFF_PSW + BT*3)           // BT
#define OFF_TLOGIT   (OFF_COPY + BT)            // BT
#define OFF_PMAX     (OFF_TLOGIT + BT)          // BT*NVB (unused)
#define OFF_PSUM     (OFF_PMAX + BT*NVB)        // BT*NVB
#define OFF_NLL      (OFF_PSUM + BT*NVB)        // BT
#define OFF_APACK    (OFF_NLL + BT)             // BT*H3 shorts = BT*H3/2 floats
#define OFF_XW       (OFF_APACK + BT*H3/2)      // BT*H4 floats
#define OFF_WHH      (OFF_XW + BT*H4)           // 4*8192*8 shorts = 131072 floats
#define OFF_HFRAG    (OFF_WHH + 131072)         // 2 x 8192 shorts = 8192 floats
#define OFF_BAR      (OFF_HFRAG + 8192)         // 64 uints
#define OFF_BPACK    (OFF_BAR + 64)             // NT32P*24*2*64*8 shorts
#define BPACK_SHORTS ((size_t)NT32P*24*2*64*8)  // 38,535,168 shorts
#define WS_NEEDED_BYTES ((size_t)(OFF_BPACK)*4 + BPACK_SHORTS*2)

typedef __attribute__((ext_vector_type(8))) short short8;
typedef __attribute__((ext_vector_type(16))) float floatx16;

__device__ __forceinline__ short f2bf(float f) {
    __hip_bfloat16 h = __float2bfloat16(f);
    return *reinterpret_cast<short*>(&h);
}
__device__ __forceinline__ float bf2f(short s) {
    unsigned int u = ((unsigned int)(unsigned short)s) << 16;
    return __uint_as_float(u);
}
__device__ __forceinline__ float sigm(float x) { return 1.f/(1.f + expf(-x)); }

// ---------------- K0: embedding lookup ----------------
__global__ __launch_bounds__(256) void k_embed(
    const float* __restrict__ embed, const int* __restrict__ dec_input,
    float* __restrict__ x_out)
{
    int i = blockIdx.x*256 + threadIdx.x;
    int bt = i >> 5;
    int e4 = i & 31;
    int tok = dec_input[bt];
    reinterpret_cast<float4*>(x_out)[(size_t)bt*32 + e4] =
        reinterpret_cast<const float4*>(embed)[(size_t)tok*32 + e4];
}

// ---------------- K0b: W_hh -> per-block-sliced 32x32x16 B-frag order -------
// slot s = q*8192 + ct_l*1024 + kstep*64 + l ; 8 shorts each:
//   col = (ct_l>>1)*256 + q*64 + (ct_l&1)*32 + (l&31)
//   k   = kstep*16 + (l>>5)*8 + j
__global__ __launch_bounds__(256) void k_whh_pack(
    const float* __restrict__ Whh, short* __restrict__ wp)
{
    int s = blockIdx.x*256 + threadIdx.x;      // 0..32767
    int l = s & 63;
    int kstep = (s >> 6) & 15;
    int ct_l = (s >> 10) & 7;
    int q = s >> 13;
    int col = (ct_l >> 1)*256 + q*64 + (ct_l & 1)*32 + (l & 31);
    int kb = kstep*16 + ((l >> 5) << 3);
    short8 v;
    #pragma unroll
    for (int j = 0; j < 8; ++j) v[j] = f2bf(Whh[(size_t)(kb + j)*H4 + col]);
    *reinterpret_cast<short8*>(wp + (size_t)s*8) = v;
}

// ---------------- K0c: init h0 -> hfrag buf0 (A-frag layout) + zero bars ----
__global__ __launch_bounds__(256) void k_init(
    const float* __restrict__ h0, short* __restrict__ hbuf0,
    unsigned int* __restrict__ bar)
{
    int gid = blockIdx.x*256 + threadIdx.x;    // 0..8191
    int r = gid >> 8;                          // batch row
    int hidx = gid & 255;
    int kstep = hidx >> 4;
    int kk = hidx & 15;
    int l = ((kk >> 3) << 5) + r;
    hbuf0[(size_t)(kstep*64 + l)*8 + (kk & 7)] = f2bf(h0[r*HH + hidx]);
    if (blockIdx.x == 0 && threadIdx.x < 64) bar[threadIdx.x] = 0u;
}

// ---------------- generic fp32 GEMM + bias ----------------
__global__ __launch_bounds__(256) void k_gemm_bias(
    const float* __restrict__ A, const float* __restrict__ Wm,
    const float* __restrict__ bias, float* __restrict__ C, int N_, int K_)
{
    __shared__ float As[64][17];
    __shared__ __align__(16) float Bs[16][128];
    int bm = blockIdx.x*64, bn = blockIdx.y*128;
    int tid = threadIdx.x, tr = tid >> 4, tc = tid & 15;
    float acc[4][8] = {};
    for (int k0 = 0; k0 < K_; k0 += 16) {
        for (int i = tid; i < 64*16; i += 256) { int r = i >> 4, c = i & 15; As[r][c] = A[(size_t)(bm+r)*K_ + k0 + c]; }
        for (int i = tid; i < 16*128; i += 256) { int r = i >> 7, c = i & 127; Bs[r][c] = Wm[(size_t)(k0+r)*N_ + bn + c]; }
        __syncthreads();
        #pragma unroll
        for (int kk = 0; kk < 16; ++kk) {
            float a0 = As[tr*4+0][kk], a1 = As[tr*4+1][kk], a2 = As[tr*4+2][kk], a3 = As[tr*4+3][kk];
            const float4* bp = reinterpret_cast<const float4*>(&Bs[kk][tc*8]);
            float4 q0 = bp[0], q1 = bp[1];
            float bb[8] = {q0.x,q0.y,q0.z,q0.w,q1.x,q1.y,q1.z,q1.w};
            #pragma unroll
            for (int j = 0; j < 8; ++j) {
                acc[0][j] += a0*bb[j]; acc[1][j] += a1*bb[j];
                acc[2][j] += a2*bb[j]; acc[3][j] += a3*bb[j];
            }
        }
        __syncthreads();
    }
    for (int i = 0; i < 4; ++i) {
        int r = bm + tr*4 + i;
        for (int j = 0; j < 8; ++j) {
            int c = bn + tc*8 + j;
            C[(size_t)r*N_ + c] = acc[i][j] + bias[c];
        }
    }
}

// ---------------- K1: column-split MFMA LSTM, 4 blocks, W-slice in LDS ------
// Block q owns hidden [q*64, q*64+64) -> 256 gate cols (8 x 32-col tiles).
// W slice preloaded to LDS once (128 KB). Per step: 8 waves x 1 tile x 16
// ksteps of mfma_f32_32x32x16_bf16 reading h-frags from global double-buffer;
// gates exchanged via LDS; h-slice written to global + device-scope spin
// barrier (4 blocks always co-resident; release/acquire via __threadfence).
__global__ __launch_bounds__(512) void k_lstm5(
    const float* __restrict__ xw, const short* __restrict__ whhp,
    const float* __restrict__ c0, short* __restrict__ hbuf,
    unsigned int* __restrict__ bar, float* __restrict__ hid_out)
{
    __shared__ short wlds[8*16*64*8];   // 128 KB
    __shared__ short g_lds[32][256];    // 16 KB (bf16 gates)
    __shared__ float c_lds[32][64];     // 8 KB
    int tid = threadIdx.x, wid = tid >> 6, lane = tid & 63;
    int q = blockIdx.x;                 // 0..3

    // preload W slice: 8192 short8 slots
    {
        const short8* wp8 = reinterpret_cast<const short8*>(whhp);
        for (int i = tid; i < 8192; i += 512)
            *reinterpret_cast<short8*>(&wlds[i*8]) = wp8[(size_t)q*8192 + i];
    }
    for (int i = tid; i < 32*64; i += 512) {
        int b = i >> 6, jj = i & 63;
        c_lds[b][jj] = c0[b*HH + q*64 + jj];
    }
    __syncthreads();

    for (int t = 0; t < TT; ++t) {
        const short* hcur = hbuf + (size_t)(t & 1)*8192;
        short* hnxt = hbuf + (size_t)((t + 1) & 1)*8192;

        floatx16 acc;
        #pragma unroll
        for (int r = 0; r < 16; ++r) acc[r] = 0.f;
        #pragma unroll
        for (int kstep = 0; kstep < 16; ++kstep) {
            short8 af = *reinterpret_cast<const short8*>(&hcur[(size_t)(kstep*64 + lane)*8]);
            short8 bf = *reinterpret_cast<const short8*>(&wlds[((wid*16 + kstep)*64 + lane)*8]);
            acc = __builtin_amdgcn_mfma_f32_32x32x16_bf16(af, bf, acc, 0, 0, 0);
        }
        // gates: acc col = lane&31 within tile wid; row = (r&3)+8*(r>>2)+4*(lane>>5)
        int gcol = (wid >> 1)*256 + q*64 + (wid & 1)*32 + (lane & 31);
        int lcol = wid*32 + (lane & 31);
        #pragma unroll
        for (int r = 0; r < 16; ++r) {
            int row = (r & 3) + 8*(r >> 2) + 4*(lane >> 5);
            g_lds[row][lcol] = f2bf(acc[r] + xw[(size_t)(row*TT + t)*H4 + gcol]);
        }
        __syncthreads();
        // update: 2048 cells (32 b x 64 jj)
        for (int i = tid; i < 2048; i += 512) {
            int b = i >> 6, jj = i & 63;
            int c0i = ((jj >> 5))*32 + (jj & 31);
            float gi = bf2f(g_lds[b][0*64 + c0i + ((jj>>5)?0:0)]);
            // lcol(g,jj) = (g*2 + (jj>>5))*32 + (jj&31)
            gi       = bf2f(g_lds[b][((0*2 + (jj>>5))<<5) + (jj & 31)]);
            float gf = bf2f(g_lds[b][((1*2 + (jj>>5))<<5) + (jj & 31)]);
            float gg = bf2f(g_lds[b][((2*2 + (jj>>5))<<5) + (jj & 31)]);
            float go = bf2f(g_lds[b][((3*2 + (jj>>5))<<5) + (jj & 31)]);
            float c = sigm(gf)*c_lds[b][jj] + sigm(gi)*tanhf(gg);
            float h = sigm(go)*tanhf(c);
            c_lds[b][jj] = c;
            int hidx = q*64 + jj;
            hid_out[(size_t)(b*TT + t)*HH + hidx] = h;
            int kk = hidx & 15;
            int l2 = ((kk >> 3) << 5) + b;
            hnxt[(size_t)((hidx >> 4)*64 + l2)*8 + (kk & 7)] = f2bf(h);
        }
        __threadfence();
        __syncthreads();
        if (tid == 0) {
            atomicAdd(&bar[t], 1u);
            while (atomicAdd(&bar[t], 0u) < 4u) __builtin_amdgcn_s_sleep(2);
        }
        __syncthreads();
        __threadfence();
    }
}

// ---------------- K4: e scores ----------------
__global__ __launch_bounds__(256) void k_e(
    const float* __restrict__ enc_proj, const float* __restrict__ dec_proj,
    const float* __restrict__ v_w, const float* __restrict__ v_b,
    const unsigned char* __restrict__ enc_mask, float* __restrict__ e_out)
{
    int b = blockIdx.x, lbase = blockIdx.y*4;
    __shared__ float decp[TT*H2];
    int tid = threadIdx.x;
    for (int i = tid; i < TT*H2; i += 256) decp[i] = dec_proj[(size_t)b*TT*H2 + i];
    __syncthreads();
    int wave = tid >> 6, lane = tid & 63;
    int l = lbase + wave;
    const float* er = &enc_proj[(size_t)(b*LL + l)*H2];
    float ep[8], vw[8];
    #pragma unroll
    for (int k = 0; k < 8; ++k) { int e = lane + 64*k; ep[k] = er[e]; vw[k] = v_w[e]; }
    float vb = v_b[0];
    bool masked = enc_mask[b*LL + l] != 0;
    for (int t = 0; t < TT; ++t) {
        float acc = 0.f;
        #pragma unroll
        for (int k = 0; k < 8; ++k) {
            int e = lane + 64*k;
            acc += vw[k] * tanhf(ep[k] + decp[t*H2 + e]);
        }
        #pragma unroll
        for (int off = 32; off; off >>= 1) acc += __shfl_xor(acc, off);
        if (lane == 0)
            e_out[(size_t)(b*TT + t)*LL + l] = masked ? -INFINITY : (acc + vb);
    }
}

// ---------------- K5: softmax over L + context + s ----------------
__global__ __launch_bounds__(256) void k_softmax_ctx(
    float* __restrict__ attn, const float* __restrict__ enc_states,
    const float* __restrict__ hidden, float* __restrict__ s_out)
{
    int bt = blockIdx.x, b = bt / TT, tid = threadIdx.x;
    __shared__ float a[LL];
    __shared__ float red[256];
    float m = -INFINITY;
    for (int l = tid; l < LL; l += 256) m = fmaxf(m, attn[(size_t)bt*LL + l]);
    red[tid] = m; __syncthreads();
    for (int s = 128; s; s >>= 1) { if (tid < s) red[tid] = fmaxf(red[tid], red[tid+s]); __syncthreads(); }
    m = red[0]; __syncthreads();
    float sum = 0.f;
    for (int l = tid; l < LL; l += 256) { float w = expf(attn[(size_t)bt*LL + l] - m); a[l] = w; sum += w; }
    red[tid] = sum; __syncthreads();
    for (int s = 128; s; s >>= 1) { if (tid < s) red[tid] += red[tid+s]; __syncthreads(); }
    float inv = 1.0f / red[0];
    __syncthreads();
    for (int l = tid; l < LL; l += 256) { float w = a[l]*inv; a[l] = w; attn[(size_t)bt*LL + l] = w; }
    __syncthreads();
    for (int c = tid; c < H2; c += 256) {
        float acc = 0.f;
        const float* es = &enc_states[(size_t)b*LL*H2 + c];
        for (int l = 0; l < LL; ++l) acc += a[l] * es[(size_t)l*H2];
        s_out[(size_t)bt*H3 + HH + c] = acc;
    }
    for (int c = tid; c < HH; c += 256) s_out[(size_t)bt*H3 + c] = hidden[(size_t)bt*HH + c];
}

// ---------------- K6: switch softmax + copy score ----------------
__global__ __launch_bounds__(64) void k_switch_copy(
    const float* __restrict__ s, const float* __restrict__ x,
    const float* __restrict__ enc_h0,
    const float* __restrict__ wh_w, const float* __restrict__ wh_b,
    const float* __restrict__ ws_w, const float* __restrict__ ws_b,
    const float* __restrict__ wx_w, const float* __restrict__ wx_b,
    const float* __restrict__ wc_w, const float* __restrict__ wc_b,
    const int* __restrict__ article_inds, const int* __restrict__ targets,
    const float* __restrict__ attn, float* __restrict__ psw, float* __restrict__ copysc)
{
    int bt = blockIdx.x, b = bt / TT, lane = threadIdx.x;
    float s0 = 0.f, s1 = 0.f, s2 = 0.f;
    const float* ctx = &s[(size_t)bt*H3 + HH];
    const float* hid = &s[(size_t)bt*H3];
    for (int k = lane; k < H2; k += 64) { float v = ctx[k]; s0 += v*wh_w[k*3]; s1 += v*wh_w[k*3+1]; s2 += v*wh_w[k*3+2]; }
    for (int k = lane; k < HH; k += 64) { float v = hid[k]; s0 += v*ws_w[k*3]; s1 += v*ws_w[k*3+1]; s2 += v*ws_w[k*3+2]; }
    for (int k = lane; k < EE; k += 64) { float v = x[(size_t)bt*EE + k]; s0 += v*wx_w[k*3]; s1 += v*wx_w[k*3+1]; s2 += v*wx_w[k*3+2]; }
    for (int k = lane; k < HH; k += 64) { float v = enc_h0[b*HH + k]; s0 += v*wc_w[k*3]; s1 += v*wc_w[k*3+1]; s2 += v*wc_w[k*3+2]; }
    #pragma unroll
    for (int off = 32; off; off >>= 1) {
        s0 += __shfl_xor(s0, off); s1 += __shfl_xor(s1, off); s2 += __shfl_xor(s2, off);
    }
    if (lane == 0) {
        s0 += wh_b[0] + ws_b[0] + wx_b[0] + wc_b[0];
        s1 += wh_b[1] + ws_b[1] + wx_b[1] + wc_b[1];
        s2 += wh_b[2] + ws_b[2] + wx_b[2] + wc_b[2];
        float mm = fmaxf(s0, fmaxf(s1, s2));
        float e0 = expf(s0-mm), e1 = expf(s1-mm), e2 = expf(s2-mm);
        float inv = 1.f/(e0+e1+e2);
        psw[bt*3+0] = e0*inv; psw[bt*3+1] = e1*inv; psw[bt*3+2] = e2*inv;
    }
    int tgt = targets[bt];
    float cs = 0.f;
    for (int l = lane; l < LL; l += 64)
        if (article_inds[b*LL + l] == tgt) cs += attn[(size_t)bt*LL + l];
    #pragma unroll
    for (int off = 32; off; off >>= 1) cs += __shfl_xor(cs, off);
    if (lane == 0) copysc[bt] = cs;
}

// ---------------- K_pack: s_buf -> fragment-ordered bf16 (A of big GEMM) ----
__global__ __launch_bounds__(256) void k_pack(
    const float* __restrict__ A, short* __restrict__ Apack)
{
    int s = blockIdx.x*256 + threadIdx.x;
    int l = s & 63;
    int ks = (s >> 6) & 1;
    int rest = s >> 7;
    int mt = rest % 12;
    int kstep = rest / 12;
    int row = mt*32 + (l & 31);
    int kb = kstep*32 + ks*16 + ((l >> 5) << 3);
    const float4* src = reinterpret_cast<const float4*>(&A[(size_t)row*H3 + kb]);
    float4 a = src[0], b = src[1];
    short8 v;
    v[0]=f2bf(a.x); v[1]=f2bf(a.y); v[2]=f2bf(a.z); v[3]=f2bf(a.w);
    v[4]=f2bf(b.x); v[5]=f2bf(b.y); v[6]=f2bf(b.z); v[7]=f2bf(b.w);
    *reinterpret_cast<short8*>(Apack + (size_t)s*8) = v;
}

// ---------------- K_bpack: Vout_w [768,50000] fp32 -> bf16 B-frag order -----
// grid (24 ksteps, 196 col-blocks), 256 thr. Coalesced row-major reads via
// LDS transpose; contiguous 1 KB fragment writes.
// Bpack slot ((ct*24 + kstep)*2 + ks)*64 + l, 8 shorts:
//   value j = W[kstep*32 + ks*16 + (l>>5)*8 + j][ct*32 + (l&31)]
__global__ __launch_bounds__(256) void k_bpack(
    const float* __restrict__ Wm, short* __restrict__ Bp)
{
    __shared__ short tile[32][264];
    int kstep = blockIdx.x, cblk = blockIdx.y;
    int tid = threadIdx.x;
    int cbase = cblk*256;
    for (int i = tid; i < 32*64; i += 256) {
        int r = i >> 6, c4 = i & 63;
        int col = cbase + c4*4;
        float4 v = make_float4(0.f,0.f,0.f,0.f);
        if (col < VV)
            v = *reinterpret_cast<const float4*>(&Wm[(size_t)(kstep*32 + r)*VV + col]);
        tile[r][c4*4+0] = f2bf(v.x); tile[r][c4*4+1] = f2bf(v.y);
        tile[r][c4*4+2] = f2bf(v.z); tile[r][c4*4+3] = f2bf(v.w);
    }
    __syncthreads();
    int wave = tid >> 6, l = tid & 63;
    #pragma unroll
    for (int it = 0; it < 4; ++it) {
        int fid = wave*4 + it;
        int ct_l = fid >> 1, ks = fid & 1;
        int rbase = ks*16 + ((l >> 5) << 3);
        int c = ct_l*32 + (l & 31);
        short8 v;
        #pragma unroll
        for (int j = 0; j < 8; ++j) v[j] = tile[rbase + j][c];
        size_t ct_g = (size_t)cblk*8 + ct_l;
        *reinterpret_cast<short8*>(&Bp[(((ct_g*24 + kstep)*2 + ks)*64 + l)*8]) = v;
    }
}

// ---------------- K7b: packed-B MFMA GEMM + fused exp partials --------------
__global__ __launch_bounds__(512) void k_big_packed(
    const short* __restrict__ Apack, const short* __restrict__ Bp,
    const float* __restrict__ bias, const int* __restrict__ targets,
    float* __restrict__ psum, float* __restrict__ tlogit)
{
    __shared__ float pv_l[192][4];
    int bm = blockIdx.x, nvb = blockIdx.y;
    int bn = nvb * 128;
    int t = threadIdx.x;
    int wid = t >> 6, lane = t & 63;
    int wave_m = wid >> 2, wave_n = wid & 3;
    size_t ct_g = (size_t)nvb*4 + wave_n;
    int colB = bn + wave_n*32 + (lane & 31);
    bool colOK = colB < VV;
    int mt0 = bm*6 + wave_m*3;

    const short8* ap = reinterpret_cast<const short8*>(Apack);
    const short8* bp8 = reinterpret_cast<const short8*>(Bp);

    floatx16 acc[3];
    #pragma unroll
    for (int mi = 0; mi < 3; ++mi)
        #pragma unroll
        for (int r = 0; r < 16; ++r) acc[mi][r] = 0.f;

    short8 Ba0, Ba1, Bb0, Bb1;
    short8 Fa[6], Fb[6];

#define LOADB(B0, B1, kst) do { \
    B0 = bp8[((ct_g*24 + (kst))*2 + 0)*64 + lane]; \
    B1 = bp8[((ct_g*24 + (kst))*2 + 1)*64 + lane]; \
} while (0)

#define LOADA(F, kst) do { \
    _Pragma("unroll") \
    for (int mi = 0; mi < 3; ++mi) { \
        F[mi]   = ap[(size_t)(((kst)*12 + (mt0 + mi))*2 + 0)*64 + lane]; \
        F[3+mi] = ap[(size_t)(((kst)*12 + (mt0 + mi))*2 + 1)*64 + lane]; \
    } \
} while (0)

#define STEP(B0, B1, F) do { \
    _Pragma("unroll") \
    for (int mi = 0; mi < 3; ++mi) \
        acc[mi] = __builtin_amdgcn_mfma_f32_32x32x16_bf16(F[mi], B0, acc[mi], 0, 0, 0); \
    _Pragma("unroll") \
    for (int mi = 0; mi < 3; ++mi) \
        acc[mi] = __builtin_amdgcn_mfma_f32_32x32x16_bf16(F[3+mi], B1, acc[mi], 0, 0, 0); \
} while (0)

    LOADB(Ba0, Ba1, 0); LOADA(Fa, 0);
    LOADB(Bb0, Bb1, 1); LOADA(Fb, 1);
    for (int k = 0; k < KSTEPS; k += 2) {
        STEP(Ba0, Ba1, Fa);
        if (k + 2 < KSTEPS) { LOADB(Ba0, Ba1, k+2); LOADA(Fa, k+2); }
        STEP(Bb0, Bb1, Fb);
        if (k + 3 < KSTEPS) { LOADB(Bb0, Bb1, k+3); LOADA(Fb, k+3); }
    }
#undef LOADB
#undef LOADA
#undef STEP

    float bias_v = colOK ? bias[colB] : 0.f;
    int rsub = 4*(lane >> 5);
    #pragma unroll
    for (int mi = 0; mi < 3; ++mi) {
        #pragma unroll
        for (int r = 0; r < 16; ++r) {
            int row_l = wave_m*96 + mi*32 + rsub + (r & 3) + 8*(r >> 2);
            int rowg = bm*192 + row_l;
            float logit = acc[mi][r] + bias_v;
            if (colOK && colB == targets[rowg]) tlogit[rowg] = logit;
            float e = colOK ? expf(logit) : 0.f;
            #pragma unroll
            for (int msk = 16; msk; msk >>= 1) e += __shfl_xor(e, msk);
            if ((lane & 31) == 0) pv_l[row_l][wave_n] = e;
        }
    }
    __syncthreads();
    if (t < 192) {
        float ss = pv_l[t][0] + pv_l[t][1] + pv_l[t][2] + pv_l[t][3];
        int rowg = bm*192 + t;
        psum[(size_t)rowg*NVB + nvb] = ss;
    }
}

// ---------------- K7: legacy direct-read k_big (ws-size fallback) -----------
__global__ __launch_bounds__(512) void k_big(
    const short* __restrict__ Apack, const float* __restrict__ Wm,
    const float* __restrict__ bias, const int* __restrict__ targets,
    float* __restrict__ psum, float* __restrict__ tlogit)
{
    __shared__ float pv_l[192][4];
    int bm = blockIdx.x, nvb = blockIdx.y;
    int bn = nvb * 128;
    int t = threadIdx.x;
    int wid = t >> 6, lane = t & 63;
    int wave_m = wid >> 2, wave_n = wid & 3;
    int colB = bn + wave_n*32 + (lane & 31);
    int kOff = (lane >> 5) << 3;
    bool colOK = colB < VV;
    int mt0 = bm*6 + wave_m*3;
    const short8* ap = reinterpret_cast<const short8*>(Apack);
    floatx16 acc[3];
    #pragma unroll
    for (int mi = 0; mi < 3; ++mi)
        #pragma unroll
        for (int r = 0; r < 16; ++r) acc[mi][r] = 0.f;
    float Bq0a[8], Bq1a[8], Bq0b[8], Bq1b[8];
    short8 Fa[6], Fb[6];
#define LOADB(Q0, Q1, kst) do { \
    int kb_ = (kst)*32 + kOff; \
    _Pragma("unroll") \
    for (int j = 0; j < 8; ++j) Q0[j] = colOK ? Wm[(size_t)(kb_ + j)*VV + colB] : 0.f; \
    _Pragma("unroll") \
    for (int j = 0; j < 8; ++j) Q1[j] = colOK ? Wm[(size_t)(kb_ + 16 + j)*VV + colB] : 0.f; \
} while (0)
#define LOADA(F, kst) do { \
    _Pragma("unroll") \
    for (int mi = 0; mi < 3; ++mi) { \
        F[mi]   = ap[(size_t)(((kst)*12 + (mt0 + mi))*2 + 0)*64 + lane]; \
        F[3+mi] = ap[(size_t)(((kst)*12 + (mt0 + mi))*2 + 1)*64 + lane]; \
    } \
} while (0)
#define STEP(Q0, Q1, F) do { \
    short8 b0_, b1_; \
    _Pragma("unroll") \
    for (int j = 0; j < 8; ++j) { b0_[j] = f2bf(Q0[j]); b1_[j] = f2bf(Q1[j]); } \
    _Pragma("unroll") \
    for (int mi = 0; mi < 3; ++mi) \
        acc[mi] = __builtin_amdgcn_mfma_f32_32x32x16_bf16(F[mi], b0_, acc[mi], 0, 0, 0); \
    _Pragma("unroll") \
    for (int mi = 0; mi < 3; ++mi) \
        acc[mi] = __builtin_amdgcn_mfma_f32_32x32x16_bf16(F[3+mi], b1_, acc[mi], 0, 0, 0); \
} while (0)
    LOADB(Bq0a, Bq1a, 0); LOADA(Fa, 0);
    LOADB(Bq0b, Bq1b, 1); LOADA(Fb, 1);
    for (int k = 0; k < KSTEPS; k += 2) {
        STEP(Bq0a, Bq1a, Fa);
        if (k + 2 < KSTEPS) { LOADB(Bq0a, Bq1a, k+2); LOADA(Fa, k+2); }
        STEP(Bq0b, Bq1b, Fb);
        if (k + 3 < KSTEPS) { LOADB(Bq0b, Bq1b, k+3); LOADA(Fb, k+3); }
    }
#undef LOADB
#undef LOADA
#undef STEP
    float bias_v = colOK ? bias[colB] : 0.f;
    int rsub = 4*(lane >> 5);
    #pragma unroll
    for (int mi = 0; mi < 3; ++mi) {
        #pragma unroll
        for (int r = 0; r < 16; ++r) {
            int row_l = wave_m*96 + mi*32 + rsub + (r & 3) + 8*(r >> 2);
            int rowg = bm*192 + row_l;
            float logit = acc[mi][r] + bias_v;
            if (colOK && colB == targets[rowg]) tlogit[rowg] = logit;
            float e = colOK ? expf(logit) : 0.f;
            #pragma unroll
            for (int msk = 16; msk; msk >>= 1) e += __shfl_xor(e, msk);
            if ((lane & 31) == 0) pv_l[row_l][wave_n] = e;
        }
    }
    __syncthreads();
    if (t < 192) {
        float ss = pv_l[t][0] + pv_l[t][1] + pv_l[t][2] + pv_l[t][3];
        int rowg = bm*192 + t;
        psum[(size_t)rowg*NVB + nvb] = ss;
    }
}

// ---------------- K8: sum partials + per-token nll ----------------
__global__ __launch_bounds__(64) void k_lsum(
    const float* __restrict__ psum,
    const float* __restrict__ tlogit, const int* __restrict__ targets,
    const float* __restrict__ psw, const float* __restrict__ copysc,
    const float* __restrict__ dec_mask, float* __restrict__ nll)
{
    int pair = blockIdx.x, lane = threadIdx.x;
    float s = 0.f;
    for (int j = lane; j < NVB; j += 64) s += psum[(size_t)pair*NVB + j];
    #pragma unroll
    for (int off = 32; off; off >>= 1) s += __shfl_xor(s, off);
    if (lane == 0) {
        int tgt = targets[pair];
        float outv;
        if (tgt == UNK) outv = 1.0f;
        else {
            float base = 0.f;
            if (tgt < VV) {
                float pvv = expf(tlogit[pair]) / s;
                float pg = (tgt < VV - NPR) ? psw[pair*3] : psw[pair*3+1];
                base = pg * pvv;
            }
            outv = base + psw[pair*3+2] * copysc[pair];
        }
        outv = fmaxf(outv, 1e-38f);
        nll[pair] = -logf(outv) * dec_mask[pair];
    }
}

// ---------------- K9: final per-batch loss ----------------
__global__ __launch_bounds__(64) void k_final(
    const float* __restrict__ nll, const float* __restrict__ dec_lens, float* __restrict__ out)
{
    int b = threadIdx.x;
    if (b < BB) {
        float a = 0.f;
        for (int t = 0; t < TT; ++t) a += nll[b*TT + t];
        out[b] = a / dec_lens[b];
    }
}

extern "C" void kernel_launch(void* const* d_in, const int* in_sizes, int n_in,
                              void* d_out, int out_size, void* d_ws, size_t ws_size,
                              hipStream_t stream)
{
    const float* enc_states = (const float*)d_in[0];
    const float* enc_h0     = (const float*)d_in[1];
    const float* enc_c0     = (const float*)d_in[2];
    const unsigned char* enc_mask = (const unsigned char*)d_in[3];
    const int* article_inds = (const int*)d_in[4];
    const int* dec_input    = (const int*)d_in[5];
    const int* targets      = (const int*)d_in[6];
    const float* dec_lens   = (const float*)d_in[7];
    const float* dec_mask   = (const float*)d_in[8];
    const float* embed      = (const float*)d_in[9];
    const float* W_ih       = (const float*)d_in[10];
    const float* W_hh       = (const float*)d_in[11];
    const float* b_lstm     = (const float*)d_in[12];
    const float* Wh_w = (const float*)d_in[13]; const float* Wh_b = (const float*)d_in[14];
    const float* Ws_w = (const float*)d_in[15]; const float* Ws_b = (const float*)d_in[16];
    const float* v_w  = (const float*)d_in[17]; const float* v_b  = (const float*)d_in[18];
    const float* wh_w = (const float*)d_in[19]; const float* wh_b = (const float*)d_in[20];
    const float* ws_w = (const float*)d_in[21]; const float* ws_b = (const float*)d_in[22];
    const float* wx_w = (const float*)d_in[23]; const float* wx_b = (const float*)d_in[24];
    const float* wc_w = (const float*)d_in[25]; const float* wc_b = (const float*)d_in[26];
    const float* Vout_w = (const float*)d_in[27]; const float* Vout_b = (const float*)d_in[28];

    float* ws = (float*)d_ws;
    float* x_buf   = ws + OFF_X;
    float* hid     = ws + OFF_HID;
    float* encp    = ws + OFF_ENCP;
    float* decp    = ws + OFF_DECP;
    float* attn    = ws + OFF_ATTN;
    float* s_buf   = ws + OFF_S;
    float* psw     = ws + OFF_PSW;
    float* copysc  = ws + OFF_COPY;
    float* tlogit  = ws + OFF_TLOGIT;
    float* psum    = ws + OFF_PSUM;
    float* nll     = ws + OFF_NLL;
    short* apack   = (short*)(ws + OFF_APACK);
    float* xw      = ws + OFF_XW;
    short* whhp    = (short*)(ws + OFF_WHH);
    short* hbuf    = (short*)(ws + OFF_HFRAG);
    unsigned int* bar = (unsigned int*)(ws + OFF_BAR);
    short* bpack   = (short*)(ws + OFF_BPACK);
    float* out     = (float*)d_out;

    bool use_pack = ws_size >= WS_NEEDED_BYTES;

    // 1a. embedding lookup
    k_embed<<<dim3(BT*EE/4/256), dim3(256), 0, stream>>>(embed, dec_input, x_buf);
    // 1b. xw = x @ W_ih + b_lstm   [384,1024]
    k_gemm_bias<<<dim3(BT/64, H4/128), dim3(256), 0, stream>>>(x_buf, W_ih, b_lstm, xw, H4, EE);
    // 1c. pack W_hh -> per-block sliced B-frag order
    k_whh_pack<<<dim3(128), dim3(256), 0, stream>>>(W_hh, whhp);
    // 1d. init h-frag buf0 + zero barriers
    k_init<<<dim3(32), dim3(256), 0, stream>>>(enc_h0, hbuf, bar);
    // 1e. column-split MFMA LSTM (4 blocks, LDS-resident W, spin barrier)
    k_lstm5<<<dim3(4), dim3(512), 0, stream>>>(xw, whhp, enc_c0, hbuf, bar, hid);
    // 2. enc_proj
    k_gemm_bias<<<dim3(BB*LL/64, H2/128), dim3(256), 0, stream>>>(enc_states, Wh_w, Wh_b, encp, H2, H2);
    // 3. dec_proj
    k_gemm_bias<<<dim3(BT/64, H2/128), dim3(256), 0, stream>>>(hid, Ws_w, Ws_b, decp, H2, HH);
    // 4. e scores
    k_e<<<dim3(BB, LL/4), dim3(256), 0, stream>>>(encp, decp, v_w, v_b, enc_mask, attn);
    // 5. softmax + context + s
    k_softmax_ctx<<<dim3(BT), dim3(256), 0, stream>>>(attn, enc_states, hid, s_buf);
    // 6. switch + copy score
    k_switch_copy<<<dim3(BT), dim3(64), 0, stream>>>(s_buf, x_buf, enc_h0,
        wh_w, wh_b, ws_w, ws_b, wx_w, wx_b, wc_w, wc_b,
        article_inds, targets, attn, psw, copysc);
    // 6.5 pack A
    k_pack<<<dim3(BT*H3/(8*256)), dim3(256), 0, stream>>>(s_buf, apack);
    // 7. big GEMM
    if (use_pack) {
        k_bpack<<<dim3(24, 196), dim3(256), 0, stream>>>(Vout_w, bpack);
        k_big_packed<<<dim3(2, NVB), dim3(512), 0, stream>>>(apack, bpack, Vout_b, targets, psum, tlogit);
    } else {
        k_big<<<dim3(2, NVB), dim3(512), 0, stream>>>(apack, Vout_w, Vout_b, targets, psum, tlogit);
    }
    // 8. merge + nll
    k_lsum<<<dim3(BT), dim3(64), 0, stream>>>(psum, tlogit, targets, psw, copysc, dec_mask, nll);
    // 9. final loss
    k_final<<<dim3(1), dim3(64), 0, stream>>>(nll, dec_lens, out);
}

// Round 12
// 359.744 us; speedup vs baseline: 2.0001x; 1.5136x over previous
//
#include <hip/hip_runtime.h>
#include <hip/hip_bf16.h>
#include <math.h>

// Problem constants
#define BB 32
#define LL 300
#define TT 12
#define HH 256
#define EE 128
#define VV 50000
#define OOV 30
#define NPR 6
#define UNK 1
#define H2 512   // 2H
#define H3 768   // 3H
#define H4 1024  // 4H
#define BT (BB*TT)       // 384
#define NVB 391          // ceil(50000/128)
#define KSTEPS 24        // 768/32
#define NT32P (196*8)    // padded 32-col tile count for Bpack (1568)

// ---------------- ws layout (float offsets) ----------------
#define OFF_X        0                          // BT*EE
#define OFF_HID      (OFF_X + BT*EE)            // BT*HH
#define OFF_ENCP     (OFF_HID + BT*HH)          // BB*LL*H2
#define OFF_DECP     (OFF_ENCP + BB*LL*H2)      // BT*H2
#define OFF_ATTN     (OFF_DECP + BT*H2)         // BT*LL
#define OFF_S        (OFF_ATTN + BT*LL)         // BT*H3
#define OFF_PSW      (OFF_S + BT*H3)            // BT*3
#define OFF_COPY     (OFF_PSW + BT*3)           // BT
#define OFF_TLOGIT   (OFF_COPY + BT)            // BT
#define OFF_PMAX     (OFF_TLOGIT + BT)          // BT*NVB (unused legacy)
#define OFF_PSUM     (OFF_PMAX + BT*NVB)        // BT*NVB
#define OFF_NLL      (OFF_PSUM + BT*NVB)        // BT
#define OFF_APACK    (OFF_NLL + BT)             // BT*H3 shorts
#define OFF_XW       (OFF_APACK + BT*H3/2)      // BT*H4 floats
#define OFF_WHH      (OFF_XW + BT*H4)           // 131072 floats
#define OFF_HFRAG    (OFF_WHH + 131072)         // 8192 floats
#define OFF_BAR      (OFF_HFRAG + 8192)         // 64 floats
#define OFF_BPACK    (OFF_BAR + 64)             // NT32P*24*2*64*8 shorts
#define BPACK_SHORTS ((size_t)NT32P*24*2*64*8)
#define WS_NEEDED_BYTES ((size_t)(OFF_BPACK)*4 + BPACK_SHORTS*2)
// aliases living INSIDE the BPACK region (all dead before k_bpack writes):
#define OFF_APENC (OFF_BPACK)                   // 9600*512 shorts = 2457600 fl
#define OFF_APHID (OFF_APENC + 2457600)         // 384*256 shorts = 49152 fl
#define OFF_APX   (OFF_APHID + 49152)           // 384*128 shorts = 24576 fl
#define OFF_BWIH  (OFF_APX + 24576)             // 128*1024 shorts = 65536 fl
#define OFF_BWHW  (OFF_BWIH + 65536)            // 512*512 shorts = 131072 fl
#define OFF_BWSW  (OFF_BWHW + 131072)           // 256*512 shorts = 65536 fl

typedef __attribute__((ext_vector_type(8))) short short8;
typedef __attribute__((ext_vector_type(16))) float floatx16;

__device__ __forceinline__ short f2bf(float f) {
    __hip_bfloat16 h = __float2bfloat16(f);
    return *reinterpret_cast<short*>(&h);
}
__device__ __forceinline__ float bf2f(short s) {
    unsigned int u = ((unsigned int)(unsigned short)s) << 16;
    return __uint_as_float(u);
}
__device__ __forceinline__ float sigm(float x) { return 1.f/(1.f + expf(-x)); }

// ---------------- K0: embedding lookup ----------------
__global__ __launch_bounds__(256) void k_embed(
    const float* __restrict__ embed, const int* __restrict__ dec_input,
    float* __restrict__ x_out)
{
    int i = blockIdx.x*256 + threadIdx.x;
    int bt = i >> 5;
    int e4 = i & 31;
    int tok = dec_input[bt];
    reinterpret_cast<float4*>(x_out)[(size_t)bt*32 + e4] =
        reinterpret_cast<const float4*>(embed)[(size_t)tok*32 + e4];
}

// ---------------- generic A-pack: A [M,K] fp32 -> 32x32x16 A-frag bf16 ------
// slot s = ((kstep*MT + mt)*2 + ks)*64 + l ;
//   row = mt*32 + (l&31); kb = kstep*32 + ks*16 + (l>>5)*8
__global__ __launch_bounds__(256) void k_apack(
    const float* __restrict__ A, short* __restrict__ Ap, int MT, int K_)
{
    int s = blockIdx.x*256 + threadIdx.x;
    int l = s & 63;
    int ks = (s >> 6) & 1;
    int rest = s >> 7;
    int mt = rest % MT;
    int kstep = rest / MT;
    int row = mt*32 + (l & 31);
    int kb = kstep*32 + ks*16 + ((l >> 5) << 3);
    const float4* src = reinterpret_cast<const float4*>(&A[(size_t)row*K_ + kb]);
    float4 a = src[0], b = src[1];
    short8 v;
    v[0]=f2bf(a.x); v[1]=f2bf(a.y); v[2]=f2bf(a.z); v[3]=f2bf(a.w);
    v[4]=f2bf(b.x); v[5]=f2bf(b.y); v[6]=f2bf(b.z); v[7]=f2bf(b.w);
    *reinterpret_cast<short8*>(Ap + (size_t)s*8) = v;
}

// ---------------- generic W-pack: W [K,N] fp32 -> 32x32x16 B-frag bf16 ------
// slot s = ((ct*KS + kstep)*2 + ks)*64 + l ;
//   col = ct*32 + (l&31); kb = kstep*32 + ks*16 + (l>>5)*8 ; v[j]=W[kb+j][col]
__global__ __launch_bounds__(256) void k_wpack(
    const float* __restrict__ W, short* __restrict__ Bp, int KS, int N_)
{
    int s = blockIdx.x*256 + threadIdx.x;
    int l = s & 63;
    int ks = (s >> 6) & 1;
    int rest = s >> 7;
    int kstep = rest % KS;
    int ct = rest / KS;
    int col = ct*32 + (l & 31);
    int kb = kstep*32 + ks*16 + ((l >> 5) << 3);
    short8 v;
    #pragma unroll
    for (int j = 0; j < 8; ++j) v[j] = f2bf(W[(size_t)(kb + j)*N_ + col]);
    *reinterpret_cast<short8*>(Bp + (size_t)s*8) = v;
}

// ---------------- generic packed MFMA GEMM + bias: C[M,N] fp32 --------------
// grid (M/192, N/128), 512 thr (8 waves = 2m x 4n, 3 mt/wave). KS even.
__global__ __launch_bounds__(512) void k_gemm_mfma(
    const short* __restrict__ Apack, const short* __restrict__ Bpack,
    const float* __restrict__ bias, float* __restrict__ C,
    int N_, int MT, int KS)
{
    int bm = blockIdx.x, nb = blockIdx.y;
    int t = threadIdx.x;
    int wid = t >> 6, lane = t & 63;
    int wave_m = wid >> 2, wave_n = wid & 3;
    int mt0 = bm*6 + wave_m*3;
    int ct = nb*4 + wave_n;

    const short8* ap = reinterpret_cast<const short8*>(Apack);
    const short8* bp = reinterpret_cast<const short8*>(Bpack);

    floatx16 acc[3];
    #pragma unroll
    for (int mi = 0; mi < 3; ++mi)
        #pragma unroll
        for (int r = 0; r < 16; ++r) acc[mi][r] = 0.f;

    short8 Ba0, Ba1, Bb0, Bb1;
    short8 Fa[6], Fb[6];

#define LOADB(B0, B1, kst) do { \
    B0 = bp[(size_t)(((ct*KS + (kst))*2 + 0)*64 + lane)]; \
    B1 = bp[(size_t)(((ct*KS + (kst))*2 + 1)*64 + lane)]; \
} while (0)
#define LOADA(F, kst) do { \
    _Pragma("unroll") \
    for (int mi = 0; mi < 3; ++mi) { \
        F[mi]   = ap[(size_t)((((kst)*MT + (mt0 + mi))*2 + 0)*64 + lane)]; \
        F[3+mi] = ap[(size_t)((((kst)*MT + (mt0 + mi))*2 + 1)*64 + lane)]; \
    } \
} while (0)
#define STEP(B0, B1, F) do { \
    _Pragma("unroll") \
    for (int mi = 0; mi < 3; ++mi) \
        acc[mi] = __builtin_amdgcn_mfma_f32_32x32x16_bf16(F[mi], B0, acc[mi], 0, 0, 0); \
    _Pragma("unroll") \
    for (int mi = 0; mi < 3; ++mi) \
        acc[mi] = __builtin_amdgcn_mfma_f32_32x32x16_bf16(F[3+mi], B1, acc[mi], 0, 0, 0); \
} while (0)

    LOADB(Ba0, Ba1, 0); LOADA(Fa, 0);
    LOADB(Bb0, Bb1, 1); LOADA(Fb, 1);
    for (int k = 0; k < KS; k += 2) {
        STEP(Ba0, Ba1, Fa);
        if (k + 2 < KS) { LOADB(Ba0, Ba1, k+2); LOADA(Fa, k+2); }
        STEP(Bb0, Bb1, Fb);
        if (k + 3 < KS) { LOADB(Bb0, Bb1, k+3); LOADA(Fb, k+3); }
    }
#undef LOADB
#undef LOADA
#undef STEP

    int col = ct*32 + (lane & 31);
    float bias_v = bias[col];
    int rsub = 4*(lane >> 5);
    #pragma unroll
    for (int mi = 0; mi < 3; ++mi) {
        int rowg0 = bm*192 + wave_m*96 + mi*32 + rsub;
        #pragma unroll
        for (int r = 0; r < 16; ++r) {
            int rowg = rowg0 + (r & 3) + 8*(r >> 2);
            C[(size_t)rowg*N_ + col] = acc[mi][r] + bias_v;
        }
    }
}

// ---------------- fallback fp32 GEMM + bias (ws-too-small path) ----------------
__global__ __launch_bounds__(256) void k_gemm_bias(
    const float* __restrict__ A, const float* __restrict__ Wm,
    const float* __restrict__ bias, float* __restrict__ C, int N_, int K_)
{
    __shared__ float As[64][17];
    __shared__ __align__(16) float Bs[16][128];
    int bm = blockIdx.x*64, bn = blockIdx.y*128;
    int tid = threadIdx.x, tr = tid >> 4, tc = tid & 15;
    float acc[4][8] = {};
    for (int k0 = 0; k0 < K_; k0 += 16) {
        for (int i = tid; i < 64*16; i += 256) { int r = i >> 4, c = i & 15; As[r][c] = A[(size_t)(bm+r)*K_ + k0 + c]; }
        for (int i = tid; i < 16*128; i += 256) { int r = i >> 7, c = i & 127; Bs[r][c] = Wm[(size_t)(k0+r)*N_ + bn + c]; }
        __syncthreads();
        #pragma unroll
        for (int kk = 0; kk < 16; ++kk) {
            float a0 = As[tr*4+0][kk], a1 = As[tr*4+1][kk], a2 = As[tr*4+2][kk], a3 = As[tr*4+3][kk];
            const float4* bpx = reinterpret_cast<const float4*>(&Bs[kk][tc*8]);
            float4 q0 = bpx[0], q1 = bpx[1];
            float bb[8] = {q0.x,q0.y,q0.z,q0.w,q1.x,q1.y,q1.z,q1.w};
            #pragma unroll
            for (int j = 0; j < 8; ++j) {
                acc[0][j] += a0*bb[j]; acc[1][j] += a1*bb[j];
                acc[2][j] += a2*bb[j]; acc[3][j] += a3*bb[j];
            }
        }
        __syncthreads();
    }
    for (int i = 0; i < 4; ++i) {
        int r = bm + tr*4 + i;
        for (int j = 0; j < 8; ++j) {
            int c = bn + tc*8 + j;
            C[(size_t)r*N_ + c] = acc[i][j] + bias[c];
        }
    }
}

// ---------------- W_hh -> per-block-sliced 32x32x16 B-frag order ------------
__global__ __launch_bounds__(256) void k_whh_pack(
    const float* __restrict__ Whh, short* __restrict__ wp)
{
    int s = blockIdx.x*256 + threadIdx.x;      // 0..32767
    int l = s & 63;
    int kstep = (s >> 6) & 15;
    int ct_l = (s >> 10) & 7;
    int q = s >> 13;
    int col = (ct_l >> 1)*256 + q*64 + (ct_l & 1)*32 + (l & 31);
    int kb = kstep*16 + ((l >> 5) << 3);
    short8 v;
    #pragma unroll
    for (int j = 0; j < 8; ++j) v[j] = f2bf(Whh[(size_t)(kb + j)*H4 + col]);
    *reinterpret_cast<short8*>(wp + (size_t)s*8) = v;
}

// ---------------- init h0 -> hfrag buf0 + zero barriers ----------------
__global__ __launch_bounds__(256) void k_init(
    const float* __restrict__ h0, short* __restrict__ hbuf0,
    unsigned int* __restrict__ bar)
{
    int gid = blockIdx.x*256 + threadIdx.x;    // 0..8191
    int r = gid >> 8;
    int hidx = gid & 255;
    int kstep = hidx >> 4;
    int kk = hidx & 15;
    int l = ((kk >> 3) << 5) + r;
    hbuf0[(size_t)(kstep*64 + l)*8 + (kk & 7)] = f2bf(h0[r*HH + hidx]);
    if (blockIdx.x == 0 && threadIdx.x < 64) bar[threadIdx.x] = 0u;
}

// ---------------- column-split MFMA LSTM, 4 blocks, W-slice in LDS ----------
__global__ __launch_bounds__(512) void k_lstm5(
    const float* __restrict__ xw, const short* __restrict__ whhp,
    const float* __restrict__ c0, short* __restrict__ hbuf,
    unsigned int* __restrict__ bar, float* __restrict__ hid_out)
{
    __shared__ short wlds[8*16*64*8];   // 128 KB
    __shared__ short g_lds[32][256];    // 16 KB
    __shared__ float c_lds[32][64];     // 8 KB
    int tid = threadIdx.x, wid = tid >> 6, lane = tid & 63;
    int q = blockIdx.x;

    {
        const short8* wp8 = reinterpret_cast<const short8*>(whhp);
        for (int i = tid; i < 8192; i += 512)
            *reinterpret_cast<short8*>(&wlds[i*8]) = wp8[(size_t)q*8192 + i];
    }
    for (int i = tid; i < 32*64; i += 512) {
        int b = i >> 6, jj = i & 63;
        c_lds[b][jj] = c0[b*HH + q*64 + jj];
    }
    __syncthreads();

    for (int t = 0; t < TT; ++t) {
        const short* hcur = hbuf + (size_t)(t & 1)*8192;
        short* hnxt = hbuf + (size_t)((t + 1) & 1)*8192;

        floatx16 acc;
        #pragma unroll
        for (int r = 0; r < 16; ++r) acc[r] = 0.f;
        #pragma unroll
        for (int kstep = 0; kstep < 16; ++kstep) {
            short8 af = *reinterpret_cast<const short8*>(&hcur[(size_t)(kstep*64 + lane)*8]);
            short8 bf = *reinterpret_cast<const short8*>(&wlds[((wid*16 + kstep)*64 + lane)*8]);
            acc = __builtin_amdgcn_mfma_f32_32x32x16_bf16(af, bf, acc, 0, 0, 0);
        }
        int gcol = (wid >> 1)*256 + q*64 + (wid & 1)*32 + (lane & 31);
        int lcol = wid*32 + (lane & 31);
        #pragma unroll
        for (int r = 0; r < 16; ++r) {
            int row = (r & 3) + 8*(r >> 2) + 4*(lane >> 5);
            g_lds[row][lcol] = f2bf(acc[r] + xw[(size_t)(row*TT + t)*H4 + gcol]);
        }
        __syncthreads();
        for (int i = tid; i < 2048; i += 512) {
            int b = i >> 6, jj = i & 63;
            float gi = bf2f(g_lds[b][((0*2 + (jj>>5))<<5) + (jj & 31)]);
            float gf = bf2f(g_lds[b][((1*2 + (jj>>5))<<5) + (jj & 31)]);
            float gg = bf2f(g_lds[b][((2*2 + (jj>>5))<<5) + (jj & 31)]);
            float go = bf2f(g_lds[b][((3*2 + (jj>>5))<<5) + (jj & 31)]);
            float c = sigm(gf)*c_lds[b][jj] + sigm(gi)*tanhf(gg);
            float h = sigm(go)*tanhf(c);
            c_lds[b][jj] = c;
            int hidx = q*64 + jj;
            hid_out[(size_t)(b*TT + t)*HH + hidx] = h;
            int kk = hidx & 15;
            int l2 = ((kk >> 3) << 5) + b;
            hnxt[(size_t)((hidx >> 4)*64 + l2)*8 + (kk & 7)] = f2bf(h);
        }
        __threadfence();
        __syncthreads();
        if (tid == 0) {
            atomicAdd(&bar[t], 1u);
            while (atomicAdd(&bar[t], 0u) < 4u) __builtin_amdgcn_s_sleep(2);
        }
        __syncthreads();
        __threadfence();
    }
}

// ---------------- K4: e scores ----------------
__global__ __launch_bounds__(256) void k_e(
    const float* __restrict__ enc_proj, const float* __restrict__ dec_proj,
    const float* __restrict__ v_w, const float* __restrict__ v_b,
    const unsigned char* __restrict__ enc_mask, float* __restrict__ e_out)
{
    int b = blockIdx.x, lbase = blockIdx.y*4;
    __shared__ float decp[TT*H2];
    int tid = threadIdx.x;
    for (int i = tid; i < TT*H2; i += 256) decp[i] = dec_proj[(size_t)b*TT*H2 + i];
    __syncthreads();
    int wave = tid >> 6, lane = tid & 63;
    int l = lbase + wave;
    const float* er = &enc_proj[(size_t)(b*LL + l)*H2];
    float ep[8], vw[8];
    #pragma unroll
    for (int k = 0; k < 8; ++k) { int e = lane + 64*k; ep[k] = er[e]; vw[k] = v_w[e]; }
    float vb = v_b[0];
    bool masked = enc_mask[b*LL + l] != 0;
    for (int t = 0; t < TT; ++t) {
        float acc = 0.f;
        #pragma unroll
        for (int k = 0; k < 8; ++k) {
            int e = lane + 64*k;
            acc += vw[k] * tanhf(ep[k] + decp[t*H2 + e]);
        }
        #pragma unroll
        for (int off = 32; off; off >>= 1) acc += __shfl_xor(acc, off);
        if (lane == 0)
            e_out[(size_t)(b*TT + t)*LL + l] = masked ? -INFINITY : (acc + vb);
    }
}

// ---------------- K5: softmax over L + context + s ----------------
__global__ __launch_bounds__(256) void k_softmax_ctx(
    float* __restrict__ attn, const float* __restrict__ enc_states,
    const float* __restrict__ hidden, float* __restrict__ s_out)
{
    int bt = blockIdx.x, b = bt / TT, tid = threadIdx.x;
    __shared__ float a[LL];
    __shared__ float red[256];
    float m = -INFINITY;
    for (int l = tid; l < LL; l += 256) m = fmaxf(m, attn[(size_t)bt*LL + l]);
    red[tid] = m; __syncthreads();
    for (int s = 128; s; s >>= 1) { if (tid < s) red[tid] = fmaxf(red[tid], red[tid+s]); __syncthreads(); }
    m = red[0]; __syncthreads();
    float sum = 0.f;
    for (int l = tid; l < LL; l += 256) { float w = expf(attn[(size_t)bt*LL + l] - m); a[l] = w; sum += w; }
    red[tid] = sum; __syncthreads();
    for (int s = 128; s; s >>= 1) { if (tid < s) red[tid] += red[tid+s]; __syncthreads(); }
    float inv = 1.0f / red[0];
    __syncthreads();
    for (int l = tid; l < LL; l += 256) { float w = a[l]*inv; a[l] = w; attn[(size_t)bt*LL + l] = w; }
    __syncthreads();
    for (int c = tid; c < H2; c += 256) {
        float acc = 0.f;
        const float* es = &enc_states[(size_t)b*LL*H2 + c];
        for (int l = 0; l < LL; ++l) acc += a[l] * es[(size_t)l*H2];
        s_out[(size_t)bt*H3 + HH + c] = acc;
    }
    for (int c = tid; c < HH; c += 256) s_out[(size_t)bt*H3 + c] = hidden[(size_t)bt*HH + c];
}

// ---------------- K6: switch softmax + copy score ----------------
__global__ __launch_bounds__(64) void k_switch_copy(
    const float* __restrict__ s, const float* __restrict__ x,
    const float* __restrict__ enc_h0,
    const float* __restrict__ wh_w, const float* __restrict__ wh_b,
    const float* __restrict__ ws_w, const float* __restrict__ ws_b,
    const float* __restrict__ wx_w, const float* __restrict__ wx_b,
    const float* __restrict__ wc_w, const float* __restrict__ wc_b,
    const int* __restrict__ article_inds, const int* __restrict__ targets,
    const float* __restrict__ attn, float* __restrict__ psw, float* __restrict__ copysc)
{
    int bt = blockIdx.x, b = bt / TT, lane = threadIdx.x;
    float s0 = 0.f, s1 = 0.f, s2 = 0.f;
    const float* ctx = &s[(size_t)bt*H3 + HH];
    const float* hid = &s[(size_t)bt*H3];
    for (int k = lane; k < H2; k += 64) { float v = ctx[k]; s0 += v*wh_w[k*3]; s1 += v*wh_w[k*3+1]; s2 += v*wh_w[k*3+2]; }
    for (int k = lane; k < HH; k += 64) { float v = hid[k]; s0 += v*ws_w[k*3]; s1 += v*ws_w[k*3+1]; s2 += v*ws_w[k*3+2]; }
    for (int k = lane; k < EE; k += 64) { float v = x[(size_t)bt*EE + k]; s0 += v*wx_w[k*3]; s1 += v*wx_w[k*3+1]; s2 += v*wx_w[k*3+2]; }
    for (int k = lane; k < HH; k += 64) { float v = enc_h0[b*HH + k]; s0 += v*wc_w[k*3]; s1 += v*wc_w[k*3+1]; s2 += v*wc_w[k*3+2]; }
    #pragma unroll
    for (int off = 32; off; off >>= 1) {
        s0 += __shfl_xor(s0, off); s1 += __shfl_xor(s1, off); s2 += __shfl_xor(s2, off);
    }
    if (lane == 0) {
        s0 += wh_b[0] + ws_b[0] + wx_b[0] + wc_b[0];
        s1 += wh_b[1] + ws_b[1] + wx_b[1] + wc_b[1];
        s2 += wh_b[2] + ws_b[2] + wx_b[2] + wc_b[2];
        float mm = fmaxf(s0, fmaxf(s1, s2));
        float e0 = expf(s0-mm), e1 = expf(s1-mm), e2 = expf(s2-mm);
        float inv = 1.f/(e0+e1+e2);
        psw[bt*3+0] = e0*inv; psw[bt*3+1] = e1*inv; psw[bt*3+2] = e2*inv;
    }
    int tgt = targets[bt];
    float cs = 0.f;
    for (int l = lane; l < LL; l += 64)
        if (article_inds[b*LL + l] == tgt) cs += attn[(size_t)bt*LL + l];
    #pragma unroll
    for (int off = 32; off; off >>= 1) cs += __shfl_xor(cs, off);
    if (lane == 0) copysc[bt] = cs;
}

// ---------------- K_bpack: Vout_w -> bf16 B-frag order (LDS transpose) ------
__global__ __launch_bounds__(256) void k_bpack(
    const float* __restrict__ Wm, short* __restrict__ Bp)
{
    __shared__ short tile[32][264];
    int kstep = blockIdx.x, cblk = blockIdx.y;
    int tid = threadIdx.x;
    int cbase = cblk*256;
    for (int i = tid; i < 32*64; i += 256) {
        int r = i >> 6, c4 = i & 63;
        int col = cbase + c4*4;
        float4 v = make_float4(0.f,0.f,0.f,0.f);
        if (col < VV)
            v = *reinterpret_cast<const float4*>(&Wm[(size_t)(kstep*32 + r)*VV + col]);
        tile[r][c4*4+0] = f2bf(v.x); tile[r][c4*4+1] = f2bf(v.y);
        tile[r][c4*4+2] = f2bf(v.z); tile[r][c4*4+3] = f2bf(v.w);
    }
    __syncthreads();
    int wave = tid >> 6, l = tid & 63;
    #pragma unroll
    for (int it = 0; it < 4; ++it) {
        int fid = wave*4 + it;
        int ct_l = fid >> 1, ks = fid & 1;
        int rbase = ks*16 + ((l >> 5) << 3);
        int c = ct_l*32 + (l & 31);
        short8 v;
        #pragma unroll
        for (int j = 0; j < 8; ++j) v[j] = tile[rbase + j][c];
        size_t ct_g = (size_t)cblk*8 + ct_l;
        *reinterpret_cast<short8*>(&Bp[(((ct_g*24 + kstep)*2 + ks)*64 + l)*8]) = v;
    }
}

// ---------------- K7b: packed-B MFMA GEMM + fused exp partials --------------
__global__ __launch_bounds__(512) void k_big_packed(
    const short* __restrict__ Apack, const short* __restrict__ Bp,
    const float* __restrict__ bias, const int* __restrict__ targets,
    float* __restrict__ psum, float* __restrict__ tlogit)
{
    __shared__ float pv_l[192][4];
    int bm = blockIdx.x, nvb = blockIdx.y;
    int bn = nvb * 128;
    int t = threadIdx.x;
    int wid = t >> 6, lane = t & 63;
    int wave_m = wid >> 2, wave_n = wid & 3;
    size_t ct_g = (size_t)nvb*4 + wave_n;
    int colB = bn + wave_n*32 + (lane & 31);
    bool colOK = colB < VV;
    int mt0 = bm*6 + wave_m*3;

    const short8* ap = reinterpret_cast<const short8*>(Apack);
    const short8* bp8 = reinterpret_cast<const short8*>(Bp);

    floatx16 acc[3];
    #pragma unroll
    for (int mi = 0; mi < 3; ++mi)
        #pragma unroll
        for (int r = 0; r < 16; ++r) acc[mi][r] = 0.f;

    short8 Ba0, Ba1, Bb0, Bb1;
    short8 Fa[6], Fb[6];

#define LOADB(B0, B1, kst) do { \
    B0 = bp8[((ct_g*24 + (kst))*2 + 0)*64 + lane]; \
    B1 = bp8[((ct_g*24 + (kst))*2 + 1)*64 + lane]; \
} while (0)
#define LOADA(F, kst) do { \
    _Pragma("unroll") \
    for (int mi = 0; mi < 3; ++mi) { \
        F[mi]   = ap[(size_t)(((kst)*12 + (mt0 + mi))*2 + 0)*64 + lane]; \
        F[3+mi] = ap[(size_t)(((kst)*12 + (mt0 + mi))*2 + 1)*64 + lane]; \
    } \
} while (0)
#define STEP(B0, B1, F) do { \
    _Pragma("unroll") \
    for (int mi = 0; mi < 3; ++mi) \
        acc[mi] = __builtin_amdgcn_mfma_f32_32x32x16_bf16(F[mi], B0, acc[mi], 0, 0, 0); \
    _Pragma("unroll") \
    for (int mi = 0; mi < 3; ++mi) \
        acc[mi] = __builtin_amdgcn_mfma_f32_32x32x16_bf16(F[3+mi], B1, acc[mi], 0, 0, 0); \
} while (0)

    LOADB(Ba0, Ba1, 0); LOADA(Fa, 0);
    LOADB(Bb0, Bb1, 1); LOADA(Fb, 1);
    for (int k = 0; k < KSTEPS; k += 2) {
        STEP(Ba0, Ba1, Fa);
        if (k + 2 < KSTEPS) { LOADB(Ba0, Ba1, k+2); LOADA(Fa, k+2); }
        STEP(Bb0, Bb1, Fb);
        if (k + 3 < KSTEPS) { LOADB(Bb0, Bb1, k+3); LOADA(Fb, k+3); }
    }
#undef LOADB
#undef LOADA
#undef STEP

    float bias_v = colOK ? bias[colB] : 0.f;
    int rsub = 4*(lane >> 5);
    #pragma unroll
    for (int mi = 0; mi < 3; ++mi) {
        #pragma unroll
        for (int r = 0; r < 16; ++r) {
            int row_l = wave_m*96 + mi*32 + rsub + (r & 3) + 8*(r >> 2);
            int rowg = bm*192 + row_l;
            float logit = acc[mi][r] + bias_v;
            if (colOK && colB == targets[rowg]) tlogit[rowg] = logit;
            float e = colOK ? expf(logit) : 0.f;
            #pragma unroll
            for (int msk = 16; msk; msk >>= 1) e += __shfl_xor(e, msk);
            if ((lane & 31) == 0) pv_l[row_l][wave_n] = e;
        }
    }
    __syncthreads();
    if (t < 192) {
        float ss = pv_l[t][0] + pv_l[t][1] + pv_l[t][2] + pv_l[t][3];
        int rowg = bm*192 + t;
        psum[(size_t)rowg*NVB + nvb] = ss;
    }
}

// ---------------- K7: legacy direct-read k_big (ws fallback) ----------------
__global__ __launch_bounds__(512) void k_big(
    const short* __restrict__ Apack, const float* __restrict__ Wm,
    const float* __restrict__ bias, const int* __restrict__ targets,
    float* __restrict__ psum, float* __restrict__ tlogit)
{
    __shared__ float pv_l[192][4];
    int bm = blockIdx.x, nvb = blockIdx.y;
    int bn = nvb * 128;
    int t = threadIdx.x;
    int wid = t >> 6, lane = t & 63;
    int wave_m = wid >> 2, wave_n = wid & 3;
    int colB = bn + wave_n*32 + (lane & 31);
    int kOff = (lane >> 5) << 3;
    bool colOK = colB < VV;
    int mt0 = bm*6 + wave_m*3;
    const short8* ap = reinterpret_cast<const short8*>(Apack);
    floatx16 acc[3];
    #pragma unroll
    for (int mi = 0; mi < 3; ++mi)
        #pragma unroll
        for (int r = 0; r < 16; ++r) acc[mi][r] = 0.f;
    float Bq0a[8], Bq1a[8], Bq0b[8], Bq1b[8];
    short8 Fa[6], Fb[6];
#define LOADB(Q0, Q1, kst) do { \
    int kb_ = (kst)*32 + kOff; \
    _Pragma("unroll") \
    for (int j = 0; j < 8; ++j) Q0[j] = colOK ? Wm[(size_t)(kb_ + j)*VV + colB] : 0.f; \
    _Pragma("unroll") \
    for (int j = 0; j < 8; ++j) Q1[j] = colOK ? Wm[(size_t)(kb_ + 16 + j)*VV + colB] : 0.f; \
} while (0)
#define LOADA(F, kst) do { \
    _Pragma("unroll") \
    for (int mi = 0; mi < 3; ++mi) { \
        F[mi]   = ap[(size_t)(((kst)*12 + (mt0 + mi))*2 + 0)*64 + lane]; \
        F[3+mi] = ap[(size_t)(((kst)*12 + (mt0 + mi))*2 + 1)*64 + lane]; \
    } \
} while (0)
#define STEP(Q0, Q1, F) do { \
    short8 b0_, b1_; \
    _Pragma("unroll") \
    for (int j = 0; j < 8; ++j) { b0_[j] = f2bf(Q0[j]); b1_[j] = f2bf(Q1[j]); } \
    _Pragma("unroll") \
    for (int mi = 0; mi < 3; ++mi) \
        acc[mi] = __builtin_amdgcn_mfma_f32_32x32x16_bf16(F[mi], b0_, acc[mi], 0, 0, 0); \
    _Pragma("unroll") \
    for (int mi = 0; mi < 3; ++mi) \
        acc[mi] = __builtin_amdgcn_mfma_f32_32x32x16_bf16(F[3+mi], b1_, acc[mi], 0, 0, 0); \
} while (0)
    LOADB(Bq0a, Bq1a, 0); LOADA(Fa, 0);
    LOADB(Bq0b, Bq1b, 1); LOADA(Fb, 1);
    for (int k = 0; k < KSTEPS; k += 2) {
        STEP(Bq0a, Bq1a, Fa);
        if (k + 2 < KSTEPS) { LOADB(Bq0a, Bq1a, k+2); LOADA(Fa, k+2); }
        STEP(Bq0b, Bq1b, Fb);
        if (k + 3 < KSTEPS) { LOADB(Bq0b, Bq1b, k+3); LOADA(Fb, k+3); }
    }
#undef LOADB
#undef LOADA
#undef STEP
    float bias_v = colOK ? bias[colB] : 0.f;
    int rsub = 4*(lane >> 5);
    #pragma unroll
    for (int mi = 0; mi < 3; ++mi) {
        #pragma unroll
        for (int r = 0; r < 16; ++r) {
            int row_l = wave_m*96 + mi*32 + rsub + (r & 3) + 8*(r >> 2);
            int rowg = bm*192 + row_l;
            float logit = acc[mi][r] + bias_v;
            if (colOK && colB == targets[rowg]) tlogit[rowg] = logit;
            float e = colOK ? expf(logit) : 0.f;
            #pragma unroll
            for (int msk = 16; msk; msk >>= 1) e += __shfl_xor(e, msk);
            if ((lane & 31) == 0) pv_l[row_l][wave_n] = e;
        }
    }
    __syncthreads();
    if (t < 192) {
        float ss = pv_l[t][0] + pv_l[t][1] + pv_l[t][2] + pv_l[t][3];
        int rowg = bm*192 + t;
        psum[(size_t)rowg*NVB + nvb] = ss;
    }
}

// ---------------- K8: sum partials + per-token nll ----------------
__global__ __launch_bounds__(64) void k_lsum(
    const float* __restrict__ psum,
    const float* __restrict__ tlogit, const int* __restrict__ targets,
    const float* __restrict__ psw, const float* __restrict__ copysc,
    const float* __restrict__ dec_mask, float* __restrict__ nll)
{
    int pair = blockIdx.x, lane = threadIdx.x;
    float s = 0.f;
    for (int j = lane; j < NVB; j += 64) s += psum[(size_t)pair*NVB + j];
    #pragma unroll
    for (int off = 32; off; off >>= 1) s += __shfl_xor(s, off);
    if (lane == 0) {
        int tgt = targets[pair];
        float outv;
        if (tgt == UNK) outv = 1.0f;
        else {
            float base = 0.f;
            if (tgt < VV) {
                float pvv = expf(tlogit[pair]) / s;
                float pg = (tgt < VV - NPR) ? psw[pair*3] : psw[pair*3+1];
                base = pg * pvv;
            }
            outv = base + psw[pair*3+2] * copysc[pair];
        }
        outv = fmaxf(outv, 1e-38f);
        nll[pair] = -logf(outv) * dec_mask[pair];
    }
}

// ---------------- K9: final per-batch loss ----------------
__global__ __launch_bounds__(64) void k_final(
    const float* __restrict__ nll, const float* __restrict__ dec_lens, float* __restrict__ out)
{
    int b = threadIdx.x;
    if (b < BB) {
        float a = 0.f;
        for (int t = 0; t < TT; ++t) a += nll[b*TT + t];
        out[b] = a / dec_lens[b];
    }
}

extern "C" void kernel_launch(void* const* d_in, const int* in_sizes, int n_in,
                              void* d_out, int out_size, void* d_ws, size_t ws_size,
                              hipStream_t stream)
{
    const float* enc_states = (const float*)d_in[0];
    const float* enc_h0     = (const float*)d_in[1];
    const float* enc_c0     = (const float*)d_in[2];
    const unsigned char* enc_mask = (const unsigned char*)d_in[3];
    const int* article_inds = (const int*)d_in[4];
    const int* dec_input    = (const int*)d_in[5];
    const int* targets      = (const int*)d_in[6];
    const float* dec_lens   = (const float*)d_in[7];
    const float* dec_mask   = (const float*)d_in[8];
    const float* embed      = (const float*)d_in[9];
    const float* W_ih       = (const float*)d_in[10];
    const float* W_hh       = (const float*)d_in[11];
    const float* b_lstm     = (const float*)d_in[12];
    const float* Wh_w = (const float*)d_in[13]; const float* Wh_b = (const float*)d_in[14];
    const float* Ws_w = (const float*)d_in[15]; const float* Ws_b = (const float*)d_in[16];
    const float* v_w  = (const float*)d_in[17]; const float* v_b  = (const float*)d_in[18];
    const float* wh_w = (const float*)d_in[19]; const float* wh_b = (const float*)d_in[20];
    const float* ws_w = (const float*)d_in[21]; const float* ws_b = (const float*)d_in[22];
    const float* wx_w = (const float*)d_in[23]; const float* wx_b = (const float*)d_in[24];
    const float* wc_w = (const float*)d_in[25]; const float* wc_b = (const float*)d_in[26];
    const float* Vout_w = (const float*)d_in[27]; const float* Vout_b = (const float*)d_in[28];

    float* ws = (float*)d_ws;
    float* x_buf   = ws + OFF_X;
    float* hid     = ws + OFF_HID;
    float* encp    = ws + OFF_ENCP;
    float* decp    = ws + OFF_DECP;
    float* attn    = ws + OFF_ATTN;
    float* s_buf   = ws + OFF_S;
    float* psw     = ws + OFF_PSW;
    float* copysc  = ws + OFF_COPY;
    float* tlogit  = ws + OFF_TLOGIT;
    float* psum    = ws + OFF_PSUM;
    float* nll     = ws + OFF_NLL;
    short* apack   = (short*)(ws + OFF_APACK);
    float* xw      = ws + OFF_XW;
    short* whhp    = (short*)(ws + OFF_WHH);
    short* hbuf    = (short*)(ws + OFF_HFRAG);
    unsigned int* bar = (unsigned int*)(ws + OFF_BAR);
    short* bpack   = (short*)(ws + OFF_BPACK);
    // aliases inside the BPACK region (dead before k_bpack writes):
    short* apenc   = (short*)(ws + OFF_APENC);
    short* aphid   = (short*)(ws + OFF_APHID);
    short* apx     = (short*)(ws + OFF_APX);
    short* bwih    = (short*)(ws + OFF_BWIH);
    short* bwhw    = (short*)(ws + OFF_BWHW);
    short* bwsw    = (short*)(ws + OFF_BWSW);
    float* out     = (float*)d_out;

    bool use_pack = ws_size >= WS_NEEDED_BYTES;

    // 1a. embedding lookup
    k_embed<<<dim3(BT*EE/4/256), dim3(256), 0, stream>>>(embed, dec_input, x_buf);

    if (use_pack) {
        // 1b. xw = x @ W_ih + b_lstm  via MFMA
        k_apack<<<dim3(BT*EE/8/256), dim3(256), 0, stream>>>(x_buf, apx, 12, EE);
        k_wpack<<<dim3(EE*H4/8/256), dim3(256), 0, stream>>>(W_ih, bwih, EE/32, H4);
        k_gemm_mfma<<<dim3(BT/192, H4/128), dim3(512), 0, stream>>>(apx, bwih, b_lstm, xw, H4, BT/32, EE/32);
    } else {
        k_gemm_bias<<<dim3(BT/64, H4/128), dim3(256), 0, stream>>>(x_buf, W_ih, b_lstm, xw, H4, EE);
    }
    // 1c-1e. LSTM
    k_whh_pack<<<dim3(128), dim3(256), 0, stream>>>(W_hh, whhp);
    k_init<<<dim3(32), dim3(256), 0, stream>>>(enc_h0, hbuf, bar);
    k_lstm5<<<dim3(4), dim3(512), 0, stream>>>(xw, whhp, enc_c0, hbuf, bar, hid);

    if (use_pack) {
        // 2. enc_proj via MFMA
        k_apack<<<dim3(BB*LL*H2/8/256), dim3(256), 0, stream>>>(enc_states, apenc, BB*LL/32, H2);
        k_wpack<<<dim3(H2*H2/8/256), dim3(256), 0, stream>>>(Wh_w, bwhw, H2/32, H2);
        k_gemm_mfma<<<dim3(BB*LL/192, H2/128), dim3(512), 0, stream>>>(apenc, bwhw, Wh_b, encp, H2, BB*LL/32, H2/32);
        // 3. dec_proj via MFMA
        k_apack<<<dim3(BT*HH/8/256), dim3(256), 0, stream>>>(hid, aphid, 12, HH);
        k_wpack<<<dim3(HH*H2/8/256), dim3(256), 0, stream>>>(Ws_w, bwsw, HH/32, H2);
        k_gemm_mfma<<<dim3(BT/192, H2/128), dim3(512), 0, stream>>>(aphid, bwsw, Ws_b, decp, H2, BT/32, HH/32);
    } else {
        k_gemm_bias<<<dim3(BB*LL/64, H2/128), dim3(256), 0, stream>>>(enc_states, Wh_w, Wh_b, encp, H2, H2);
        k_gemm_bias<<<dim3(BT/64, H2/128), dim3(256), 0, stream>>>(hid, Ws_w, Ws_b, decp, H2, HH);
    }
    // 4. e scores
    k_e<<<dim3(BB, LL/4), dim3(256), 0, stream>>>(encp, decp, v_w, v_b, enc_mask, attn);
    // 5. softmax + context + s
    k_softmax_ctx<<<dim3(BT), dim3(256), 0, stream>>>(attn, enc_states, hid, s_buf);
    // 6. switch + copy score
    k_switch_copy<<<dim3(BT), dim3(64), 0, stream>>>(s_buf, x_buf, enc_h0,
        wh_w, wh_b, ws_w, ws_b, wx_w, wx_b, wc_w, wc_b,
        article_inds, targets, attn, psw, copysc);
    // 6.5 pack A of big GEMM
    k_apack<<<dim3(BT*H3/8/256), dim3(256), 0, stream>>>(s_buf, apack, 12, H3);
    // 7. big GEMM
    if (use_pack) {
        k_bpack<<<dim3(24, 196), dim3(256), 0, stream>>>(Vout_w, bpack);
        k_big_packed<<<dim3(2, NVB), dim3(512), 0, stream>>>(apack, bpack, Vout_b, targets, psum, tlogit);
    } else {
        k_big<<<dim3(2, NVB), dim3(512), 0, stream>>>(apack, Vout_w, Vout_b, targets, psum, tlogit);
    }
    // 8. merge + nll
    k_lsum<<<dim3(BT), dim3(64), 0, stream>>>(psum, tlogit, targets, psw, copysc, dec_mask, nll);
    // 9. final loss
    k_final<<<dim3(1), dim3(64), 0, stream>>>(nll, dec_lens, out);
}

// Round 13
// 342.756 us; speedup vs baseline: 2.0992x; 1.0496x over previous
//
#include <hip/hip_runtime.h>
#include <hip/hip_bf16.h>
#include <math.h>

// Problem constants
#define BB 32
#define LL 300
#define TT 12
#define HH 256
#define EE 128
#define VV 50000
#define OOV 30
#define NPR 6
#define UNK 1
#define H2 512   // 2H
#define H3 768   // 3H
#define H4 1024  // 4H
#define BT (BB*TT)       // 384
#define NVB 391          // ceil(50000/128)
#define KSTEPS 24        // 768/32
#define NT32P (196*8)    // padded 32-col tile count for Bpack (1568)

// ---------------- ws layout (float offsets) ----------------
#define OFF_X        0                          // BT*EE
#define OFF_HID      (OFF_X + BT*EE)            // BT*HH
#define OFF_ENCP     (OFF_HID + BT*HH)          // BB*LL*H2
#define OFF_DECP     (OFF_ENCP + BB*LL*H2)      // BT*H2
#define OFF_ATTN     (OFF_DECP + BT*H2)         // BT*LL
#define OFF_S        (OFF_ATTN + BT*LL)         // BT*H3
#define OFF_PSW      (OFF_S + BT*H3)            // BT*3
#define OFF_COPY     (OFF_PSW + BT*3)           // BT
#define OFF_TLOGIT   (OFF_COPY + BT)            // BT
#define OFF_PMAX     (OFF_TLOGIT + BT)          // BT*NVB (unused legacy)
#define OFF_PSUM     (OFF_PMAX + BT*NVB)        // BT*NVB
#define OFF_NLL      (OFF_PSUM + BT*NVB)        // BT
#define OFF_APACK    (OFF_NLL + BT)             // BT*H3 shorts (bf16) / bytes (fp8)
#define OFF_XW       (OFF_APACK + BT*H3/2)      // BT*H4 floats
#define OFF_WHH      (OFF_XW + BT*H4)           // 131072 floats
#define OFF_HFRAG    (OFF_WHH + 131072)         // 8192 floats
#define OFF_BAR      (OFF_HFRAG + 8192)         // 64 floats
#define OFF_BPACK    (OFF_BAR + 64)             // region (fp8 uses half)
#define BPACK_SHORTS ((size_t)NT32P*24*2*64*8)
#define WS_NEEDED_BYTES ((size_t)(OFF_BPACK)*4 + BPACK_SHORTS*2)
// aliases living INSIDE the BPACK region (all dead before k_bpack8 writes):
#define OFF_APENC (OFF_BPACK)                   // 9600*512 shorts = 2457600 fl
#define OFF_APHID (OFF_APENC + 2457600)         // 384*256 shorts
#define OFF_APX   (OFF_APHID + 49152)           // 384*128 shorts
#define OFF_BWIH  (OFF_APX + 24576)             // 128*1024 shorts
#define OFF_BWHW  (OFF_BWIH + 65536)            // 512*512 shorts
#define OFF_BWSW  (OFF_BWHW + 131072)           // 256*512 shorts

typedef __attribute__((ext_vector_type(8))) short short8;
typedef __attribute__((ext_vector_type(2))) int int2v;
typedef __attribute__((ext_vector_type(16))) float floatx16;

__device__ __forceinline__ short f2bf(float f) {
    __hip_bfloat16 h = __float2bfloat16(f);
    return *reinterpret_cast<short*>(&h);
}
__device__ __forceinline__ float bf2f(short s) {
    unsigned int u = ((unsigned int)(unsigned short)s) << 16;
    return __uint_as_float(u);
}
__device__ __forceinline__ float sigm(float x) { return 1.f/(1.f + expf(-x)); }

// pack 8 floats -> 8 fp8 e4m3 bytes (one i64)
__device__ __forceinline__ long pk8(const float* f) {
    int lo = __builtin_amdgcn_cvt_pk_fp8_f32(f[0], f[1], 0, 0);
    lo = __builtin_amdgcn_cvt_pk_fp8_f32(f[2], f[3], lo, 1);
    int hi = __builtin_amdgcn_cvt_pk_fp8_f32(f[4], f[5], 0, 0);
    hi = __builtin_amdgcn_cvt_pk_fp8_f32(f[6], f[7], hi, 1);
    int2v v; v[0] = lo; v[1] = hi;
    return *reinterpret_cast<long*>(&v);
}

// ---------------- K0: embedding lookup ----------------
__global__ __launch_bounds__(256) void k_embed(
    const float* __restrict__ embed, const int* __restrict__ dec_input,
    float* __restrict__ x_out)
{
    int i = blockIdx.x*256 + threadIdx.x;
    int bt = i >> 5;
    int e4 = i & 31;
    int tok = dec_input[bt];
    reinterpret_cast<float4*>(x_out)[(size_t)bt*32 + e4] =
        reinterpret_cast<const float4*>(embed)[(size_t)tok*32 + e4];
}

// ---------------- generic A-pack: A [M,K] fp32 -> 32x32x16 A-frag bf16 ------
__global__ __launch_bounds__(256) void k_apack(
    const float* __restrict__ A, short* __restrict__ Ap, int MT, int K_)
{
    int s = blockIdx.x*256 + threadIdx.x;
    int l = s & 63;
    int ks = (s >> 6) & 1;
    int rest = s >> 7;
    int mt = rest % MT;
    int kstep = rest / MT;
    int row = mt*32 + (l & 31);
    int kb = kstep*32 + ks*16 + ((l >> 5) << 3);
    const float4* src = reinterpret_cast<const float4*>(&A[(size_t)row*K_ + kb]);
    float4 a = src[0], b = src[1];
    short8 v;
    v[0]=f2bf(a.x); v[1]=f2bf(a.y); v[2]=f2bf(a.z); v[3]=f2bf(a.w);
    v[4]=f2bf(b.x); v[5]=f2bf(b.y); v[6]=f2bf(b.z); v[7]=f2bf(b.w);
    *reinterpret_cast<short8*>(Ap + (size_t)s*8) = v;
}

// ---------------- A-pack fp8: s_buf [384,768] -> fp8 A-frags ----------------
__global__ __launch_bounds__(256) void k_apack8(
    const float* __restrict__ A, long* __restrict__ Ap)
{
    int s = blockIdx.x*256 + threadIdx.x;          // 0..36863
    int l = s & 63;
    int ks = (s >> 6) & 1;
    int rest = s >> 7;
    int mt = rest % 12;
    int kstep = rest / 12;
    int row = mt*32 + (l & 31);
    int kb = kstep*32 + ks*16 + ((l >> 5) << 3);
    const float4* src = reinterpret_cast<const float4*>(&A[(size_t)row*H3 + kb]);
    float4 a = src[0], b = src[1];
    float f[8] = {a.x,a.y,a.z,a.w,b.x,b.y,b.z,b.w};
    Ap[s] = pk8(f);
}

// ---------------- generic W-pack: W [K,N] fp32 -> 32x32x16 B-frag bf16 ------
__global__ __launch_bounds__(256) void k_wpack(
    const float* __restrict__ W, short* __restrict__ Bp, int KS, int N_)
{
    int s = blockIdx.x*256 + threadIdx.x;
    int l = s & 63;
    int ks = (s >> 6) & 1;
    int rest = s >> 7;
    int kstep = rest % KS;
    int ct = rest / KS;
    int col = ct*32 + (l & 31);
    int kb = kstep*32 + ks*16 + ((l >> 5) << 3);
    short8 v;
    #pragma unroll
    for (int j = 0; j < 8; ++j) v[j] = f2bf(W[(size_t)(kb + j)*N_ + col]);
    *reinterpret_cast<short8*>(Bp + (size_t)s*8) = v;
}

// ---------------- generic packed MFMA GEMM + bias: C[M,N] fp32 --------------
__global__ __launch_bounds__(512) void k_gemm_mfma(
    const short* __restrict__ Apack, const short* __restrict__ Bpack,
    const float* __restrict__ bias, float* __restrict__ C,
    int N_, int MT, int KS)
{
    int bm = blockIdx.x, nb = blockIdx.y;
    int t = threadIdx.x;
    int wid = t >> 6, lane = t & 63;
    int wave_m = wid >> 2, wave_n = wid & 3;
    int mt0 = bm*6 + wave_m*3;
    int ct = nb*4 + wave_n;

    const short8* ap = reinterpret_cast<const short8*>(Apack);
    const short8* bp = reinterpret_cast<const short8*>(Bpack);

    floatx16 acc[3];
    #pragma unroll
    for (int mi = 0; mi < 3; ++mi)
        #pragma unroll
        for (int r = 0; r < 16; ++r) acc[mi][r] = 0.f;

    short8 Ba0, Ba1, Bb0, Bb1;
    short8 Fa[6], Fb[6];

#define LOADB(B0, B1, kst) do { \
    B0 = bp[(size_t)(((ct*KS + (kst))*2 + 0)*64 + lane)]; \
    B1 = bp[(size_t)(((ct*KS + (kst))*2 + 1)*64 + lane)]; \
} while (0)
#define LOADA(F, kst) do { \
    _Pragma("unroll") \
    for (int mi = 0; mi < 3; ++mi) { \
        F[mi]   = ap[(size_t)((((kst)*MT + (mt0 + mi))*2 + 0)*64 + lane)]; \
        F[3+mi] = ap[(size_t)((((kst)*MT + (mt0 + mi))*2 + 1)*64 + lane)]; \
    } \
} while (0)
#define STEP(B0, B1, F) do { \
    _Pragma("unroll") \
    for (int mi = 0; mi < 3; ++mi) \
        acc[mi] = __builtin_amdgcn_mfma_f32_32x32x16_bf16(F[mi], B0, acc[mi], 0, 0, 0); \
    _Pragma("unroll") \
    for (int mi = 0; mi < 3; ++mi) \
        acc[mi] = __builtin_amdgcn_mfma_f32_32x32x16_bf16(F[3+mi], B1, acc[mi], 0, 0, 0); \
} while (0)

    LOADB(Ba0, Ba1, 0); LOADA(Fa, 0);
    LOADB(Bb0, Bb1, 1); LOADA(Fb, 1);
    for (int k = 0; k < KS; k += 2) {
        STEP(Ba0, Ba1, Fa);
        if (k + 2 < KS) { LOADB(Ba0, Ba1, k+2); LOADA(Fa, k+2); }
        STEP(Bb0, Bb1, Fb);
        if (k + 3 < KS) { LOADB(Bb0, Bb1, k+3); LOADA(Fb, k+3); }
    }
#undef LOADB
#undef LOADA
#undef STEP

    int col = ct*32 + (lane & 31);
    float bias_v = bias[col];
    int rsub = 4*(lane >> 5);
    #pragma unroll
    for (int mi = 0; mi < 3; ++mi) {
        int rowg0 = bm*192 + wave_m*96 + mi*32 + rsub;
        #pragma unroll
        for (int r = 0; r < 16; ++r) {
            int rowg = rowg0 + (r & 3) + 8*(r >> 2);
            C[(size_t)rowg*N_ + col] = acc[mi][r] + bias_v;
        }
    }
}

// ---------------- fallback fp32 GEMM + bias ----------------
__global__ __launch_bounds__(256) void k_gemm_bias(
    const float* __restrict__ A, const float* __restrict__ Wm,
    const float* __restrict__ bias, float* __restrict__ C, int N_, int K_)
{
    __shared__ float As[64][17];
    __shared__ __align__(16) float Bs[16][128];
    int bm = blockIdx.x*64, bn = blockIdx.y*128;
    int tid = threadIdx.x, tr = tid >> 4, tc = tid & 15;
    float acc[4][8] = {};
    for (int k0 = 0; k0 < K_; k0 += 16) {
        for (int i = tid; i < 64*16; i += 256) { int r = i >> 4, c = i & 15; As[r][c] = A[(size_t)(bm+r)*K_ + k0 + c]; }
        for (int i = tid; i < 16*128; i += 256) { int r = i >> 7, c = i & 127; Bs[r][c] = Wm[(size_t)(k0+r)*N_ + bn + c]; }
        __syncthreads();
        #pragma unroll
        for (int kk = 0; kk < 16; ++kk) {
            float a0 = As[tr*4+0][kk], a1 = As[tr*4+1][kk], a2 = As[tr*4+2][kk], a3 = As[tr*4+3][kk];
            const float4* bpx = reinterpret_cast<const float4*>(&Bs[kk][tc*8]);
            float4 q0 = bpx[0], q1 = bpx[1];
            float bb[8] = {q0.x,q0.y,q0.z,q0.w,q1.x,q1.y,q1.z,q1.w};
            #pragma unroll
            for (int j = 0; j < 8; ++j) {
                acc[0][j] += a0*bb[j]; acc[1][j] += a1*bb[j];
                acc[2][j] += a2*bb[j]; acc[3][j] += a3*bb[j];
            }
        }
        __syncthreads();
    }
    for (int i = 0; i < 4; ++i) {
        int r = bm + tr*4 + i;
        for (int j = 0; j < 8; ++j) {
            int c = bn + tc*8 + j;
            C[(size_t)r*N_ + c] = acc[i][j] + bias[c];
        }
    }
}

// ---------------- W_hh -> per-block-sliced 32x32x16 B-frag order ------------
__global__ __launch_bounds__(256) void k_whh_pack(
    const float* __restrict__ Whh, short* __restrict__ wp)
{
    int s = blockIdx.x*256 + threadIdx.x;      // 0..32767
    int l = s & 63;
    int kstep = (s >> 6) & 15;
    int ct_l = (s >> 10) & 7;
    int q = s >> 13;
    int col = (ct_l >> 1)*256 + q*64 + (ct_l & 1)*32 + (l & 31);
    int kb = kstep*16 + ((l >> 5) << 3);
    short8 v;
    #pragma unroll
    for (int j = 0; j < 8; ++j) v[j] = f2bf(Whh[(size_t)(kb + j)*H4 + col]);
    *reinterpret_cast<short8*>(wp + (size_t)s*8) = v;
}

// ---------------- init h0 -> hfrag buf0 + zero barriers ----------------
__global__ __launch_bounds__(256) void k_init(
    const float* __restrict__ h0, short* __restrict__ hbuf0,
    unsigned int* __restrict__ bar)
{
    int gid = blockIdx.x*256 + threadIdx.x;    // 0..8191
    int r = gid >> 8;
    int hidx = gid & 255;
    int kstep = hidx >> 4;
    int kk = hidx & 15;
    int l = ((kk >> 3) << 5) + r;
    hbuf0[(size_t)(kstep*64 + l)*8 + (kk & 7)] = f2bf(h0[r*HH + hidx]);
    if (blockIdx.x == 0 && threadIdx.x < 64) bar[threadIdx.x] = 0u;
}

// ---------------- column-split MFMA LSTM, 4 blocks, W-slice in LDS ----------
__global__ __launch_bounds__(512) void k_lstm5(
    const float* __restrict__ xw, const short* __restrict__ whhp,
    const float* __restrict__ c0, short* __restrict__ hbuf,
    unsigned int* __restrict__ bar, float* __restrict__ hid_out)
{
    __shared__ short wlds[8*16*64*8];   // 128 KB
    __shared__ short g_lds[32][256];    // 16 KB
    __shared__ float c_lds[32][64];     // 8 KB
    int tid = threadIdx.x, wid = tid >> 6, lane = tid & 63;
    int q = blockIdx.x;

    {
        const short8* wp8 = reinterpret_cast<const short8*>(whhp);
        for (int i = tid; i < 8192; i += 512)
            *reinterpret_cast<short8*>(&wlds[i*8]) = wp8[(size_t)q*8192 + i];
    }
    for (int i = tid; i < 32*64; i += 512) {
        int b = i >> 6, jj = i & 63;
        c_lds[b][jj] = c0[b*HH + q*64 + jj];
    }
    __syncthreads();

    for (int t = 0; t < TT; ++t) {
        const short* hcur = hbuf + (size_t)(t & 1)*8192;
        short* hnxt = hbuf + (size_t)((t + 1) & 1)*8192;

        floatx16 acc;
        #pragma unroll
        for (int r = 0; r < 16; ++r) acc[r] = 0.f;
        #pragma unroll
        for (int kstep = 0; kstep < 16; ++kstep) {
            short8 af = *reinterpret_cast<const short8*>(&hcur[(size_t)(kstep*64 + lane)*8]);
            short8 bf = *reinterpret_cast<const short8*>(&wlds[((wid*16 + kstep)*64 + lane)*8]);
            acc = __builtin_amdgcn_mfma_f32_32x32x16_bf16(af, bf, acc, 0, 0, 0);
        }
        int gcol = (wid >> 1)*256 + q*64 + (wid & 1)*32 + (lane & 31);
        int lcol = wid*32 + (lane & 31);
        #pragma unroll
        for (int r = 0; r < 16; ++r) {
            int row = (r & 3) + 8*(r >> 2) + 4*(lane >> 5);
            g_lds[row][lcol] = f2bf(acc[r] + xw[(size_t)(row*TT + t)*H4 + gcol]);
        }
        __syncthreads();
        for (int i = tid; i < 2048; i += 512) {
            int b = i >> 6, jj = i & 63;
            float gi = bf2f(g_lds[b][((0*2 + (jj>>5))<<5) + (jj & 31)]);
            float gf = bf2f(g_lds[b][((1*2 + (jj>>5))<<5) + (jj & 31)]);
            float gg = bf2f(g_lds[b][((2*2 + (jj>>5))<<5) + (jj & 31)]);
            float go = bf2f(g_lds[b][((3*2 + (jj>>5))<<5) + (jj & 31)]);
            float c = sigm(gf)*c_lds[b][jj] + sigm(gi)*tanhf(gg);
            float h = sigm(go)*tanhf(c);
            c_lds[b][jj] = c;
            int hidx = q*64 + jj;
            hid_out[(size_t)(b*TT + t)*HH + hidx] = h;
            int kk = hidx & 15;
            int l2 = ((kk >> 3) << 5) + b;
            hnxt[(size_t)((hidx >> 4)*64 + l2)*8 + (kk & 7)] = f2bf(h);
        }
        __threadfence();
        __syncthreads();
        if (tid == 0) {
            atomicAdd(&bar[t], 1u);
            while (atomicAdd(&bar[t], 0u) < 4u) __builtin_amdgcn_s_sleep(2);
        }
        __syncthreads();
        __threadfence();
    }
}

// ---------------- K4: e scores ----------------
__global__ __launch_bounds__(256) void k_e(
    const float* __restrict__ enc_proj, const float* __restrict__ dec_proj,
    const float* __restrict__ v_w, const float* __restrict__ v_b,
    const unsigned char* __restrict__ enc_mask, float* __restrict__ e_out)
{
    int b = blockIdx.x, lbase = blockIdx.y*4;
    __shared__ float decp[TT*H2];
    int tid = threadIdx.x;
    for (int i = tid; i < TT*H2; i += 256) decp[i] = dec_proj[(size_t)b*TT*H2 + i];
    __syncthreads();
    int wave = tid >> 6, lane = tid & 63;
    int l = lbase + wave;
    const float* er = &enc_proj[(size_t)(b*LL + l)*H2];
    float ep[8], vw[8];
    #pragma unroll
    for (int k = 0; k < 8; ++k) { int e = lane + 64*k; ep[k] = er[e]; vw[k] = v_w[e]; }
    float vb = v_b[0];
    bool masked = enc_mask[b*LL + l] != 0;
    for (int t = 0; t < TT; ++t) {
        float acc = 0.f;
        #pragma unroll
        for (int k = 0; k < 8; ++k) {
            int e = lane + 64*k;
            acc += vw[k] * tanhf(ep[k] + decp[t*H2 + e]);
        }
        #pragma unroll
        for (int off = 32; off; off >>= 1) acc += __shfl_xor(acc, off);
        if (lane == 0)
            e_out[(size_t)(b*TT + t)*LL + l] = masked ? -INFINITY : (acc + vb);
    }
}

// ---------------- K5: softmax over L + context + s ----------------
__global__ __launch_bounds__(256) void k_softmax_ctx(
    float* __restrict__ attn, const float* __restrict__ enc_states,
    const float* __restrict__ hidden, float* __restrict__ s_out)
{
    int bt = blockIdx.x, b = bt / TT, tid = threadIdx.x;
    __shared__ float a[LL];
    __shared__ float red[256];
    float m = -INFINITY;
    for (int l = tid; l < LL; l += 256) m = fmaxf(m, attn[(size_t)bt*LL + l]);
    red[tid] = m; __syncthreads();
    for (int s = 128; s; s >>= 1) { if (tid < s) red[tid] = fmaxf(red[tid], red[tid+s]); __syncthreads(); }
    m = red[0]; __syncthreads();
    float sum = 0.f;
    for (int l = tid; l < LL; l += 256) { float w = expf(attn[(size_t)bt*LL + l] - m); a[l] = w; sum += w; }
    red[tid] = sum; __syncthreads();
    for (int s = 128; s; s >>= 1) { if (tid < s) red[tid] += red[tid+s]; __syncthreads(); }
    float inv = 1.0f / red[0];
    __syncthreads();
    for (int l = tid; l < LL; l += 256) { float w = a[l]*inv; a[l] = w; attn[(size_t)bt*LL + l] = w; }
    __syncthreads();
    for (int c = tid; c < H2; c += 256) {
        float acc = 0.f;
        const float* es = &enc_states[(size_t)b*LL*H2 + c];
        for (int l = 0; l < LL; ++l) acc += a[l] * es[(size_t)l*H2];
        s_out[(size_t)bt*H3 + HH + c] = acc;
    }
    for (int c = tid; c < HH; c += 256) s_out[(size_t)bt*H3 + c] = hidden[(size_t)bt*HH + c];
}

// ---------------- K6: switch softmax + copy score ----------------
__global__ __launch_bounds__(64) void k_switch_copy(
    const float* __restrict__ s, const float* __restrict__ x,
    const float* __restrict__ enc_h0,
    const float* __restrict__ wh_w, const float* __restrict__ wh_b,
    const float* __restrict__ ws_w, const float* __restrict__ ws_b,
    const float* __restrict__ wx_w, const float* __restrict__ wx_b,
    const float* __restrict__ wc_w, const float* __restrict__ wc_b,
    const int* __restrict__ article_inds, const int* __restrict__ targets,
    const float* __restrict__ attn, float* __restrict__ psw, float* __restrict__ copysc)
{
    int bt = blockIdx.x, b = bt / TT, lane = threadIdx.x;
    float s0 = 0.f, s1 = 0.f, s2 = 0.f;
    const float* ctx = &s[(size_t)bt*H3 + HH];
    const float* hid = &s[(size_t)bt*H3];
    for (int k = lane; k < H2; k += 64) { float v = ctx[k]; s0 += v*wh_w[k*3]; s1 += v*wh_w[k*3+1]; s2 += v*wh_w[k*3+2]; }
    for (int k = lane; k < HH; k += 64) { float v = hid[k]; s0 += v*ws_w[k*3]; s1 += v*ws_w[k*3+1]; s2 += v*ws_w[k*3+2]; }
    for (int k = lane; k < EE; k += 64) { float v = x[(size_t)bt*EE + k]; s0 += v*wx_w[k*3]; s1 += v*wx_w[k*3+1]; s2 += v*wx_w[k*3+2]; }
    for (int k = lane; k < HH; k += 64) { float v = enc_h0[b*HH + k]; s0 += v*wc_w[k*3]; s1 += v*wc_w[k*3+1]; s2 += v*wc_w[k*3+2]; }
    #pragma unroll
    for (int off = 32; off; off >>= 1) {
        s0 += __shfl_xor(s0, off); s1 += __shfl_xor(s1, off); s2 += __shfl_xor(s2, off);
    }
    if (lane == 0) {
        s0 += wh_b[0] + ws_b[0] + wx_b[0] + wc_b[0];
        s1 += wh_b[1] + ws_b[1] + wx_b[1] + wc_b[1];
        s2 += wh_b[2] + ws_b[2] + wx_b[2] + wc_b[2];
        float mm = fmaxf(s0, fmaxf(s1, s2));
        float e0 = expf(s0-mm), e1 = expf(s1-mm), e2 = expf(s2-mm);
        float inv = 1.f/(e0+e1+e2);
        psw[bt*3+0] = e0*inv; psw[bt*3+1] = e1*inv; psw[bt*3+2] = e2*inv;
    }
    int tgt = targets[bt];
    float cs = 0.f;
    for (int l = lane; l < LL; l += 64)
        if (article_inds[b*LL + l] == tgt) cs += attn[(size_t)bt*LL + l];
    #pragma unroll
    for (int off = 32; off; off >>= 1) cs += __shfl_xor(cs, off);
    if (lane == 0) copysc[bt] = cs;
}

// ---------------- K_bpack8: Vout_w -> fp8 B-frag order (LDS transpose) ------
// grid (24, 196), 256 thr. tile stored as fp8 bytes in dword rows.
__global__ __launch_bounds__(256) void k_bpack8(
    const float* __restrict__ Wm, unsigned char* __restrict__ Bp)
{
    __shared__ unsigned int tile[32][66];      // 32 rows x 256 fp8 bytes (+pad)
    int kstep = blockIdx.x, cblk = blockIdx.y;
    int tid = threadIdx.x;
    int cbase = cblk*256;
    for (int i = tid; i < 32*64; i += 256) {
        int r = i >> 6, c4 = i & 63;
        int col = cbase + c4*4;
        float4 v = make_float4(0.f,0.f,0.f,0.f);
        if (col < VV)
            v = *reinterpret_cast<const float4*>(&Wm[(size_t)(kstep*32 + r)*VV + col]);
        int w = __builtin_amdgcn_cvt_pk_fp8_f32(v.x, v.y, 0, 0);
        w = __builtin_amdgcn_cvt_pk_fp8_f32(v.z, v.w, w, 1);
        tile[r][c4] = (unsigned int)w;
    }
    __syncthreads();
    int wave = tid >> 6, l = tid & 63;
    const unsigned char* tb = reinterpret_cast<const unsigned char*>(tile);
    #pragma unroll
    for (int it = 0; it < 4; ++it) {
        int fid = wave*4 + it;
        int ct_l = fid >> 1, ks = fid & 1;
        int rbase = ks*16 + ((l >> 5) << 3);
        int c = ct_l*32 + (l & 31);
        unsigned int lo = 0, hi = 0;
        #pragma unroll
        for (int j = 0; j < 4; ++j)
            lo |= (unsigned int)tb[(rbase + j)*264 + c] << (8*j);
        #pragma unroll
        for (int j = 0; j < 4; ++j)
            hi |= (unsigned int)tb[(rbase + 4 + j)*264 + c] << (8*j);
        size_t ct_g = (size_t)cblk*8 + ct_l;
        unsigned int* dst = reinterpret_cast<unsigned int*>(
            &Bp[(((ct_g*24 + kstep)*2 + ks)*64 + l)*8]);
        dst[0] = lo; dst[1] = hi;
    }
}

// ---------------- K7c: fp8 MFMA big GEMM, 4-deep prefetch + exp partials ----
__global__ __launch_bounds__(512) void k_big_fp8(
    const long* __restrict__ Apack, const long* __restrict__ Bp,
    const float* __restrict__ bias, const int* __restrict__ targets,
    float* __restrict__ psum, float* __restrict__ tlogit)
{
    __shared__ float pv_l[192][4];
    int bm = blockIdx.x, nvb = blockIdx.y;
    int bn = nvb * 128;
    int t = threadIdx.x;
    int wid = t >> 6, lane = t & 63;
    int wave_m = wid >> 2, wave_n = wid & 3;
    size_t ct_g = (size_t)nvb*4 + wave_n;
    int colB = bn + wave_n*32 + (lane & 31);
    bool colOK = colB < VV;
    int mt0 = bm*6 + wave_m*3;

    floatx16 acc[3];
    #pragma unroll
    for (int mi = 0; mi < 3; ++mi)
        #pragma unroll
        for (int r = 0; r < 16; ++r) acc[mi][r] = 0.f;

    long B0a, B1a, B0b, B1b, B0c, B1c, B0d, B1d;
    long Fa[6], Fb[6], Fc[6], Fd[6];

#define LOADB(B0, B1, kst) do { \
    B0 = Bp[(ct_g*24 + (kst))*2*64 + 0*64 + lane]; \
    B1 = Bp[(ct_g*24 + (kst))*2*64 + 1*64 + lane]; \
} while (0)
#define LOADA(F, kst) do { \
    _Pragma("unroll") \
    for (int mi = 0; mi < 3; ++mi) { \
        F[mi]   = Apack[(size_t)(((kst)*12 + (mt0 + mi))*2 + 0)*64 + lane]; \
        F[3+mi] = Apack[(size_t)(((kst)*12 + (mt0 + mi))*2 + 1)*64 + lane]; \
    } \
} while (0)
#define STEP(B0, B1, F) do { \
    _Pragma("unroll") \
    for (int mi = 0; mi < 3; ++mi) \
        acc[mi] = __builtin_amdgcn_mfma_f32_32x32x16_fp8_fp8(F[mi], B0, acc[mi], 0, 0, 0); \
    _Pragma("unroll") \
    for (int mi = 0; mi < 3; ++mi) \
        acc[mi] = __builtin_amdgcn_mfma_f32_32x32x16_fp8_fp8(F[3+mi], B1, acc[mi], 0, 0, 0); \
} while (0)

    LOADB(B0a, B1a, 0); LOADA(Fa, 0);
    LOADB(B0b, B1b, 1); LOADA(Fb, 1);
    LOADB(B0c, B1c, 2); LOADA(Fc, 2);
    LOADB(B0d, B1d, 3); LOADA(Fd, 3);
    for (int k = 0; k < KSTEPS; k += 4) {
        STEP(B0a, B1a, Fa);
        if (k + 4 < KSTEPS) { LOADB(B0a, B1a, k+4); LOADA(Fa, k+4); }
        STEP(B0b, B1b, Fb);
        if (k + 5 < KSTEPS) { LOADB(B0b, B1b, k+5); LOADA(Fb, k+5); }
        STEP(B0c, B1c, Fc);
        if (k + 6 < KSTEPS) { LOADB(B0c, B1c, k+6); LOADA(Fc, k+6); }
        STEP(B0d, B1d, Fd);
        if (k + 7 < KSTEPS) { LOADB(B0d, B1d, k+7); LOADA(Fd, k+7); }
    }
#undef LOADB
#undef LOADA
#undef STEP

    float bias_v = colOK ? bias[colB] : 0.f;
    int rsub = 4*(lane >> 5);
    #pragma unroll
    for (int mi = 0; mi < 3; ++mi) {
        #pragma unroll
        for (int r = 0; r < 16; ++r) {
            int row_l = wave_m*96 + mi*32 + rsub + (r & 3) + 8*(r >> 2);
            int rowg = bm*192 + row_l;
            float logit = acc[mi][r] + bias_v;
            if (colOK && colB == targets[rowg]) tlogit[rowg] = logit;
            float e = colOK ? expf(logit) : 0.f;
            #pragma unroll
            for (int msk = 16; msk; msk >>= 1) e += __shfl_xor(e, msk);
            if ((lane & 31) == 0) pv_l[row_l][wave_n] = e;
        }
    }
    __syncthreads();
    if (t < 192) {
        float ss = pv_l[t][0] + pv_l[t][1] + pv_l[t][2] + pv_l[t][3];
        int rowg = bm*192 + t;
        psum[(size_t)rowg*NVB + nvb] = ss;
    }
}

// ---------------- K7: legacy direct-read k_big (ws fallback, bf16) ----------
__global__ __launch_bounds__(512) void k_big(
    const short* __restrict__ Apack, const float* __restrict__ Wm,
    const float* __restrict__ bias, const int* __restrict__ targets,
    float* __restrict__ psum, float* __restrict__ tlogit)
{
    __shared__ float pv_l[192][4];
    int bm = blockIdx.x, nvb = blockIdx.y;
    int bn = nvb * 128;
    int t = threadIdx.x;
    int wid = t >> 6, lane = t & 63;
    int wave_m = wid >> 2, wave_n = wid & 3;
    int colB = bn + wave_n*32 + (lane & 31);
    int kOff = (lane >> 5) << 3;
    bool colOK = colB < VV;
    int mt0 = bm*6 + wave_m*3;
    const short8* ap = reinterpret_cast<const short8*>(Apack);
    floatx16 acc[3];
    #pragma unroll
    for (int mi = 0; mi < 3; ++mi)
        #pragma unroll
        for (int r = 0; r < 16; ++r) acc[mi][r] = 0.f;
    float Bq0a[8], Bq1a[8], Bq0b[8], Bq1b[8];
    short8 Fa[6], Fb[6];
#define LOADB(Q0, Q1, kst) do { \
    int kb_ = (kst)*32 + kOff; \
    _Pragma("unroll") \
    for (int j = 0; j < 8; ++j) Q0[j] = colOK ? Wm[(size_t)(kb_ + j)*VV + colB] : 0.f; \
    _Pragma("unroll") \
    for (int j = 0; j < 8; ++j) Q1[j] = colOK ? Wm[(size_t)(kb_ + 16 + j)*VV + colB] : 0.f; \
} while (0)
#define LOADA(F, kst) do { \
    _Pragma("unroll") \
    for (int mi = 0; mi < 3; ++mi) { \
        F[mi]   = ap[(size_t)(((kst)*12 + (mt0 + mi))*2 + 0)*64 + lane]; \
        F[3+mi] = ap[(size_t)(((kst)*12 + (mt0 + mi))*2 + 1)*64 + lane]; \
    } \
} while (0)
#define STEP(Q0, Q1, F) do { \
    short8 b0_, b1_; \
    _Pragma("unroll") \
    for (int j = 0; j < 8; ++j) { b0_[j] = f2bf(Q0[j]); b1_[j] = f2bf(Q1[j]); } \
    _Pragma("unroll") \
    for (int mi = 0; mi < 3; ++mi) \
        acc[mi] = __builtin_amdgcn_mfma_f32_32x32x16_bf16(F[mi], b0_, acc[mi], 0, 0, 0); \
    _Pragma("unroll") \
    for (int mi = 0; mi < 3; ++mi) \
        acc[mi] = __builtin_amdgcn_mfma_f32_32x32x16_bf16(F[3+mi], b1_, acc[mi], 0, 0, 0); \
} while (0)
    LOADB(Bq0a, Bq1a, 0); LOADA(Fa, 0);
    LOADB(Bq0b, Bq1b, 1); LOADA(Fb, 1);
    for (int k = 0; k < KSTEPS; k += 2) {
        STEP(Bq0a, Bq1a, Fa);
        if (k + 2 < KSTEPS) { LOADB(Bq0a, Bq1a, k+2); LOADA(Fa, k+2); }
        STEP(Bq0b, Bq1b, Fb);
        if (k + 3 < KSTEPS) { LOADB(Bq0b, Bq1b, k+3); LOADA(Fb, k+3); }
    }
#undef LOADB
#undef LOADA
#undef STEP
    float bias_v = colOK ? bias[colB] : 0.f;
    int rsub = 4*(lane >> 5);
    #pragma unroll
    for (int mi = 0; mi < 3; ++mi) {
        #pragma unroll
        for (int r = 0; r < 16; ++r) {
            int row_l = wave_m*96 + mi*32 + rsub + (r & 3) + 8*(r >> 2);
            int rowg = bm*192 + row_l;
            float logit = acc[mi][r] + bias_v;
            if (colOK && colB == targets[rowg]) tlogit[rowg] = logit;
            float e = colOK ? expf(logit) : 0.f;
            #pragma unroll
            for (int msk = 16; msk; msk >>= 1) e += __shfl_xor(e, msk);
            if ((lane & 31) == 0) pv_l[row_l][wave_n] = e;
        }
    }
    __syncthreads();
    if (t < 192) {
        float ss = pv_l[t][0] + pv_l[t][1] + pv_l[t][2] + pv_l[t][3];
        int rowg = bm*192 + t;
        psum[(size_t)rowg*NVB + nvb] = ss;
    }
}

// ---------------- K8: sum partials + per-token nll ----------------
__global__ __launch_bounds__(64) void k_lsum(
    const float* __restrict__ psum,
    const float* __restrict__ tlogit, const int* __restrict__ targets,
    const float* __restrict__ psw, const float* __restrict__ copysc,
    const float* __restrict__ dec_mask, float* __restrict__ nll)
{
    int pair = blockIdx.x, lane = threadIdx.x;
    float s = 0.f;
    for (int j = lane; j < NVB; j += 64) s += psum[(size_t)pair*NVB + j];
    #pragma unroll
    for (int off = 32; off; off >>= 1) s += __shfl_xor(s, off);
    if (lane == 0) {
        int tgt = targets[pair];
        float outv;
        if (tgt == UNK) outv = 1.0f;
        else {
            float base = 0.f;
            if (tgt < VV) {
                float pvv = expf(tlogit[pair]) / s;
                float pg = (tgt < VV - NPR) ? psw[pair*3] : psw[pair*3+1];
                base = pg * pvv;
            }
            outv = base + psw[pair*3+2] * copysc[pair];
        }
        outv = fmaxf(outv, 1e-38f);
        nll[pair] = -logf(outv) * dec_mask[pair];
    }
}

// ---------------- K9: final per-batch loss ----------------
__global__ __launch_bounds__(64) void k_final(
    const float* __restrict__ nll, const float* __restrict__ dec_lens, float* __restrict__ out)
{
    int b = threadIdx.x;
    if (b < BB) {
        float a = 0.f;
        for (int t = 0; t < TT; ++t) a += nll[b*TT + t];
        out[b] = a / dec_lens[b];
    }
}

extern "C" void kernel_launch(void* const* d_in, const int* in_sizes, int n_in,
                              void* d_out, int out_size, void* d_ws, size_t ws_size,
                              hipStream_t stream)
{
    const float* enc_states = (const float*)d_in[0];
    const float* enc_h0     = (const float*)d_in[1];
    const float* enc_c0     = (const float*)d_in[2];
    const unsigned char* enc_mask = (const unsigned char*)d_in[3];
    const int* article_inds = (const int*)d_in[4];
    const int* dec_input    = (const int*)d_in[5];
    const int* targets      = (const int*)d_in[6];
    const float* dec_lens   = (const float*)d_in[7];
    const float* dec_mask   = (const float*)d_in[8];
    const float* embed      = (const float*)d_in[9];
    const float* W_ih       = (const float*)d_in[10];
    const float* W_hh       = (const float*)d_in[11];
    const float* b_lstm     = (const float*)d_in[12];
    const float* Wh_w = (const float*)d_in[13]; const float* Wh_b = (const float*)d_in[14];
    const float* Ws_w = (const float*)d_in[15]; const float* Ws_b = (const float*)d_in[16];
    const float* v_w  = (const float*)d_in[17]; const float* v_b  = (const float*)d_in[18];
    const float* wh_w = (const float*)d_in[19]; const float* wh_b = (const float*)d_in[20];
    const float* ws_w = (const float*)d_in[21]; const float* ws_b = (const float*)d_in[22];
    const float* wx_w = (const float*)d_in[23]; const float* wx_b = (const float*)d_in[24];
    const float* wc_w = (const float*)d_in[25]; const float* wc_b = (const float*)d_in[26];
    const float* Vout_w = (const float*)d_in[27]; const float* Vout_b = (const float*)d_in[28];

    float* ws = (float*)d_ws;
    float* x_buf   = ws + OFF_X;
    float* hid     = ws + OFF_HID;
    float* encp    = ws + OFF_ENCP;
    float* decp    = ws + OFF_DECP;
    float* attn    = ws + OFF_ATTN;
    float* s_buf   = ws + OFF_S;
    float* psw     = ws + OFF_PSW;
    float* copysc  = ws + OFF_COPY;
    float* tlogit  = ws + OFF_TLOGIT;
    float* psum    = ws + OFF_PSUM;
    float* nll     = ws + OFF_NLL;
    short* apack   = (short*)(ws + OFF_APACK);
    long*  apack8  = (long*)(ws + OFF_APACK);
    float* xw      = ws + OFF_XW;
    short* whhp    = (short*)(ws + OFF_WHH);
    short* hbuf    = (short*)(ws + OFF_HFRAG);
    unsigned int* bar = (unsigned int*)(ws + OFF_BAR);
    unsigned char* bpack8 = (unsigned char*)(ws + OFF_BPACK);
    // aliases inside the BPACK region (dead before k_bpack8 writes):
    short* apenc   = (short*)(ws + OFF_APENC);
    short* aphid   = (short*)(ws + OFF_APHID);
    short* apx     = (short*)(ws + OFF_APX);
    short* bwih    = (short*)(ws + OFF_BWIH);
    short* bwhw    = (short*)(ws + OFF_BWHW);
    short* bwsw    = (short*)(ws + OFF_BWSW);
    float* out     = (float*)d_out;

    bool use_pack = ws_size >= WS_NEEDED_BYTES;

    // 1a. embedding lookup
    k_embed<<<dim3(BT*EE/4/256), dim3(256), 0, stream>>>(embed, dec_input, x_buf);

    if (use_pack) {
        // 1b. xw = x @ W_ih + b_lstm  via MFMA
        k_apack<<<dim3(BT*EE/8/256), dim3(256), 0, stream>>>(x_buf, apx, 12, EE);
        k_wpack<<<dim3(EE*H4/8/256), dim3(256), 0, stream>>>(W_ih, bwih, EE/32, H4);
        k_gemm_mfma<<<dim3(BT/192, H4/128), dim3(512), 0, stream>>>(apx, bwih, b_lstm, xw, H4, BT/32, EE/32);
    } else {
        k_gemm_bias<<<dim3(BT/64, H4/128), dim3(256), 0, stream>>>(x_buf, W_ih, b_lstm, xw, H4, EE);
    }
    // 1c-1e. LSTM
    k_whh_pack<<<dim3(128), dim3(256), 0, stream>>>(W_hh, whhp);
    k_init<<<dim3(32), dim3(256), 0, stream>>>(enc_h0, hbuf, bar);
    k_lstm5<<<dim3(4), dim3(512), 0, stream>>>(xw, whhp, enc_c0, hbuf, bar, hid);

    if (use_pack) {
        // 2. enc_proj via MFMA
        k_apack<<<dim3(BB*LL*H2/8/256), dim3(256), 0, stream>>>(enc_states, apenc, BB*LL/32, H2);
        k_wpack<<<dim3(H2*H2/8/256), dim3(256), 0, stream>>>(Wh_w, bwhw, H2/32, H2);
        k_gemm_mfma<<<dim3(BB*LL/192, H2/128), dim3(512), 0, stream>>>(apenc, bwhw, Wh_b, encp, H2, BB*LL/32, H2/32);
        // 3. dec_proj via MFMA
        k_apack<<<dim3(BT*HH/8/256), dim3(256), 0, stream>>>(hid, aphid, 12, HH);
        k_wpack<<<dim3(HH*H2/8/256), dim3(256), 0, stream>>>(Ws_w, bwsw, HH/32, H2);
        k_gemm_mfma<<<dim3(BT/192, H2/128), dim3(512), 0, stream>>>(aphid, bwsw, Ws_b, decp, H2, BT/32, HH/32);
    } else {
        k_gemm_bias<<<dim3(BB*LL/64, H2/128), dim3(256), 0, stream>>>(enc_states, Wh_w, Wh_b, encp, H2, H2);
        k_gemm_bias<<<dim3(BT/64, H2/128), dim3(256), 0, stream>>>(hid, Ws_w, Ws_b, decp, H2, HH);
    }
    // 4. e scores
    k_e<<<dim3(BB, LL/4), dim3(256), 0, stream>>>(encp, decp, v_w, v_b, enc_mask, attn);
    // 5. softmax + context + s
    k_softmax_ctx<<<dim3(BT), dim3(256), 0, stream>>>(attn, enc_states, hid, s_buf);
    // 6. switch + copy score
    k_switch_copy<<<dim3(BT), dim3(64), 0, stream>>>(s_buf, x_buf, enc_h0,
        wh_w, wh_b, ws_w, ws_b, wx_w, wx_b, wc_w, wc_b,
        article_inds, targets, attn, psw, copysc);
    // 7. big GEMM (fp8 path) or fallback
    if (use_pack) {
        k_apack8<<<dim3(BT*H3/8/256), dim3(256), 0, stream>>>(s_buf, apack8);
        k_bpack8<<<dim3(24, 196), dim3(256), 0, stream>>>(Vout_w, bpack8);
        k_big_fp8<<<dim3(2, NVB), dim3(512), 0, stream>>>(apack8, (const long*)bpack8, Vout_b, targets, psum, tlogit);
    } else {
        k_apack<<<dim3(BT*H3/8/256), dim3(256), 0, stream>>>(s_buf, apack, 12, H3);
        k_big<<<dim3(2, NVB), dim3(512), 0, stream>>>(apack, Vout_w, Vout_b, targets, psum, tlogit);
    }
    // 8. merge + nll
    k_lsum<<<dim3(BT), dim3(64), 0, stream>>>(psum, tlogit, targets, psw, copysc, dec_mask, nll);
    // 9. final loss
    k_final<<<dim3(1), dim3(64), 0, stream>>>(nll, dec_lens, out);
}

// Round 15
// 342.494 us; speedup vs baseline: 2.1008x; 1.0008x over previous
//
#include <hip/hip_runtime.h>
#include <hip/hip_bf16.h>
#include <math.h>

// Problem constants
#define BB 32
#define LL 300
#define TT 12
#define HH 256
#define EE 128
#define VV 50000
#define OOV 30
#define NPR 6
#define UNK 1
#define H2 512   // 2H
#define H3 768   // 3H
#define H4 1024  // 4H
#define BT (BB*TT)       // 384
#define NVB 391          // ceil(50000/128)
#define KSTEPS 24        // 768/32
#define NT32P (196*8)    // padded 32-col tile count for Bpack (1568)

// ---------------- ws layout (float offsets) ----------------
#define OFF_X        0                          // BT*EE
#define OFF_HID      (OFF_X + BT*EE)            // BT*HH
#define OFF_ENCP     (OFF_HID + BT*HH)          // BB*LL*H2
#define OFF_DECP     (OFF_ENCP + BB*LL*H2)      // BT*H2
#define OFF_ATTN     (OFF_DECP + BT*H2)         // BT*LL
#define OFF_S        (OFF_ATTN + BT*LL)         // BT*H3
#define OFF_PSW      (OFF_S + BT*H3)            // BT*3
#define OFF_COPY     (OFF_PSW + BT*3)           // BT
#define OFF_TLOGIT   (OFF_COPY + BT)            // BT
#define OFF_PMAX     (OFF_TLOGIT + BT)          // BT*NVB (unused legacy)
#define OFF_PSUM     (OFF_PMAX + BT*NVB)        // BT*NVB
#define OFF_NLL      (OFF_PSUM + BT*NVB)        // BT
#define OFF_APACK    (OFF_NLL + BT)             // BT*H3 shorts (bf16) / bytes (fp8)
#define OFF_XW       (OFF_APACK + BT*H3/2)      // BT*H4 floats
#define OFF_WHH      (OFF_XW + BT*H4)           // 131072 floats
#define OFF_HFRAG    (OFF_WHH + 131072)         // 8192 floats
#define OFF_BAR      (OFF_HFRAG + 8192)         // 64 floats
#define OFF_BPACK    (OFF_BAR + 64)             // region (fp8 uses half)
#define BPACK_SHORTS ((size_t)NT32P*24*2*64*8)
#define WS_NEEDED_BYTES ((size_t)(OFF_BPACK)*4 + BPACK_SHORTS*2)
// aliases living INSIDE the BPACK region (all dead before k_bpack8 writes):
#define OFF_APENC (OFF_BPACK)                   // 9600*512 shorts = 2457600 fl
#define OFF_APHID (OFF_APENC + 2457600)         // 384*256 shorts
#define OFF_APX   (OFF_APHID + 49152)           // 384*128 shorts
#define OFF_BWIH  (OFF_APX + 24576)             // 128*1024 shorts
#define OFF_BWHW  (OFF_BWIH + 65536)            // 512*512 shorts
#define OFF_BWSW  (OFF_BWHW + 131072)           // 256*512 shorts

typedef __attribute__((ext_vector_type(8))) short short8;
typedef __attribute__((ext_vector_type(2))) int int2v;
typedef __attribute__((ext_vector_type(16))) float floatx16;

__device__ __forceinline__ short f2bf(float f) {
    __hip_bfloat16 h = __float2bfloat16(f);
    return *reinterpret_cast<short*>(&h);
}
__device__ __forceinline__ float bf2f(short s) {
    unsigned int u = ((unsigned int)(unsigned short)s) << 16;
    return __uint_as_float(u);
}
__device__ __forceinline__ float sigm(float x) { return 1.f/(1.f + expf(-x)); }

// pack 8 floats -> 8 fp8 e4m3 bytes (one i64)
__device__ __forceinline__ long pk8(const float* f) {
    int lo = __builtin_amdgcn_cvt_pk_fp8_f32(f[0], f[1], 0, 0);
    lo = __builtin_amdgcn_cvt_pk_fp8_f32(f[2], f[3], lo, 1);
    int hi = __builtin_amdgcn_cvt_pk_fp8_f32(f[4], f[5], 0, 0);
    hi = __builtin_amdgcn_cvt_pk_fp8_f32(f[6], f[7], hi, 1);
    int2v v; v[0] = lo; v[1] = hi;
    return *reinterpret_cast<long*>(&v);
}

// ---------------- K0: embedding lookup ----------------
__global__ __launch_bounds__(256) void k_embed(
    const float* __restrict__ embed, const int* __restrict__ dec_input,
    float* __restrict__ x_out)
{
    int i = blockIdx.x*256 + threadIdx.x;
    int bt = i >> 5;
    int e4 = i & 31;
    int tok = dec_input[bt];
    reinterpret_cast<float4*>(x_out)[(size_t)bt*32 + e4] =
        reinterpret_cast<const float4*>(embed)[(size_t)tok*32 + e4];
}

// ---------------- generic A-pack: A [M,K] fp32 -> 32x32x16 A-frag bf16 ------
__global__ __launch_bounds__(256) void k_apack(
    const float* __restrict__ A, short* __restrict__ Ap, int MT, int K_)
{
    int s = blockIdx.x*256 + threadIdx.x;
    int l = s & 63;
    int ks = (s >> 6) & 1;
    int rest = s >> 7;
    int mt = rest % MT;
    int kstep = rest / MT;
    int row = mt*32 + (l & 31);
    int kb = kstep*32 + ks*16 + ((l >> 5) << 3);
    const float4* src = reinterpret_cast<const float4*>(&A[(size_t)row*K_ + kb]);
    float4 a = src[0], b = src[1];
    short8 v;
    v[0]=f2bf(a.x); v[1]=f2bf(a.y); v[2]=f2bf(a.z); v[3]=f2bf(a.w);
    v[4]=f2bf(b.x); v[5]=f2bf(b.y); v[6]=f2bf(b.z); v[7]=f2bf(b.w);
    *reinterpret_cast<short8*>(Ap + (size_t)s*8) = v;
}

// ---------------- A-pack fp8: s_buf [384,768] -> fp8 A-frags ----------------
__global__ __launch_bounds__(256) void k_apack8(
    const float* __restrict__ A, long* __restrict__ Ap)
{
    int s = blockIdx.x*256 + threadIdx.x;          // 0..36863
    int l = s & 63;
    int ks = (s >> 6) & 1;
    int rest = s >> 7;
    int mt = rest % 12;
    int kstep = rest / 12;
    int row = mt*32 + (l & 31);
    int kb = kstep*32 + ks*16 + ((l >> 5) << 3);
    const float4* src = reinterpret_cast<const float4*>(&A[(size_t)row*H3 + kb]);
    float4 a = src[0], b = src[1];
    float f[8] = {a.x,a.y,a.z,a.w,b.x,b.y,b.z,b.w};
    Ap[s] = pk8(f);
}

// ---------------- generic W-pack: W [K,N] fp32 -> 32x32x16 B-frag bf16 ------
__global__ __launch_bounds__(256) void k_wpack(
    const float* __restrict__ W, short* __restrict__ Bp, int KS, int N_)
{
    int s = blockIdx.x*256 + threadIdx.x;
    int l = s & 63;
    int ks = (s >> 6) & 1;
    int rest = s >> 7;
    int kstep = rest % KS;
    int ct = rest / KS;
    int col = ct*32 + (l & 31);
    int kb = kstep*32 + ks*16 + ((l >> 5) << 3);
    short8 v;
    #pragma unroll
    for (int j = 0; j < 8; ++j) v[j] = f2bf(W[(size_t)(kb + j)*N_ + col]);
    *reinterpret_cast<short8*>(Bp + (size_t)s*8) = v;
}

// ---------------- generic packed MFMA GEMM + bias: C[M,N] fp32 --------------
// __launch_bounds__(512,1): allow big VGPR budget so the prefetch ring lives
// in registers (acc alone = 48 VGPRs; default budget defeated the pipeline).
__global__ __launch_bounds__(512, 1) void k_gemm_mfma(
    const short* __restrict__ Apack, const short* __restrict__ Bpack,
    const float* __restrict__ bias, float* __restrict__ C,
    int N_, int MT, int KS)
{
    int bm = blockIdx.x, nb = blockIdx.y;
    int t = threadIdx.x;
    int wid = t >> 6, lane = t & 63;
    int wave_m = wid >> 2, wave_n = wid & 3;
    int mt0 = bm*6 + wave_m*3;
    int ct = nb*4 + wave_n;

    const short8* ap = reinterpret_cast<const short8*>(Apack);
    const short8* bp = reinterpret_cast<const short8*>(Bpack);

    floatx16 acc[3];
    #pragma unroll
    for (int mi = 0; mi < 3; ++mi)
        #pragma unroll
        for (int r = 0; r < 16; ++r) acc[mi][r] = 0.f;

    short8 Ba0, Ba1, Bb0, Bb1;
    short8 Fa[6], Fb[6];

#define LOADB(B0, B1, kst) do { \
    B0 = bp[(size_t)(((ct*KS + (kst))*2 + 0)*64 + lane)]; \
    B1 = bp[(size_t)(((ct*KS + (kst))*2 + 1)*64 + lane)]; \
} while (0)
#define LOADA(F, kst) do { \
    _Pragma("unroll") \
    for (int mi = 0; mi < 3; ++mi) { \
        F[mi]   = ap[(size_t)((((kst)*MT + (mt0 + mi))*2 + 0)*64 + lane)]; \
        F[3+mi] = ap[(size_t)((((kst)*MT + (mt0 + mi))*2 + 1)*64 + lane)]; \
    } \
} while (0)
#define STEP(B0, B1, F) do { \
    _Pragma("unroll") \
    for (int mi = 0; mi < 3; ++mi) \
        acc[mi] = __builtin_amdgcn_mfma_f32_32x32x16_bf16(F[mi], B0, acc[mi], 0, 0, 0); \
    _Pragma("unroll") \
    for (int mi = 0; mi < 3; ++mi) \
        acc[mi] = __builtin_amdgcn_mfma_f32_32x32x16_bf16(F[3+mi], B1, acc[mi], 0, 0, 0); \
} while (0)

    LOADB(Ba0, Ba1, 0); LOADA(Fa, 0);
    LOADB(Bb0, Bb1, 1); LOADA(Fb, 1);
    for (int k = 0; k < KS; k += 2) {
        STEP(Ba0, Ba1, Fa);
        if (k + 2 < KS) { LOADB(Ba0, Ba1, k+2); LOADA(Fa, k+2); }
        STEP(Bb0, Bb1, Fb);
        if (k + 3 < KS) { LOADB(Bb0, Bb1, k+3); LOADA(Fb, k+3); }
    }
#undef LOADB
#undef LOADA
#undef STEP

    int col = ct*32 + (lane & 31);
    float bias_v = bias[col];
    int rsub = 4*(lane >> 5);
    #pragma unroll
    for (int mi = 0; mi < 3; ++mi) {
        int rowg0 = bm*192 + wave_m*96 + mi*32 + rsub;
        #pragma unroll
        for (int r = 0; r < 16; ++r) {
            int rowg = rowg0 + (r & 3) + 8*(r >> 2);
            C[(size_t)rowg*N_ + col] = acc[mi][r] + bias_v;
        }
    }
}

// ---------------- fallback fp32 GEMM + bias ----------------
__global__ __launch_bounds__(256) void k_gemm_bias(
    const float* __restrict__ A, const float* __restrict__ Wm,
    const float* __restrict__ bias, float* __restrict__ C, int N_, int K_)
{
    __shared__ float As[64][17];
    __shared__ __align__(16) float Bs[16][128];
    int bm = blockIdx.x*64, bn = blockIdx.y*128;
    int tid = threadIdx.x, tr = tid >> 4, tc = tid & 15;
    float acc[4][8] = {};
    for (int k0 = 0; k0 < K_; k0 += 16) {
        for (int i = tid; i < 64*16; i += 256) { int r = i >> 4, c = i & 15; As[r][c] = A[(size_t)(bm+r)*K_ + k0 + c]; }
        for (int i = tid; i < 16*128; i += 256) { int r = i >> 7, c = i & 127; Bs[r][c] = Wm[(size_t)(k0+r)*N_ + bn + c]; }
        __syncthreads();
        #pragma unroll
        for (int kk = 0; kk < 16; ++kk) {
            float a0 = As[tr*4+0][kk], a1 = As[tr*4+1][kk], a2 = As[tr*4+2][kk], a3 = As[tr*4+3][kk];
            const float4* bpx = reinterpret_cast<const float4*>(&Bs[kk][tc*8]);
            float4 q0 = bpx[0], q1 = bpx[1];
            float bb[8] = {q0.x,q0.y,q0.z,q0.w,q1.x,q1.y,q1.z,q1.w};
            #pragma unroll
            for (int j = 0; j < 8; ++j) {
                acc[0][j] += a0*bb[j]; acc[1][j] += a1*bb[j];
                acc[2][j] += a2*bb[j]; acc[3][j] += a3*bb[j];
            }
        }
        __syncthreads();
    }
    for (int i = 0; i < 4; ++i) {
        int r = bm + tr*4 + i;
        for (int j = 0; j < 8; ++j) {
            int c = bn + tc*8 + j;
            C[(size_t)r*N_ + c] = acc[i][j] + bias[c];
        }
    }
}

// ---------------- W_hh -> per-block-sliced 32x32x16 B-frag order ------------
__global__ __launch_bounds__(256) void k_whh_pack(
    const float* __restrict__ Whh, short* __restrict__ wp)
{
    int s = blockIdx.x*256 + threadIdx.x;      // 0..32767
    int l = s & 63;
    int kstep = (s >> 6) & 15;
    int ct_l = (s >> 10) & 7;
    int q = s >> 13;
    int col = (ct_l >> 1)*256 + q*64 + (ct_l & 1)*32 + (l & 31);
    int kb = kstep*16 + ((l >> 5) << 3);
    short8 v;
    #pragma unroll
    for (int j = 0; j < 8; ++j) v[j] = f2bf(Whh[(size_t)(kb + j)*H4 + col]);
    *reinterpret_cast<short8*>(wp + (size_t)s*8) = v;
}

// ---------------- init h0 -> hfrag buf0 + zero barriers ----------------
__global__ __launch_bounds__(256) void k_init(
    const float* __restrict__ h0, short* __restrict__ hbuf0,
    unsigned int* __restrict__ bar)
{
    int gid = blockIdx.x*256 + threadIdx.x;    // 0..8191
    int r = gid >> 8;
    int hidx = gid & 255;
    int kstep = hidx >> 4;
    int kk = hidx & 15;
    int l = ((kk >> 3) << 5) + r;
    hbuf0[(size_t)(kstep*64 + l)*8 + (kk & 7)] = f2bf(h0[r*HH + hidx]);
    if (blockIdx.x == 0 && threadIdx.x < 64) bar[threadIdx.x] = 0u;
}

// ---------------- column-split MFMA LSTM, 4 blocks, W-slice in LDS ----------
__global__ __launch_bounds__(512) void k_lstm5(
    const float* __restrict__ xw, const short* __restrict__ whhp,
    const float* __restrict__ c0, short* __restrict__ hbuf,
    unsigned int* __restrict__ bar, float* __restrict__ hid_out)
{
    __shared__ short wlds[8*16*64*8];   // 128 KB
    __shared__ short g_lds[32][256];    // 16 KB
    __shared__ float c_lds[32][64];     // 8 KB
    int tid = threadIdx.x, wid = tid >> 6, lane = tid & 63;
    int q = blockIdx.x;

    {
        const short8* wp8 = reinterpret_cast<const short8*>(whhp);
        for (int i = tid; i < 8192; i += 512)
            *reinterpret_cast<short8*>(&wlds[i*8]) = wp8[(size_t)q*8192 + i];
    }
    for (int i = tid; i < 32*64; i += 512) {
        int b = i >> 6, jj = i & 63;
        c_lds[b][jj] = c0[b*HH + q*64 + jj];
    }
    __syncthreads();

    for (int t = 0; t < TT; ++t) {
        const short* hcur = hbuf + (size_t)(t & 1)*8192;
        short* hnxt = hbuf + (size_t)((t + 1) & 1)*8192;

        floatx16 acc;
        #pragma unroll
        for (int r = 0; r < 16; ++r) acc[r] = 0.f;
        #pragma unroll
        for (int kstep = 0; kstep < 16; ++kstep) {
            short8 af = *reinterpret_cast<const short8*>(&hcur[(size_t)(kstep*64 + lane)*8]);
            short8 bf = *reinterpret_cast<const short8*>(&wlds[((wid*16 + kstep)*64 + lane)*8]);
            acc = __builtin_amdgcn_mfma_f32_32x32x16_bf16(af, bf, acc, 0, 0, 0);
        }
        int gcol = (wid >> 1)*256 + q*64 + (wid & 1)*32 + (lane & 31);
        int lcol = wid*32 + (lane & 31);
        #pragma unroll
        for (int r = 0; r < 16; ++r) {
            int row = (r & 3) + 8*(r >> 2) + 4*(lane >> 5);
            g_lds[row][lcol] = f2bf(acc[r] + xw[(size_t)(row*TT + t)*H4 + gcol]);
        }
        __syncthreads();
        for (int i = tid; i < 2048; i += 512) {
            int b = i >> 6, jj = i & 63;
            float gi = bf2f(g_lds[b][((0*2 + (jj>>5))<<5) + (jj & 31)]);
            float gf = bf2f(g_lds[b][((1*2 + (jj>>5))<<5) + (jj & 31)]);
            float gg = bf2f(g_lds[b][((2*2 + (jj>>5))<<5) + (jj & 31)]);
            float go = bf2f(g_lds[b][((3*2 + (jj>>5))<<5) + (jj & 31)]);
            float c = sigm(gf)*c_lds[b][jj] + sigm(gi)*tanhf(gg);
            float h = sigm(go)*tanhf(c);
            c_lds[b][jj] = c;
            int hidx = q*64 + jj;
            hid_out[(size_t)(b*TT + t)*HH + hidx] = h;
            int kk = hidx & 15;
            int l2 = ((kk >> 3) << 5) + b;
            hnxt[(size_t)((hidx >> 4)*64 + l2)*8 + (kk & 7)] = f2bf(h);
        }
        __threadfence();
        __syncthreads();
        if (tid == 0) {
            atomicAdd(&bar[t], 1u);
            while (atomicAdd(&bar[t], 0u) < 4u) __builtin_amdgcn_s_sleep(2);
        }
        __syncthreads();
        __threadfence();
    }
}

// ---------------- K4: e scores ----------------
__global__ __launch_bounds__(256) void k_e(
    const float* __restrict__ enc_proj, const float* __restrict__ dec_proj,
    const float* __restrict__ v_w, const float* __restrict__ v_b,
    const unsigned char* __restrict__ enc_mask, float* __restrict__ e_out)
{
    int b = blockIdx.x, lbase = blockIdx.y*4;
    __shared__ float decp[TT*H2];
    int tid = threadIdx.x;
    for (int i = tid; i < TT*H2; i += 256) decp[i] = dec_proj[(size_t)b*TT*H2 + i];
    __syncthreads();
    int wave = tid >> 6, lane = tid & 63;
    int l = lbase + wave;
    const float* er = &enc_proj[(size_t)(b*LL + l)*H2];
    float ep[8], vw[8];
    #pragma unroll
    for (int k = 0; k < 8; ++k) { int e = lane + 64*k; ep[k] = er[e]; vw[k] = v_w[e]; }
    float vb = v_b[0];
    bool masked = enc_mask[b*LL + l] != 0;
    for (int t = 0; t < TT; ++t) {
        float acc = 0.f;
        #pragma unroll
        for (int k = 0; k < 8; ++k) {
            int e = lane + 64*k;
            acc += vw[k] * tanhf(ep[k] + decp[t*H2 + e]);
        }
        #pragma unroll
        for (int off = 32; off; off >>= 1) acc += __shfl_xor(acc, off);
        if (lane == 0)
            e_out[(size_t)(b*TT + t)*LL + l] = masked ? -INFINITY : (acc + vb);
    }
}

// ---------------- K5: softmax over L + context + s ----------------
__global__ __launch_bounds__(256) void k_softmax_ctx(
    float* __restrict__ attn, const float* __restrict__ enc_states,
    const float* __restrict__ hidden, float* __restrict__ s_out)
{
    int bt = blockIdx.x, b = bt / TT, tid = threadIdx.x;
    __shared__ float a[LL];
    __shared__ float red[256];
    float m = -INFINITY;
    for (int l = tid; l < LL; l += 256) m = fmaxf(m, attn[(size_t)bt*LL + l]);
    red[tid] = m; __syncthreads();
    for (int s = 128; s; s >>= 1) { if (tid < s) red[tid] = fmaxf(red[tid], red[tid+s]); __syncthreads(); }
    m = red[0]; __syncthreads();
    float sum = 0.f;
    for (int l = tid; l < LL; l += 256) { float w = expf(attn[(size_t)bt*LL + l] - m); a[l] = w; sum += w; }
    red[tid] = sum; __syncthreads();
    for (int s = 128; s; s >>= 1) { if (tid < s) red[tid] += red[tid+s]; __syncthreads(); }
    float inv = 1.0f / red[0];
    __syncthreads();
    for (int l = tid; l < LL; l += 256) { float w = a[l]*inv; a[l] = w; attn[(size_t)bt*LL + l] = w; }
    __syncthreads();
    for (int c = tid; c < H2; c += 256) {
        float acc = 0.f;
        const float* es = &enc_states[(size_t)b*LL*H2 + c];
        for (int l = 0; l < LL; ++l) acc += a[l] * es[(size_t)l*H2];
        s_out[(size_t)bt*H3 + HH + c] = acc;
    }
    for (int c = tid; c < HH; c += 256) s_out[(size_t)bt*H3 + c] = hidden[(size_t)bt*HH + c];
}

// ---------------- K6: switch softmax + copy score ----------------
__global__ __launch_bounds__(64) void k_switch_copy(
    const float* __restrict__ s, const float* __restrict__ x,
    const float* __restrict__ enc_h0,
    const float* __restrict__ wh_w, const float* __restrict__ wh_b,
    const float* __restrict__ ws_w, const float* __restrict__ ws_b,
    const float* __restrict__ wx_w, const float* __restrict__ wx_b,
    const float* __restrict__ wc_w, const float* __restrict__ wc_b,
    const int* __restrict__ article_inds, const int* __restrict__ targets,
    const float* __restrict__ attn, float* __restrict__ psw, float* __restrict__ copysc)
{
    int bt = blockIdx.x, b = bt / TT, lane = threadIdx.x;
    float s0 = 0.f, s1 = 0.f, s2 = 0.f;
    const float* ctx = &s[(size_t)bt*H3 + HH];
    const float* hid = &s[(size_t)bt*H3];
    for (int k = lane; k < H2; k += 64) { float v = ctx[k]; s0 += v*wh_w[k*3]; s1 += v*wh_w[k*3+1]; s2 += v*wh_w[k*3+2]; }
    for (int k = lane; k < HH; k += 64) { float v = hid[k]; s0 += v*ws_w[k*3]; s1 += v*ws_w[k*3+1]; s2 += v*ws_w[k*3+2]; }
    for (int k = lane; k < EE; k += 64) { float v = x[(size_t)bt*EE + k]; s0 += v*wx_w[k*3]; s1 += v*wx_w[k*3+1]; s2 += v*wx_w[k*3+2]; }
    for (int k = lane; k < HH; k += 64) { float v = enc_h0[b*HH + k]; s0 += v*wc_w[k*3]; s1 += v*wc_w[k*3+1]; s2 += v*wc_w[k*3+2]; }
    #pragma unroll
    for (int off = 32; off; off >>= 1) {
        s0 += __shfl_xor(s0, off); s1 += __shfl_xor(s1, off); s2 += __shfl_xor(s2, off);
    }
    if (lane == 0) {
        s0 += wh_b[0] + ws_b[0] + wx_b[0] + wc_b[0];
        s1 += wh_b[1] + ws_b[1] + wx_b[1] + wc_b[1];
        s2 += wh_b[2] + ws_b[2] + wx_b[2] + wc_b[2];
        float mm = fmaxf(s0, fmaxf(s1, s2));
        float e0 = expf(s0-mm), e1 = expf(s1-mm), e2 = expf(s2-mm);
        float inv = 1.f/(e0+e1+e2);
        psw[bt*3+0] = e0*inv; psw[bt*3+1] = e1*inv; psw[bt*3+2] = e2*inv;
    }
    int tgt = targets[bt];
    float cs = 0.f;
    for (int l = lane; l < LL; l += 64)
        if (article_inds[b*LL + l] == tgt) cs += attn[(size_t)bt*LL + l];
    #pragma unroll
    for (int off = 32; off; off >>= 1) cs += __shfl_xor(cs, off);
    if (lane == 0) copysc[bt] = cs;
}

// ---------------- K_bpack8: Vout_w -> fp8 B-frag order (LDS transpose) ------
__global__ __launch_bounds__(256) void k_bpack8(
    const float* __restrict__ Wm, unsigned char* __restrict__ Bp)
{
    __shared__ unsigned int tile[32][66];      // 32 rows x 256 fp8 bytes (+pad)
    int kstep = blockIdx.x, cblk = blockIdx.y;
    int tid = threadIdx.x;
    int cbase = cblk*256;
    for (int i = tid; i < 32*64; i += 256) {
        int r = i >> 6, c4 = i & 63;
        int col = cbase + c4*4;
        float4 v = make_float4(0.f,0.f,0.f,0.f);
        if (col < VV)
            v = *reinterpret_cast<const float4*>(&Wm[(size_t)(kstep*32 + r)*VV + col]);
        int w = __builtin_amdgcn_cvt_pk_fp8_f32(v.x, v.y, 0, 0);
        w = __builtin_amdgcn_cvt_pk_fp8_f32(v.z, v.w, w, 1);
        tile[r][c4] = (unsigned int)w;
    }
    __syncthreads();
    int wave = tid >> 6, l = tid & 63;
    const unsigned char* tb = reinterpret_cast<const unsigned char*>(tile);
    #pragma unroll
    for (int it = 0; it < 4; ++it) {
        int fid = wave*4 + it;
        int ct_l = fid >> 1, ks = fid & 1;
        int rbase = ks*16 + ((l >> 5) << 3);
        int c = ct_l*32 + (l & 31);
        unsigned int lo = 0, hi = 0;
        #pragma unroll
        for (int j = 0; j < 4; ++j)
            lo |= (unsigned int)tb[(rbase + j)*264 + c] << (8*j);
        #pragma unroll
        for (int j = 0; j < 4; ++j)
            hi |= (unsigned int)tb[(rbase + 4 + j)*264 + c] << (8*j);
        size_t ct_g = (size_t)cblk*8 + ct_l;
        unsigned int* dst = reinterpret_cast<unsigned int*>(
            &Bp[(((ct_g*24 + kstep)*2 + ks)*64 + l)*8]);
        dst[0] = lo; dst[1] = hi;
    }
}

// ---------------- K7c: fp8 MFMA big GEMM, 4-deep prefetch + exp partials ----
// __launch_bounds__(512,1): acc=48 VGPRs + 4-deep ring (64 VGPRs) must live in
// registers; default budget (VGPR=48 observed) sank all loads -> serialized.
__global__ __launch_bounds__(512, 1) void k_big_fp8(
    const long* __restrict__ Apack, const long* __restrict__ Bp,
    const float* __restrict__ bias, const int* __restrict__ targets,
    float* __restrict__ psum, float* __restrict__ tlogit)
{
    __shared__ float pv_l[192][4];
    int bm = blockIdx.x, nvb = blockIdx.y;
    int bn = nvb * 128;
    int t = threadIdx.x;
    int wid = t >> 6, lane = t & 63;
    int wave_m = wid >> 2, wave_n = wid & 3;
    size_t ct_g = (size_t)nvb*4 + wave_n;
    int colB = bn + wave_n*32 + (lane & 31);
    bool colOK = colB < VV;
    int mt0 = bm*6 + wave_m*3;

    floatx16 acc[3];
    #pragma unroll
    for (int mi = 0; mi < 3; ++mi)
        #pragma unroll
        for (int r = 0; r < 16; ++r) acc[mi][r] = 0.f;

    long B0a, B1a, B0b, B1b, B0c, B1c, B0d, B1d;
    long Fa[6], Fb[6], Fc[6], Fd[6];

#define LOADB(B0, B1, kst) do { \
    B0 = Bp[(ct_g*24 + (kst))*2*64 + 0*64 + lane]; \
    B1 = Bp[(ct_g*24 + (kst))*2*64 + 1*64 + lane]; \
} while (0)
#define LOADA(F, kst) do { \
    _Pragma("unroll") \
    for (int mi = 0; mi < 3; ++mi) { \
        F[mi]   = Apack[(size_t)(((kst)*12 + (mt0 + mi))*2 + 0)*64 + lane]; \
        F[3+mi] = Apack[(size_t)(((kst)*12 + (mt0 + mi))*2 + 1)*64 + lane]; \
    } \
} while (0)
#define STEP(B0, B1, F) do { \
    _Pragma("unroll") \
    for (int mi = 0; mi < 3; ++mi) \
        acc[mi] = __builtin_amdgcn_mfma_f32_32x32x16_fp8_fp8(F[mi], B0, acc[mi], 0, 0, 0); \
    _Pragma("unroll") \
    for (int mi = 0; mi < 3; ++mi) \
        acc[mi] = __builtin_amdgcn_mfma_f32_32x32x16_fp8_fp8(F[3+mi], B1, acc[mi], 0, 0, 0); \
} while (0)

    LOADB(B0a, B1a, 0); LOADA(Fa, 0);
    LOADB(B0b, B1b, 1); LOADA(Fb, 1);
    LOADB(B0c, B1c, 2); LOADA(Fc, 2);
    LOADB(B0d, B1d, 3); LOADA(Fd, 3);
    for (int k = 0; k < KSTEPS; k += 4) {
        STEP(B0a, B1a, Fa);
        if (k + 4 < KSTEPS) { LOADB(B0a, B1a, k+4); LOADA(Fa, k+4); }
        STEP(B0b, B1b, Fb);
        if (k + 5 < KSTEPS) { LOADB(B0b, B1b, k+5); LOADA(Fb, k+5); }
        STEP(B0c, B1c, Fc);
        if (k + 6 < KSTEPS) { LOADB(B0c, B1c, k+6); LOADA(Fc, k+6); }
        STEP(B0d, B1d, Fd);
        if (k + 7 < KSTEPS) { LOADB(B0d, B1d, k+7); LOADA(Fd, k+7); }
    }
#undef LOADB
#undef LOADA
#undef STEP

    float bias_v = colOK ? bias[colB] : 0.f;
    int rsub = 4*(lane >> 5);
    #pragma unroll
    for (int mi = 0; mi < 3; ++mi) {
        #pragma unroll
        for (int r = 0; r < 16; ++r) {
            int row_l = wave_m*96 + mi*32 + rsub + (r & 3) + 8*(r >> 2);
            int rowg = bm*192 + row_l;
            float logit = acc[mi][r] + bias_v;
            if (colOK && colB == targets[rowg]) tlogit[rowg] = logit;
            float e = colOK ? expf(logit) : 0.f;
            #pragma unroll
            for (int msk = 16; msk; msk >>= 1) e += __shfl_xor(e, msk);
            if ((lane & 31) == 0) pv_l[row_l][wave_n] = e;
        }
    }
    __syncthreads();
    if (t < 192) {
        float ss = pv_l[t][0] + pv_l[t][1] + pv_l[t][2] + pv_l[t][3];
        int rowg = bm*192 + t;
        psum[(size_t)rowg*NVB + nvb] = ss;
    }
}

// ---------------- K7: legacy direct-read k_big (ws fallback, bf16) ----------
__global__ __launch_bounds__(512) void k_big(
    const short* __restrict__ Apack, const float* __restrict__ Wm,
    const float* __restrict__ bias, const int* __restrict__ targets,
    float* __restrict__ psum, float* __restrict__ tlogit)
{
    __shared__ float pv_l[192][4];
    int bm = blockIdx.x, nvb = blockIdx.y;
    int bn = nvb * 128;
    int t = threadIdx.x;
    int wid = t >> 6, lane = t & 63;
    int wave_m = wid >> 2, wave_n = wid & 3;
    int colB = bn + wave_n*32 + (lane & 31);
    int kOff = (lane >> 5) << 3;
    bool colOK = colB < VV;
    int mt0 = bm*6 + wave_m*3;
    const short8* ap = reinterpret_cast<const short8*>(Apack);
    floatx16 acc[3];
    #pragma unroll
    for (int mi = 0; mi < 3; ++mi)
        #pragma unroll
        for (int r = 0; r < 16; ++r) acc[mi][r] = 0.f;
    float Bq0a[8], Bq1a[8], Bq0b[8], Bq1b[8];
    short8 Fa[6], Fb[6];
#define LOADB(Q0, Q1, kst) do { \
    int kb_ = (kst)*32 + kOff; \
    _Pragma("unroll") \
    for (int j = 0; j < 8; ++j) Q0[j] = colOK ? Wm[(size_t)(kb_ + j)*VV + colB] : 0.f; \
    _Pragma("unroll") \
    for (int j = 0; j < 8; ++j) Q1[j] = colOK ? Wm[(size_t)(kb_ + 16 + j)*VV + colB] : 0.f; \
} while (0)
#define LOADA(F, kst) do { \
    _Pragma("unroll") \
    for (int mi = 0; mi < 3; ++mi) { \
        F[mi]   = ap[(size_t)(((kst)*12 + (mt0 + mi))*2 + 0)*64 + lane]; \
        F[3+mi] = ap[(size_t)(((kst)*12 + (mt0 + mi))*2 + 1)*64 + lane]; \
    } \
} while (0)
#define STEP(Q0, Q1, F) do { \
    short8 b0_, b1_; \
    _Pragma("unroll") \
    for (int j = 0; j < 8; ++j) { b0_[j] = f2bf(Q0[j]); b1_[j] = f2bf(Q1[j]); } \
    _Pragma("unroll") \
    for (int mi = 0; mi < 3; ++mi) \
        acc[mi] = __builtin_amdgcn_mfma_f32_32x32x16_bf16(F[mi], b0_, acc[mi], 0, 0, 0); \
    _Pragma("unroll") \
    for (int mi = 0; mi < 3; ++mi) \
        acc[mi] = __builtin_amdgcn_mfma_f32_32x32x16_bf16(F[3+mi], b1_, acc[mi], 0, 0, 0); \
} while (0)
    LOADB(Bq0a, Bq1a, 0); LOADA(Fa, 0);
    LOADB(Bq0b, Bq1b, 1); LOADA(Fb, 1);
    for (int k = 0; k < KSTEPS; k += 2) {
        STEP(Bq0a, Bq1a, Fa);
        if (k + 2 < KSTEPS) { LOADB(Bq0a, Bq1a, k+2); LOADA(Fa, k+2); }
        STEP(Bq0b, Bq1b, Fb);
        if (k + 3 < KSTEPS) { LOADB(Bq0b, Bq1b, k+3); LOADA(Fb, k+3); }
    }
#undef LOADB
#undef LOADA
#undef STEP
    float bias_v = colOK ? bias[colB] : 0.f;
    int rsub = 4*(lane >> 5);
    #pragma unroll
    for (int mi = 0; mi < 3; ++mi) {
        #pragma unroll
        for (int r = 0; r < 16; ++r) {
            int row_l = wave_m*96 + mi*32 + rsub + (r & 3) + 8*(r >> 2);
            int rowg = bm*192 + row_l;
            float logit = acc[mi][r] + bias_v;
            if (colOK && colB == targets[rowg]) tlogit[rowg] = logit;
            float e = colOK ? expf(logit) : 0.f;
            #pragma unroll
            for (int msk = 16; msk; msk >>= 1) e += __shfl_xor(e, msk);
            if ((lane & 31) == 0) pv_l[row_l][wave_n] = e;
        }
    }
    __syncthreads();
    if (t < 192) {
        float ss = pv_l[t][0] + pv_l[t][1] + pv_l[t][2] + pv_l[t][3];
        int rowg = bm*192 + t;
        psum[(size_t)rowg*NVB + nvb] = ss;
    }
}

// ---------------- K8: sum partials + per-token nll ----------------
__global__ __launch_bounds__(64) void k_lsum(
    const float* __restrict__ psum,
    const float* __restrict__ tlogit, const int* __restrict__ targets,
    const float* __restrict__ psw, const float* __restrict__ copysc,
    const float* __restrict__ dec_mask, float* __restrict__ nll)
{
    int pair = blockIdx.x, lane = threadIdx.x;
    float s = 0.f;
    for (int j = lane; j < NVB; j += 64) s += psum[(size_t)pair*NVB + j];
    #pragma unroll
    for (int off = 32; off; off >>= 1) s += __shfl_xor(s, off);
    if (lane == 0) {
        int tgt = targets[pair];
        float outv;
        if (tgt == UNK) outv = 1.0f;
        else {
            float base = 0.f;
            if (tgt < VV) {
                float pvv = expf(tlogit[pair]) / s;
                float pg = (tgt < VV - NPR) ? psw[pair*3] : psw[pair*3+1];
                base = pg * pvv;
            }
            outv = base + psw[pair*3+2] * copysc[pair];
        }
        outv = fmaxf(outv, 1e-38f);
        nll[pair] = -logf(outv) * dec_mask[pair];
    }
}

// ---------------- K9: final per-batch loss ----------------
__global__ __launch_bounds__(64) void k_final(
    const float* __restrict__ nll, const float* __restrict__ dec_lens, float* __restrict__ out)
{
    int b = threadIdx.x;
    if (b < BB) {
        float a = 0.f;
        for (int t = 0; t < TT; ++t) a += nll[b*TT + t];
        out[b] = a / dec_lens[b];
    }
}

extern "C" void kernel_launch(void* const* d_in, const int* in_sizes, int n_in,
                              void* d_out, int out_size, void* d_ws, size_t ws_size,
                              hipStream_t stream)
{
    const float* enc_states = (const float*)d_in[0];
    const float* enc_h0     = (const float*)d_in[1];
    const float* enc_c0     = (const float*)d_in[2];
    const unsigned char* enc_mask = (const unsigned char*)d_in[3];
    const int* article_inds = (const int*)d_in[4];
    const int* dec_input    = (const int*)d_in[5];
    const int* targets      = (const int*)d_in[6];
    const float* dec_lens   = (const float*)d_in[7];
    const float* dec_mask   = (const float*)d_in[8];
    const float* embed      = (const float*)d_in[9];
    const float* W_ih       = (const float*)d_in[10];
    const float* W_hh       = (const float*)d_in[11];
    const float* b_lstm     = (const float*)d_in[12];
    const float* Wh_w = (const float*)d_in[13]; const float* Wh_b = (const float*)d_in[14];
    const float* Ws_w = (const float*)d_in[15]; const float* Ws_b = (const float*)d_in[16];
    const float* v_w  = (const float*)d_in[17]; const float* v_b  = (const float*)d_in[18];
    const float* wh_w = (const float*)d_in[19]; const float* wh_b = (const float*)d_in[20];
    const float* ws_w = (const float*)d_in[21]; const float* ws_b = (const float*)d_in[22];
    const float* wx_w = (const float*)d_in[23]; const float* wx_b = (const float*)d_in[24];
    const float* wc_w = (const float*)d_in[25]; const float* wc_b = (const float*)d_in[26];
    const float* Vout_w = (const float*)d_in[27]; const float* Vout_b = (const float*)d_in[28];

    float* ws = (float*)d_ws;
    float* x_buf   = ws + OFF_X;
    float* hid     = ws + OFF_HID;
    float* encp    = ws + OFF_ENCP;
    float* decp    = ws + OFF_DECP;
    float* attn    = ws + OFF_ATTN;
    float* s_buf   = ws + OFF_S;
    float* psw     = ws + OFF_PSW;
    float* copysc  = ws + OFF_COPY;
    float* tlogit  = ws + OFF_TLOGIT;
    float* psum    = ws + OFF_PSUM;
    float* nll     = ws + OFF_NLL;
    short* apack   = (short*)(ws + OFF_APACK);
    long*  apack8  = (long*)(ws + OFF_APACK);
    float* xw      = ws + OFF_XW;
    short* whhp    = (short*)(ws + OFF_WHH);
    short* hbuf    = (short*)(ws + OFF_HFRAG);
    unsigned int* bar = (unsigned int*)(ws + OFF_BAR);
    unsigned char* bpack8 = (unsigned char*)(ws + OFF_BPACK);
    // aliases inside the BPACK region (dead before k_bpack8 writes):
    short* apenc   = (short*)(ws + OFF_APENC);
    short* aphid   = (short*)(ws + OFF_APHID);
    short* apx     = (short*)(ws + OFF_APX);
    short* bwih    = (short*)(ws + OFF_BWIH);
    short* bwhw    = (short*)(ws + OFF_BWHW);
    short* bwsw    = (short*)(ws + OFF_BWSW);
    float* out     = (float*)d_out;

    bool use_pack = ws_size >= WS_NEEDED_BYTES;

    // 1a. embedding lookup
    k_embed<<<dim3(BT*EE/4/256), dim3(256), 0, stream>>>(embed, dec_input, x_buf);

    if (use_pack) {
        // 1b. xw = x @ W_ih + b_lstm  via MFMA
        k_apack<<<dim3(BT*EE/8/256), dim3(256), 0, stream>>>(x_buf, apx, 12, EE);
        k_wpack<<<dim3(EE*H4/8/256), dim3(256), 0, stream>>>(W_ih, bwih, EE/32, H4);
        k_gemm_mfma<<<dim3(BT/192, H4/128), dim3(512), 0, stream>>>(apx, bwih, b_lstm, xw, H4, BT/32, EE/32);
    } else {
        k_gemm_bias<<<dim3(BT/64, H4/128), dim3(256), 0, stream>>>(x_buf, W_ih, b_lstm, xw, H4, EE);
    }
    // 1c-1e. LSTM
    k_whh_pack<<<dim3(128), dim3(256), 0, stream>>>(W_hh, whhp);
    k_init<<<dim3(32), dim3(256), 0, stream>>>(enc_h0, hbuf, bar);
    k_lstm5<<<dim3(4), dim3(512), 0, stream>>>(xw, whhp, enc_c0, hbuf, bar, hid);

    if (use_pack) {
        // 2. enc_proj via MFMA
        k_apack<<<dim3(BB*LL*H2/8/256), dim3(256), 0, stream>>>(enc_states, apenc, BB*LL/32, H2);
        k_wpack<<<dim3(H2*H2/8/256), dim3(256), 0, stream>>>(Wh_w, bwhw, H2/32, H2);
        k_gemm_mfma<<<dim3(BB*LL/192, H2/128), dim3(512), 0, stream>>>(apenc, bwhw, Wh_b, encp, H2, BB*LL/32, H2/32);
        // 3. dec_proj via MFMA
        k_apack<<<dim3(BT*HH/8/256), dim3(256), 0, stream>>>(hid, aphid, 12, HH);
        k_wpack<<<dim3(HH*H2/8/256), dim3(256), 0, stream>>>(Ws_w, bwsw, HH/32, H2);
        k_gemm_mfma<<<dim3(BT/192, H2/128), dim3(512), 0, stream>>>(aphid, bwsw, Ws_b, decp, H2, BT/32, HH/32);
    } else {
        k_gemm_bias<<<dim3(BB*LL/64, H2/128), dim3(256), 0, stream>>>(enc_states, Wh_w, Wh_b, encp, H2, H2);
        k_gemm_bias<<<dim3(BT/64, H2/128), dim3(256), 0, stream>>>(hid, Ws_w, Ws_b, decp, H2, HH);
    }
    // 4. e scores
    k_e<<<dim3(BB, LL/4), dim3(256), 0, stream>>>(encp, decp, v_w, v_b, enc_mask, attn);
    // 5. softmax + context + s
    k_softmax_ctx<<<dim3(BT), dim3(256), 0, stream>>>(attn, enc_states, hid, s_buf);
    // 6. switch + copy score
    k_switch_copy<<<dim3(BT), dim3(64), 0, stream>>>(s_buf, x_buf, enc_h0,
        wh_w, wh_b, ws_w, ws_b, wx_w, wx_b, wc_w, wc_b,
        article_inds, targets, attn, psw, copysc);
    // 7. big GEMM (fp8 path) or fallback
    if (use_pack) {
        k_apack8<<<dim3(BT*H3/8/256), dim3(256), 0, stream>>>(s_buf, apack8);
        k_bpack8<<<dim3(24, 196), dim3(256), 0, stream>>>(Vout_w, bpack8);
        k_big_fp8<<<dim3(2, NVB), dim3(512), 0, stream>>>(apack8, (const long*)bpack8, Vout_b, targets, psum, tlogit);
    } else {
        k_apack<<<dim3(BT*H3/8/256), dim3(256), 0, stream>>>(s_buf, apack, 12, H3);
        k_big<<<dim3(2, NVB), dim3(512), 0, stream>>>(apack, Vout_w, Vout_b, targets, psum, tlogit);
    }
    // 8. merge + nll
    k_lsum<<<dim3(BT), dim3(64), 0, stream>>>(psum, tlogit, targets, psw, copysc, dec_mask, nll);
    // 9. final loss
    k_final<<<dim3(1), dim3(64), 0, stream>>>(nll, dec_lens, out);
}